// Round 17
// baseline (328.324 us; speedup 1.0000x reference)
//
#include <hip/hip_runtime.h>
#include <math.h>

#define B_ 2
#define S_ 2048
#define M_ 1024
#define H_ 16
#define D_ 64
#define R_ (B_*S_)          // 4096 rows

typedef __attribute__((ext_vector_type(8))) short short8v;    // 8 bf16 = 4 VGPR
typedef __attribute__((ext_vector_type(4))) float float4v;
typedef __attribute__((ext_vector_type(16))) float float16v; // 32x32 C/D

__device__ __forceinline__ float4 ld4(const float* p) {
    return *(const float4* __restrict__)p;
}

__device__ __forceinline__ ushort f2bf(float f) {            // RNE
    union { float f; unsigned u; } x; x.f = f;
    unsigned u = x.u + 0x7fffu + ((x.u >> 16) & 1u);
    return (ushort)(u >> 16);
}
__device__ __forceinline__ float bf2f(ushort s) {
    union { unsigned u; float f; } x; x.u = ((unsigned)s) << 16; return x.f;
}
__device__ __forceinline__ unsigned cvtpk(float lo, float hi) {
    unsigned r;
    asm("v_cvt_pk_bf16_f32 %0, %1, %2" : "=v"(r) : "v"(lo), "v"(hi));
    return r;
}
#if __has_builtin(__builtin_amdgcn_exp2f)
__device__ __forceinline__ float fexp2(float x) { return __builtin_amdgcn_exp2f(x); }
#else
__device__ __forceinline__ float fexp2(float x) { return exp2f(x); }
#endif
#if __has_builtin(__builtin_amdgcn_rcpf)
__device__ __forceinline__ float frcp(float x) { return __builtin_amdgcn_rcpf(x); }
#else
__device__ __forceinline__ float frcp(float x) { return 1.f / x; }
#endif
__device__ __forceinline__ float4v mfma16(short8v a, short8v b, float4v c) {
    return __builtin_amdgcn_mfma_f32_16x16x32_bf16(a, b, c, 0, 0, 0);
}
__device__ __forceinline__ float16v mfma32(short8v a, short8v b, float16v c) {
    return __builtin_amdgcn_mfma_f32_32x32x16_bf16(a, b, c, 0, 0, 0);
}
__device__ __forceinline__ void glds16(const void* g, void* l) {
    __builtin_amdgcn_global_load_lds(
        (const __attribute__((address_space(1))) void*)g,
        (__attribute__((address_space(3))) void*)l, 16, 0, 0);
}

// ---------------------------------------------------------------------------
// prep kernels (fused)
// ---------------------------------------------------------------------------
__global__ __launch_bounds__(256) void cast2_k(const float* __restrict__ a,
                                               const float* __restrict__ b,
                                               ushort* __restrict__ oa,
                                               ushort* __restrict__ ob) {
    size_t u = (size_t)blockIdx.x * 256 + threadIdx.x;       // float4 units
    const float* in; ushort* out;
    if (u < (1u << 20)) { in = a; out = oa; }
    else { u -= (1u << 20); in = b; out = ob; }
    float4 v = ld4(in + u * 4);
    ushort4 o = { f2bf(v.x), f2bf(v.y), f2bf(v.z), f2bf(v.w) };
    *(ushort4*)&out[u * 4] = o;
}

__global__ __launch_bounds__(256) void biasp_k(
    const float* __restrict__ q1, const float* __restrict__ k1,
    const float* __restrict__ v1, const float* __restrict__ k2,
    const float* __restrict__ v2, const float* __restrict__ q2,
    float* __restrict__ dst, float SCv) {
    const int seg = blockIdx.x >> 2;
    const int li = (blockIdx.x & 3) * 256 + threadIdx.x;
    const float* s; int off; float sc;
    switch (seg) {
        case 0: s = q1; off = 0;    sc = SCv; break;
        case 1: s = k1; off = 1024; sc = 1.f; break;
        case 2: s = v1; off = 2048; sc = 1.f; break;
        case 3: s = k2; off = 4096; sc = 1.f; break;
        case 4: s = v2; off = 5120; sc = 1.f; break;
        default: s = q2; off = 8192; sc = SCv; break;
    }
    dst[off + li] = s[li] * sc;
}

__global__ __launch_bounds__(256) void wtransH_k(
    const float* __restrict__ s0, const float* __restrict__ s1,
    const float* __restrict__ s2, const float* __restrict__ s3,
    const float* __restrict__ s4, const float* __restrict__ s5,
    ushort* __restrict__ oQKV1, ushort* __restrict__ oQ2,
    ushort* __restrict__ oKV2, float SCv) {
    __shared__ float t[32][33];
    const int z = blockIdx.z, s6 = z >> 4, h = z & 15;
    const float* srcs[6] = { s0, s1, s2, s3, s4, s5 };
    const float* ib = srcs[s6] + (size_t)h * 1024 * 64;
    ushort* ob;
    if (s6 < 3)       ob = oQKV1 + (size_t)s6 * (1024 * 1024) + (size_t)h * (64 * 1024);
    else if (s6 == 3) ob = oQ2 + (size_t)h * (64 * 1024);
    else              ob = oKV2 + (size_t)(s6 - 4) * (1024 * 1024) + (size_t)h * (64 * 1024);
    const float scale = (s6 == 0 || s6 == 3) ? SCv : 1.f;
    const int k0 = blockIdx.y * 32, n0 = blockIdx.x * 32;
    const int tx = threadIdx.x & 31, ty = threadIdx.x >> 5;
    #pragma unroll
    for (int i = 0; i < 4; ++i)
        t[ty + i * 8][tx] = ib[(size_t)(k0 + ty + i * 8) * 64 + n0 + tx];
    __syncthreads();
    #pragma unroll
    for (int i = 0; i < 4; ++i)
        ob[(size_t)(n0 + ty + i * 8) * 1024 + k0 + tx] = f2bf(t[tx][ty + i * 8] * scale);
}

__global__ __launch_bounds__(256) void wtrans_k(const float* __restrict__ inA,
                                                const float* __restrict__ inB,
                                                ushort* __restrict__ outA,
                                                ushort* __restrict__ outB,
                                                int K, int N) {
    __shared__ float t[32][33];
    const float* ib = blockIdx.z ? inB : inA;
    ushort* ob = blockIdx.z ? outB : outA;
    const int k0 = blockIdx.y * 32, n0 = blockIdx.x * 32;
    const int tx = threadIdx.x & 31, ty = threadIdx.x >> 5;
    #pragma unroll
    for (int i = 0; i < 4; ++i)
        t[ty + i * 8][tx] = ib[(size_t)(k0 + ty + i * 8) * N + n0 + tx];
    __syncthreads();
    #pragma unroll
    for (int i = 0; i < 4; ++i)
        ob[(size_t)(n0 + ty + i * 8) * K + k0 + tx] = f2bf(t[tx][ty + i * 8]);
}

// ---------------------------------------------------------------------------
// bf16 MFMA GEMM, TMxTN tile, BK=64, 256 thr (4 waves 2x2). XOR-swizzled.
// ---------------------------------------------------------------------------
template<int TM, int TN, int BK, int OUTMODE, int ACT>
__global__ __launch_bounds__(256) void gemm_bf16_k(
    const ushort* __restrict__ A, const ushort* __restrict__ Bt,
    const float* __restrict__ bias, void* __restrict__ C,
    ushort* __restrict__ Cvt, int matV, int N, int K)
{
    constexpr int NI = TM / 32;
    constexpr int NJ = TN / 32;
    constexpr int KS = BK / 32;
    constexpr int CHR = BK / 8;                 // 16B chunks per row (8 for BK=64)
    __shared__ __align__(16) ushort At[TM * BK];
    __shared__ __align__(16) ushort Bts[TN * BK];
    const int tid = threadIdx.x, lane = tid & 63, w = tid >> 6;
    const int wm = w >> 1, wn = w & 1;
    const int q = lane & 15, g = lane >> 4;
    const int m0 = blockIdx.y * TM, n0 = blockIdx.x * TN;

    float4v acc[NI][NJ];
    #pragma unroll
    for (int i = 0; i < NI; ++i)
        #pragma unroll
        for (int j = 0; j < NJ; ++j) acc[i][j] = (float4v){0.f, 0.f, 0.f, 0.f};

    for (int k0 = 0; k0 < K; k0 += BK) {
        #pragma unroll
        for (int t = 0; t < TM * CHR / 256; ++t) {
            const int cb = (w * (TM * CHR / 256) + t) * 64;
            const int c = cb + lane;
            const int row = c / CHR, kc = (c % CHR) ^ (row & (CHR - 1));
            glds16(&A[(size_t)(m0 + row) * K + k0 + kc * 8], &At[cb * 8]);
        }
        #pragma unroll
        for (int t = 0; t < TN * CHR / 256; ++t) {
            const int cb = (w * (TN * CHR / 256) + t) * 64;
            const int c = cb + lane;
            const int row = c / CHR, kc = (c % CHR) ^ (row & (CHR - 1));
            glds16(&Bt[(size_t)(n0 + row) * K + k0 + kc * 8], &Bts[cb * 8]);
        }
        __syncthreads();
        #pragma unroll
        for (int ks = 0; ks < KS; ++ks) {
            short8v af[NI], bf[NJ];
            #pragma unroll
            for (int i = 0; i < NI; ++i) {
                const int row = wm * (TM / 2) + i * 16 + q;
                af[i] = *(const short8v*)((const char*)At +
                        row * (BK * 2) + (((ks * 4 + g) ^ (q & (CHR - 1))) << 4));
            }
            #pragma unroll
            for (int j = 0; j < NJ; ++j) {
                const int row = wn * (TN / 2) + j * 16 + q;
                bf[j] = *(const short8v*)((const char*)Bts +
                        row * (BK * 2) + (((ks * 4 + g) ^ (q & (CHR - 1))) << 4));
            }
            #pragma unroll
            for (int i = 0; i < NI; ++i)
                #pragma unroll
                for (int j = 0; j < NJ; ++j)
                    acc[i][j] = mfma16(af[i], bf[j], acc[i][j]);
        }
        __syncthreads();
    }

    float bcol[NJ];
    #pragma unroll
    for (int j = 0; j < NJ; ++j) bcol[j] = bias[n0 + wn * (TN / 2) + j * 16 + q];

    #pragma unroll
    for (int i = 0; i < NI; ++i) {
        const int rowg0 = m0 + wm * (TM / 2) + i * 16 + g * 4;
        #pragma unroll
        for (int j = 0; j < NJ; ++j) {
            const int colg = n0 + wn * (TN / 2) + j * 16 + q;
            float v[4];
            #pragma unroll
            for (int r = 0; r < 4; ++r) {
                v[r] = acc[i][j][r] + bcol[j];
                if (ACT) v[r] = fmaxf(v[r], 0.f);
            }
            if (OUTMODE == 0) {
                #pragma unroll
                for (int r = 0; r < 4; ++r)
                    ((float*)C)[(size_t)(rowg0 + r) * N + colg] = v[r];
            } else if (OUTMODE == 1) {
                #pragma unroll
                for (int r = 0; r < 4; ++r)
                    ((ushort*)C)[(size_t)(rowg0 + r) * N + colg] = f2bf(v[r]);
            } else {
                const int mat = colg >> 10, h = (colg >> 6) & 15, d = colg & 63;
                const int bb = rowg0 >> 11, s0 = rowg0 & 2047;
                if (mat == matV) {   // V -> transposed layout [bh][d][s]
                    uint2 pv;
                    pv.x = cvtpk(v[0], v[1]);
                    pv.y = cvtpk(v[2], v[3]);
                    *(uint2*)&Cvt[((size_t)(bb * H_ + h) * D_ + d) * S_ + s0] = pv;
                } else {
                    #pragma unroll
                    for (int r = 0; r < 4; ++r)
                        ((ushort*)C)[((((size_t)(mat * B_ + bb) * H_ + h) * S_) + s0 + r) * D_ + d] = f2bf(v[r]);
                }
            }
        }
    }
}

// ---------------------------------------------------------------------------
// Flash attention, 32x32x16 bf16 MFMA, swapped form, STATIC-MAX softmax.
// R17: 128-thread blocks (2 waves x 32 q), q-tile 64, grid 1024 = 4 blk/CU.
// Same per-wave math as R16 (validated); finer blocks -> 4 independent
// barrier groups/CU fill the ~1300-cyc/tile stall term.
// Causal: ktiles = qb+1; bijective qb map balances co-resident quads
// {t, t+8, t+16, t+24} -> {31-t, t, 23-t, t+8} (sum 62), longest-first.
// ---------------------------------------------------------------------------
template<int CAUSAL>
__global__ __launch_bounds__(128) void fattn_k(
    const ushort* __restrict__ Qg, const ushort* __restrict__ Kg,
    const ushort* __restrict__ VTg, ushort* __restrict__ Og, int Skv)
{
    __shared__ __align__(16) ushort Kt[2][64 * 64];   // [kv][d] swizzled, 8 KB x2
    __shared__ __align__(16) ushort Vt[2][64 * 64];   // [d][kv] swizzled, 8 KB x2
    const int tid = threadIdx.x, lane = tid & 63, w = tid >> 6;   // w 0..1
    const int q = lane & 31, hi = lane >> 5;
    const int id = blockIdx.x;
    const int bh = id & 31;
    const int t_ = id >> 5;                           // 0..31
    int qb;
    if (CAUSAL) {
        if (t_ < 8)       qb = 31 - t_;
        else if (t_ < 16) qb = t_ - 8;
        else if (t_ < 24) qb = 39 - t_;
        else              qb = t_ - 16;
    } else qb = t_;
    const int q0b = qb * 64;
    const int q0w = q0b + w * 32;
    const float MB = 24.f;                            // static exponent bias

    // staging sources: 1024 chunks over 128 threads = 8/thread (4 K + 4 V)
    const ushort* kS[4]; const ushort* vS[4];
    #pragma unroll
    for (int i = 0; i < 4; ++i) {
        const int c = i * 128 + tid;
        const int r = c >> 3, ch = c & 7, sc = ch ^ (r & 7);
        kS[i] = Kg + ((size_t)bh * Skv + r) * 64 + sc * 8;
        vS[i] = VTg + ((size_t)bh * 64 + r) * (size_t)Skv + sc * 8;
    }

#define STAGE(nb) do { \
        glds16(kS[0], &Kt[nb][(tid) * 8]); \
        glds16(kS[1], &Kt[nb][(tid + 128) * 8]); \
        glds16(kS[2], &Kt[nb][(tid + 256) * 8]); \
        glds16(kS[3], &Kt[nb][(tid + 384) * 8]); \
        glds16(vS[0], &Vt[nb][(tid) * 8]); \
        glds16(vS[1], &Vt[nb][(tid + 128) * 8]); \
        glds16(vS[2], &Vt[nb][(tid + 256) * 8]); \
        glds16(vS[3], &Vt[nb][(tid + 384) * 8]); \
        kS[0] += 64 * 64; kS[1] += 64 * 64; kS[2] += 64 * 64; kS[3] += 64 * 64; \
        vS[0] += 64; vS[1] += 64; vS[2] += 64; vS[3] += 64; } while (0)

    // Q B-fragments (Q pre-scaled by 0.125*log2e): B[k=d][col=q], k=ki*16+hi*8+e
    short8v qf[4];
    #pragma unroll
    for (int ki = 0; ki < 4; ++ki)
        qf[ki] = *(const short8v*)&Qg[((size_t)bh * S_ + q0w + q) * 64 + ki * 16 + hi * 8];

    // LDS byte base: row=q (+b2*4096), chunk=(2ki+hi)^(q&7) => base ^ (ki<<5)
    const int ktB = q * 128 + ((hi ^ (q & 7)) << 4);

    float16v oacc0, oacc1;
    #pragma unroll
    for (int r = 0; r < 16; ++r) { oacc0[r] = 0.f; oacc1[r] = 0.f; }
    float l_ = 0.f;

    const int ktiles = CAUSAL ? (qb + 1) : (Skv >> 6);
    int cur = 0;

    STAGE(0);
    __syncthreads();

    for (int kt = 0; kt < ktiles; ++kt) {
        if (kt + 1 < ktiles) STAGE(cur ^ 1);          // issue-early
        const char* ktp = (const char*)Kt + cur * 8192;
        const char* vtp = (const char*)Vt + cur * 8192;
        const int kv0 = kt * 64;

        // S^T = K . Q^T : two kv-32 blocks, K=16 chunks over d
        float16v st0, st1;
        #pragma unroll
        for (int r = 0; r < 16; ++r) { st0[r] = 0.f; st1[r] = 0.f; }
        __builtin_amdgcn_s_setprio(1);
        #pragma unroll
        for (int ki = 0; ki < 4; ++ki) {
            short8v kf0 = *(const short8v*)(ktp + (ktB ^ (ki << 5)));
            short8v kf1 = *(const short8v*)(ktp + (ktB ^ (ki << 5)) + 4096);
            st0 = mfma32(kf0, qf[ki], st0);
            st1 = mfma32(kf1, qf[ki], st1);
        }
        __builtin_amdgcn_s_setprio(0);

        if (CAUSAL && kt == ktiles - 1) {             // diagonal tile (kv0 == q0b)
            const int qg_ = q0w + q;
            #pragma unroll
            for (int r = 0; r < 16; ++r) {
                const int row = (r & 3) + 8 * (r >> 2) + 4 * hi;
                if (kv0 + row > qg_)      st0[r] = -1e9f;
                if (kv0 + 32 + row > qg_) st1[r] = -1e9f;
            }
        }

        // STATIC-MAX: P = exp2(s - MB). exact (scale cancels in O = PV / l).
        float ts[16];
        #pragma unroll
        for (int r = 0; r < 16; ++r) {
            st0[r] = fexp2(st0[r] - MB);
            st1[r] = fexp2(st1[r] - MB);
            ts[r] = st0[r] + st1[r];
        }
        #pragma unroll
        for (int off = 8; off >= 1; off >>= 1)
            #pragma unroll
            for (int i = 0; i < 8; ++i)
                if (i < off) ts[i] += ts[i + off];
        l_ += ts[0] + __shfl_xor(ts[0], 32);

        // pack P to bf16 words: W[b][s] = rows (2s,2s+1) of kv-block b (lane's set)
        unsigned W0[8], W1[8];
        #pragma unroll
        for (int s = 0; s < 8; ++s) {
            W0[s] = cvtpk(st0[2 * s], st0[2 * s + 1]);
            W1[s] = cvtpk(st1[2 * s], st1[2 * s + 1]);
        }

        // build PV B-frags bq[kb]: P[kv0+kb*16+hi*8+e][q], e=0..7 (R14-verified)
        short8v bq[4];
        #pragma unroll
        for (int kb = 0; kb < 4; ++kb) {
            union { unsigned u[4]; short8v v; } bb;
            #pragma unroll
            for (int j = 0; j < 4; ++j) {
                const unsigned* Wb = (kb >> 1) ? W1 : W0;
                const int s0 = (j & 1) + 4 * (kb & 1);
                const unsigned own  = hi ? Wb[s0 + 2] : Wb[s0];
                const unsigned send = hi ? Wb[s0]     : Wb[s0 + 2];
                const unsigned rec  = (unsigned)__shfl_xor((int)send, 32);
                bb.u[j] = (j >> 1) ? (hi ? own : rec) : (hi ? rec : own);
            }
            bq[kb] = bb.v;
        }

        // O^T += V^T . P^T : two d-32 blocks x four kv-16 blocks
        __builtin_amdgcn_s_setprio(1);
        #pragma unroll
        for (int kb = 0; kb < 4; ++kb) {
            short8v vf0 = *(const short8v*)(vtp + (ktB ^ (kb << 5)));
            short8v vf1 = *(const short8v*)(vtp + (ktB ^ (kb << 5)) + 4096);
            oacc0 = mfma32(vf0, bq[kb], oacc0);
            oacc1 = mfma32(vf1, bq[kb], oacc1);
        }
        __builtin_amdgcn_s_setprio(0);

        __syncthreads();       // drains stage(t+1) vmcnt + protects Kt/Vt[cur]
        cur ^= 1;
    }
#undef STAGE

    // normalize + stage O (64 rows x 64 d = 8 KB) into dead Kt[0], swizzled
    const float inv = frcp(l_);
    char* Ob = (char*)Kt;
    const int qr = w * 32 + q;
    #pragma unroll
    for (int s = 0; s < 8; ++s) {
        const int d0a = 2 * (s & 1) + 8 * (s >> 1) + 4 * hi;        // db=0
        unsigned wa = cvtpk(oacc0[2 * s] * inv, oacc0[2 * s + 1] * inv);
        *(unsigned*)(Ob + qr * 128 + ((((d0a >> 3) ^ (qr & 7)) << 4) | ((2 * d0a) & 15))) = wa;
        const int d0b = d0a + 32;                                    // db=1
        unsigned wb = cvtpk(oacc1[2 * s] * inv, oacc1[2 * s + 1] * inv);
        *(unsigned*)(Ob + qr * 128 + ((((d0b >> 3) ^ (qr & 7)) << 4) | ((2 * d0b) & 15))) = wb;
    }
    __syncthreads();
    const int b = bh >> 4, h = bh & 15;
    #pragma unroll
    for (int t = 0; t < 4; ++t) {
        const int c = t * 128 + tid;
        const int qrow = c >> 3, ch = c & 7;
        short8v v = *(const short8v*)(Ob + qrow * 128 + ((ch ^ (qrow & 7)) << 4));
        *(short8v*)&Og[((size_t)(b * S_ + q0b + qrow)) * M_ + h * 64 + ch * 8] = v;
    }
}

// ---------------------------------------------------------------------------
// Fused residual-add + LayerNorm. X bf16, residual fp32; emits fp32 (+bf16).
// ---------------------------------------------------------------------------
template<int EMITB>
__global__ __launch_bounds__(256) void ln_k(
    const ushort* __restrict__ X, const float* __restrict__ Rz,
    const float* __restrict__ g, const float* __restrict__ be,
    float* __restrict__ outf, ushort* __restrict__ outb)
{
    __shared__ float red[8];
    const int row = blockIdx.x, tid = threadIdx.x;
    const int lane = tid & 63, w = tid >> 6;

    ushort4 xu = *(const ushort4*)&X[(size_t)row * M_ + tid * 4];
    float4 rr = ld4(Rz + (size_t)row * M_ + tid * 4);
    float4 x = make_float4(bf2f(xu.x) + rr.x, bf2f(xu.y) + rr.y,
                           bf2f(xu.z) + rr.z, bf2f(xu.w) + rr.w);

    float sm = x.x + x.y + x.z + x.w;
    #pragma unroll
    for (int off = 1; off < 64; off <<= 1) sm += __shfl_xor(sm, off);
    if (lane == 0) red[w] = sm;
    __syncthreads();
    const float mean = (red[0] + red[1] + red[2] + red[3]) * (1.f / M_);

    x.x -= mean; x.y -= mean; x.z -= mean; x.w -= mean;
    float vs = x.x * x.x + x.y * x.y + x.z * x.z + x.w * x.w;
    #pragma unroll
    for (int off = 1; off < 64; off <<= 1) vs += __shfl_xor(vs, off);
    if (lane == 0) red[4 + w] = vs;
    __syncthreads();
    const float var = (red[4] + red[5] + red[6] + red[7]) * (1.f / M_);
    const float rs = rsqrtf(var + 1e-5f);

    float4 gg = ld4(g + tid * 4), bb = ld4(be + tid * 4);
    float4 y = make_float4(x.x * rs * gg.x + bb.x, x.y * rs * gg.y + bb.y,
                           x.z * rs * gg.z + bb.z, x.w * rs * gg.w + bb.w);
    *(float4*)(outf + (size_t)row * M_ + tid * 4) = y;
    if (EMITB) {
        ushort4 ob = { f2bf(y.x), f2bf(y.y), f2bf(y.z), f2bf(y.w) };
        *(ushort4*)&outb[(size_t)row * M_ + tid * 4] = ob;
    }
}

// ---------------------------------------------------------------------------
extern "C" void kernel_launch(void* const* d_in, const int* in_sizes, int n_in,
                              void* d_out, int out_size, void* d_ws, size_t ws_size,
                              hipStream_t stream)
{
    const float* input = (const float*)d_in[0];
    const float* enc   = (const float*)d_in[1];
    const float* Wq1 = (const float*)d_in[2];  const float* bq1 = (const float*)d_in[3];
    const float* Wk1 = (const float*)d_in[4];  const float* bk1 = (const float*)d_in[5];
    const float* Wv1 = (const float*)d_in[6];  const float* bv1 = (const float*)d_in[7];
    const float* Wo1 = (const float*)d_in[8];  const float* bo1 = (const float*)d_in[9];
    const float* ln1g = (const float*)d_in[10]; const float* ln1b = (const float*)d_in[11];
    const float* Wq2 = (const float*)d_in[12]; const float* bq2 = (const float*)d_in[13];
    const float* Wk2 = (const float*)d_in[14]; const float* bk2 = (const float*)d_in[15];
    const float* Wv2 = (const float*)d_in[16]; const float* bv2 = (const float*)d_in[17];
    const float* Wo2 = (const float*)d_in[18]; const float* bo2 = (const float*)d_in[19];
    const float* ln2g = (const float*)d_in[20]; const float* ln2b = (const float*)d_in[21];
    const float* Wf1 = (const float*)d_in[22]; const float* bf1 = (const float*)d_in[23];
    const float* Wf2 = (const float*)d_in[24]; const float* bf2 = (const float*)d_in[25];
    const float* ln3g = (const float*)d_in[26]; const float* ln3b = (const float*)d_in[27];

    const float SC = 0.18033688011112042f;     // 0.125 * log2(e)

    char* W = (char*)d_ws;
    #define OFS(mb) ((void*)(W + (size_t)(mb) * 1024 * 1024))
    ushort* x0b    = (ushort*)OFS(0);
    ushort* encb   = (ushort*)OFS(8);
    ushort* WqkvT1 = (ushort*)OFS(16);
    ushort* Wo1T   = (ushort*)OFS(22);
    ushort* Wq2T   = (ushort*)OFS(24);
    ushort* WkvT2  = (ushort*)OFS(26);
    ushort* Wo2T   = (ushort*)OFS(30);
    ushort* Wf1T   = (ushort*)OFS(32);
    ushort* Wf2T   = (ushort*)OFS(36);
    float*  biasQKV1 = (float*)OFS(40);
    float*  biasKV2  = (float*)((char*)OFS(40) + 16384);
    float*  biasQ2   = (float*)((char*)OFS(40) + 32768);
    ushort* QKV1   = (ushort*)OFS(41);   // [3][B][H][S][D] (V region unused)
    ushort* VT1    = (ushort*)OFS(65);
    ushort* att1b  = (ushort*)OFS(73);
    ushort* o1b    = (ushort*)OFS(81);
    float*  out1f  = (float*)OFS(41);
    ushort* out1b  = (ushort*)OFS(57);
    ushort* Q2     = (ushort*)OFS(65);
    ushort* KV2    = (ushort*)OFS(73);   // [2][B][H][S][D] (V region unused)
    ushort* VT2    = (ushort*)OFS(0);
    ushort* att2b  = (ushort*)OFS(8);
    ushort* o2b    = (ushort*)OFS(65);
    float*  out2f  = (float*)OFS(73);
    ushort* out2b  = (ushort*)OFS(0);
    ushort* ff1b   = (ushort*)OFS(41);
    ushort* ff2b   = (ushort*)OFS(57);
    float*  out    = (float*)d_out;
    const size_t MAT = (size_t)B_ * H_ * S_ * D_;   // 4 Mi elements

    dim3 blk(256);
    dim3 blkA(128);

    // ---- prep (6 launches) ----
    cast2_k<<<8192, blk, 0, stream>>>(input, enc, x0b, encb);
    biasp_k<<<24, blk, 0, stream>>>(bq1, bk1, bv1, bk2, bv2, bq2, biasQKV1, SC);
    wtransH_k<<<dim3(2, 32, 96), blk, 0, stream>>>(Wq1, Wk1, Wv1, Wq2, Wk2, Wv2,
                                                   WqkvT1, Wq2T, WkvT2, SC);
    wtrans_k<<<dim3(32, 32, 2), blk, 0, stream>>>(Wo1, Wo2, Wo1T, Wo2T, 1024, 1024);
    wtrans_k<<<dim3(64, 32, 1), blk, 0, stream>>>(Wf1, Wf1, Wf1T, Wf1T, 1024, 2048);
    wtrans_k<<<dim3(32, 64, 1), blk, 0, stream>>>(Wf2, Wf2, Wf2T, Wf2T, 2048, 1024);

    // ---- masked self-attention ----
    gemm_bf16_k<128, 128, 64, 2, 0><<<dim3(24, 32), blk, 0, stream>>>(
        x0b, WqkvT1, biasQKV1, QKV1, VT1, 2, 3072, 1024);
    fattn_k<1><<<dim3(1024), blkA, 0, stream>>>(QKV1, QKV1 + MAT, VT1, att1b, S_);
    gemm_bf16_k<64, 64, 64, 1, 0><<<dim3(16, 64), blk, 0, stream>>>(
        att1b, Wo1T, bo1, o1b, nullptr, 9, 1024, 1024);
    ln_k<1><<<dim3(R_), blk, 0, stream>>>(o1b, input, ln1g, ln1b, out1f, out1b);

    // ---- cross-attention ----
    gemm_bf16_k<64, 64, 64, 2, 0><<<dim3(16, 64), blk, 0, stream>>>(
        out1b, Wq2T, biasQ2, Q2, nullptr, 9, 1024, 1024);
    gemm_bf16_k<128, 128, 64, 2, 0><<<dim3(16, 32), blk, 0, stream>>>(
        encb, WkvT2, biasKV2, KV2, VT2, 1, 2048, 1024);
    fattn_k<0><<<dim3(1024), blkA, 0, stream>>>(Q2, KV2, VT2, att2b, S_);
    gemm_bf16_k<64, 64, 64, 1, 0><<<dim3(16, 64), blk, 0, stream>>>(
        att2b, Wo2T, bo2, o2b, nullptr, 9, 1024, 1024);
    ln_k<1><<<dim3(R_), blk, 0, stream>>>(o2b, out1f, ln2g, ln2b, out2f, out2b);

    // ---- FFN ----
    gemm_bf16_k<128, 64, 64, 1, 1><<<dim3(32, 32), blk, 0, stream>>>(
        out2b, Wf1T, bf1, ff1b, nullptr, 9, 2048, 1024);
    gemm_bf16_k<64, 64, 64, 1, 0><<<dim3(16, 64), blk, 0, stream>>>(
        ff1b, Wf2T, bf2, ff2b, nullptr, 9, 1024, 2048);
    ln_k<0><<<dim3(R_), blk, 0, stream>>>(ff2b, out2f, ln3g, ln3b, out, nullptr);
    #undef OFS
}

// Round 18
// 307.389 us; speedup vs baseline: 1.0681x; 1.0681x over previous
//
#include <hip/hip_runtime.h>
#include <math.h>

#define B_ 2
#define S_ 2048
#define M_ 1024
#define H_ 16
#define D_ 64
#define R_ (B_*S_)          // 4096 rows

typedef __attribute__((ext_vector_type(8))) short short8v;    // 8 bf16 = 4 VGPR
typedef __attribute__((ext_vector_type(4))) float float4v;
typedef __attribute__((ext_vector_type(16))) float float16v; // 32x32 C/D

__device__ __forceinline__ float4 ld4(const float* p) {
    return *(const float4* __restrict__)p;
}

__device__ __forceinline__ ushort f2bf(float f) {            // RNE
    union { float f; unsigned u; } x; x.f = f;
    unsigned u = x.u + 0x7fffu + ((x.u >> 16) & 1u);
    return (ushort)(u >> 16);
}
__device__ __forceinline__ float bf2f(ushort s) {
    union { unsigned u; float f; } x; x.u = ((unsigned)s) << 16; return x.f;
}
__device__ __forceinline__ unsigned cvtpk(float lo, float hi) {
    unsigned r;
    asm("v_cvt_pk_bf16_f32 %0, %1, %2" : "=v"(r) : "v"(lo), "v"(hi));
    return r;
}
#if __has_builtin(__builtin_amdgcn_exp2f)
__device__ __forceinline__ float fexp2(float x) { return __builtin_amdgcn_exp2f(x); }
#else
__device__ __forceinline__ float fexp2(float x) { return exp2f(x); }
#endif
#if __has_builtin(__builtin_amdgcn_rcpf)
__device__ __forceinline__ float frcp(float x) { return __builtin_amdgcn_rcpf(x); }
#else
__device__ __forceinline__ float frcp(float x) { return 1.f / x; }
#endif
__device__ __forceinline__ float4v mfma16(short8v a, short8v b, float4v c) {
    return __builtin_amdgcn_mfma_f32_16x16x32_bf16(a, b, c, 0, 0, 0);
}
__device__ __forceinline__ float16v mfma32(short8v a, short8v b, float16v c) {
    return __builtin_amdgcn_mfma_f32_32x32x16_bf16(a, b, c, 0, 0, 0);
}
__device__ __forceinline__ void glds16(const void* g, void* l) {
    __builtin_amdgcn_global_load_lds(
        (const __attribute__((address_space(1))) void*)g,
        (__attribute__((address_space(3))) void*)l, 16, 0, 0);
}

// ---------------------------------------------------------------------------
// prep kernels (fused)
// ---------------------------------------------------------------------------
__global__ __launch_bounds__(256) void cast2_k(const float* __restrict__ a,
                                               const float* __restrict__ b,
                                               ushort* __restrict__ oa,
                                               ushort* __restrict__ ob) {
    size_t u = (size_t)blockIdx.x * 256 + threadIdx.x;       // float4 units
    const float* in; ushort* out;
    if (u < (1u << 20)) { in = a; out = oa; }
    else { u -= (1u << 20); in = b; out = ob; }
    float4 v = ld4(in + u * 4);
    ushort4 o = { f2bf(v.x), f2bf(v.y), f2bf(v.z), f2bf(v.w) };
    *(ushort4*)&out[u * 4] = o;
}

__global__ __launch_bounds__(256) void biasp_k(
    const float* __restrict__ q1, const float* __restrict__ k1,
    const float* __restrict__ v1, const float* __restrict__ k2,
    const float* __restrict__ v2, const float* __restrict__ q2,
    float* __restrict__ dst, float SCv) {
    const int seg = blockIdx.x >> 2;
    const int li = (blockIdx.x & 3) * 256 + threadIdx.x;
    const float* s; int off; float sc;
    switch (seg) {
        case 0: s = q1; off = 0;    sc = SCv; break;
        case 1: s = k1; off = 1024; sc = 1.f; break;
        case 2: s = v1; off = 2048; sc = 1.f; break;
        case 3: s = k2; off = 4096; sc = 1.f; break;
        case 4: s = v2; off = 5120; sc = 1.f; break;
        default: s = q2; off = 8192; sc = SCv; break;
    }
    dst[off + li] = s[li] * sc;
}

__global__ __launch_bounds__(256) void wtransH_k(
    const float* __restrict__ s0, const float* __restrict__ s1,
    const float* __restrict__ s2, const float* __restrict__ s3,
    const float* __restrict__ s4, const float* __restrict__ s5,
    ushort* __restrict__ oQKV1, ushort* __restrict__ oQ2,
    ushort* __restrict__ oKV2, float SCv) {
    __shared__ float t[32][33];
    const int z = blockIdx.z, s6 = z >> 4, h = z & 15;
    const float* srcs[6] = { s0, s1, s2, s3, s4, s5 };
    const float* ib = srcs[s6] + (size_t)h * 1024 * 64;
    ushort* ob;
    if (s6 < 3)       ob = oQKV1 + (size_t)s6 * (1024 * 1024) + (size_t)h * (64 * 1024);
    else if (s6 == 3) ob = oQ2 + (size_t)h * (64 * 1024);
    else              ob = oKV2 + (size_t)(s6 - 4) * (1024 * 1024) + (size_t)h * (64 * 1024);
    const float scale = (s6 == 0 || s6 == 3) ? SCv : 1.f;
    const int k0 = blockIdx.y * 32, n0 = blockIdx.x * 32;
    const int tx = threadIdx.x & 31, ty = threadIdx.x >> 5;
    #pragma unroll
    for (int i = 0; i < 4; ++i)
        t[ty + i * 8][tx] = ib[(size_t)(k0 + ty + i * 8) * 64 + n0 + tx];
    __syncthreads();
    #pragma unroll
    for (int i = 0; i < 4; ++i)
        ob[(size_t)(n0 + ty + i * 8) * 1024 + k0 + tx] = f2bf(t[tx][ty + i * 8] * scale);
}

__global__ __launch_bounds__(256) void wtrans_k(const float* __restrict__ inA,
                                                const float* __restrict__ inB,
                                                ushort* __restrict__ outA,
                                                ushort* __restrict__ outB,
                                                int K, int N) {
    __shared__ float t[32][33];
    const float* ib = blockIdx.z ? inB : inA;
    ushort* ob = blockIdx.z ? outB : outA;
    const int k0 = blockIdx.y * 32, n0 = blockIdx.x * 32;
    const int tx = threadIdx.x & 31, ty = threadIdx.x >> 5;
    #pragma unroll
    for (int i = 0; i < 4; ++i)
        t[ty + i * 8][tx] = ib[(size_t)(k0 + ty + i * 8) * N + n0 + tx];
    __syncthreads();
    #pragma unroll
    for (int i = 0; i < 4; ++i)
        ob[(size_t)(n0 + ty + i * 8) * K + k0 + tx] = f2bf(t[tx][ty + i * 8]);
}

// ---------------------------------------------------------------------------
// bf16 MFMA GEMM, TMxTN tile, BK templated, 256 thr (4 waves 2x2). XOR-swizzled.
// ---------------------------------------------------------------------------
template<int TM, int TN, int BK, int OUTMODE, int ACT>
__global__ __launch_bounds__(256) void gemm_bf16_k(
    const ushort* __restrict__ A, const ushort* __restrict__ Bt,
    const float* __restrict__ bias, void* __restrict__ C,
    ushort* __restrict__ Cvt, int matV, int N, int K)
{
    constexpr int NI = TM / 32;
    constexpr int NJ = TN / 32;
    constexpr int KS = BK / 32;
    constexpr int CHR = BK / 8;                 // 16B chunks per row
    __shared__ __align__(16) ushort At[TM * BK];
    __shared__ __align__(16) ushort Bts[TN * BK];
    const int tid = threadIdx.x, lane = tid & 63, w = tid >> 6;
    const int wm = w >> 1, wn = w & 1;
    const int q = lane & 15, g = lane >> 4;
    const int m0 = blockIdx.y * TM, n0 = blockIdx.x * TN;

    float4v acc[NI][NJ];
    #pragma unroll
    for (int i = 0; i < NI; ++i)
        #pragma unroll
        for (int j = 0; j < NJ; ++j) acc[i][j] = (float4v){0.f, 0.f, 0.f, 0.f};

    for (int k0 = 0; k0 < K; k0 += BK) {
        #pragma unroll
        for (int t = 0; t < TM * CHR / 256; ++t) {
            const int cb = (w * (TM * CHR / 256) + t) * 64;
            const int c = cb + lane;
            const int row = c / CHR, kc = (c % CHR) ^ (row & (CHR - 1));
            glds16(&A[(size_t)(m0 + row) * K + k0 + kc * 8], &At[cb * 8]);
        }
        #pragma unroll
        for (int t = 0; t < TN * CHR / 256; ++t) {
            const int cb = (w * (TN * CHR / 256) + t) * 64;
            const int c = cb + lane;
            const int row = c / CHR, kc = (c % CHR) ^ (row & (CHR - 1));
            glds16(&Bt[(size_t)(n0 + row) * K + k0 + kc * 8], &Bts[cb * 8]);
        }
        __syncthreads();
        #pragma unroll
        for (int ks = 0; ks < KS; ++ks) {
            short8v af[NI], bf[NJ];
            #pragma unroll
            for (int i = 0; i < NI; ++i) {
                const int row = wm * (TM / 2) + i * 16 + q;
                af[i] = *(const short8v*)((const char*)At +
                        row * (BK * 2) + (((ks * 4 + g) ^ (q & (CHR - 1))) << 4));
            }
            #pragma unroll
            for (int j = 0; j < NJ; ++j) {
                const int row = wn * (TN / 2) + j * 16 + q;
                bf[j] = *(const short8v*)((const char*)Bts +
                        row * (BK * 2) + (((ks * 4 + g) ^ (q & (CHR - 1))) << 4));
            }
            #pragma unroll
            for (int i = 0; i < NI; ++i)
                #pragma unroll
                for (int j = 0; j < NJ; ++j)
                    acc[i][j] = mfma16(af[i], bf[j], acc[i][j]);
        }
        __syncthreads();
    }

    float bcol[NJ];
    #pragma unroll
    for (int j = 0; j < NJ; ++j) bcol[j] = bias[n0 + wn * (TN / 2) + j * 16 + q];

    #pragma unroll
    for (int i = 0; i < NI; ++i) {
        const int rowg0 = m0 + wm * (TM / 2) + i * 16 + g * 4;
        #pragma unroll
        for (int j = 0; j < NJ; ++j) {
            const int colg = n0 + wn * (TN / 2) + j * 16 + q;
            float v[4];
            #pragma unroll
            for (int r = 0; r < 4; ++r) {
                v[r] = acc[i][j][r] + bcol[j];
                if (ACT) v[r] = fmaxf(v[r], 0.f);
            }
            if (OUTMODE == 0) {
                #pragma unroll
                for (int r = 0; r < 4; ++r)
                    ((float*)C)[(size_t)(rowg0 + r) * N + colg] = v[r];
            } else if (OUTMODE == 1) {
                #pragma unroll
                for (int r = 0; r < 4; ++r)
                    ((ushort*)C)[(size_t)(rowg0 + r) * N + colg] = f2bf(v[r]);
            } else {
                const int mat = colg >> 10, h = (colg >> 6) & 15, d = colg & 63;
                const int bb = rowg0 >> 11, s0 = rowg0 & 2047;
                if (mat == matV) {   // V -> transposed layout [bh][d][s]
                    uint2 pv;
                    pv.x = cvtpk(v[0], v[1]);
                    pv.y = cvtpk(v[2], v[3]);
                    *(uint2*)&Cvt[((size_t)(bb * H_ + h) * D_ + d) * S_ + s0] = pv;
                } else {
                    #pragma unroll
                    for (int r = 0; r < 4; ++r)
                        ((ushort*)C)[((((size_t)(mat * B_ + bb) * H_ + h) * S_) + s0 + r) * D_ + d] = f2bf(v[r]);
                }
            }
        }
    }
}

// ---------------------------------------------------------------------------
// Flash attention, 32x32x16 bf16 MFMA, swapped form, STATIC-MAX softmax.
// R16-measured-best: 256 thr = 4 waves, q-tile 128, kv-tile 64 dbuf,
// P = exp2(s - 24) exact; grid 512. 57.4 us/dispatch.
// ---------------------------------------------------------------------------
template<int CAUSAL>
__global__ __launch_bounds__(256, 3) void fattn_k(
    const ushort* __restrict__ Qg, const ushort* __restrict__ Kg,
    const ushort* __restrict__ VTg, ushort* __restrict__ Og, int Skv)
{
    __shared__ __align__(16) ushort Kt[2][64 * 64];   // [kv][d] swizzled, 8 KB x2
    __shared__ __align__(16) ushort Vt[2][64 * 64];   // [d][kv] swizzled, 8 KB x2
    const int tid = threadIdx.x, lane = tid & 63, w = tid >> 6;   // w 0..3
    const int q = lane & 31, hi = lane >> 5;
    const int id = blockIdx.x;
    const int bh = id & 31;
    const int t_ = id >> 5;
    const int qb = CAUSAL ? ((t_ < 8) ? (15 - t_) : (t_ - 8)) : t_;
    const int q0b = qb * 128;
    const int q0w = q0b + w * 32;
    const float MB = 24.f;                            // static exponent bias

    // staging sources (2 chunks per thread per matrix), pre-swizzled
    const int c0 = tid, c1 = tid + 256;
    const ushort* kS0 = Kg + ((size_t)bh * Skv + (c0 >> 3)) * 64 + (((c0 & 7) ^ ((c0 >> 3) & 7)) * 8);
    const ushort* kS1 = Kg + ((size_t)bh * Skv + (c1 >> 3)) * 64 + (((c1 & 7) ^ ((c1 >> 3) & 7)) * 8);
    const ushort* vS0 = VTg + ((size_t)bh * 64 + (c0 >> 3)) * (size_t)Skv + (((c0 & 7) ^ ((c0 >> 3) & 7)) * 8);
    const ushort* vS1 = VTg + ((size_t)bh * 64 + (c1 >> 3)) * (size_t)Skv + (((c1 & 7) ^ ((c1 >> 3) & 7)) * 8);

#define STAGE(nb) do { \
        glds16(kS0, &Kt[nb][(w * 64) * 8]); \
        glds16(kS1, &Kt[nb][(256 + w * 64) * 8]); \
        glds16(vS0, &Vt[nb][(w * 64) * 8]); \
        glds16(vS1, &Vt[nb][(256 + w * 64) * 8]); \
        kS0 += 64 * 64; kS1 += 64 * 64; vS0 += 64; vS1 += 64; } while (0)

    // Q B-fragments (Q pre-scaled by 0.125*log2e): B[k=d][col=q], k=ki*16+hi*8+e
    short8v qf[4];
    #pragma unroll
    for (int ki = 0; ki < 4; ++ki)
        qf[ki] = *(const short8v*)&Qg[((size_t)bh * S_ + q0w + q) * 64 + ki * 16 + hi * 8];

    // LDS byte base: row=q (+b2*4096), chunk=(2ki+hi)^(q&7) => base ^ (ki<<5)
    const int ktB = q * 128 + ((hi ^ (q & 7)) << 4);

    float16v oacc0, oacc1;
    #pragma unroll
    for (int r = 0; r < 16; ++r) { oacc0[r] = 0.f; oacc1[r] = 0.f; }
    float l_ = 0.f;

    const int ktiles = CAUSAL ? (2 * qb + 2) : (Skv >> 6);
    int cur = 0;

    STAGE(0);
    __syncthreads();

    for (int kt = 0; kt < ktiles; ++kt) {
        if (kt + 1 < ktiles) STAGE(cur ^ 1);          // issue-early
        const char* ktp = (const char*)Kt + cur * 8192;
        const char* vtp = (const char*)Vt + cur * 8192;
        const int kv0 = kt * 64;

        // S^T = K . Q^T : two kv-32 blocks, K=16 chunks over d
        float16v st0, st1;
        #pragma unroll
        for (int r = 0; r < 16; ++r) { st0[r] = 0.f; st1[r] = 0.f; }
        __builtin_amdgcn_s_setprio(1);
        #pragma unroll
        for (int ki = 0; ki < 4; ++ki) {
            short8v kf0 = *(const short8v*)(ktp + (ktB ^ (ki << 5)));
            short8v kf1 = *(const short8v*)(ktp + (ktB ^ (ki << 5)) + 4096);
            st0 = mfma32(kf0, qf[ki], st0);
            st1 = mfma32(kf1, qf[ki], st1);
        }
        __builtin_amdgcn_s_setprio(0);

        if (CAUSAL && kv0 + 63 > q0b) {               // diagonal tiles only
            const int qg_ = q0w + q;
            #pragma unroll
            for (int r = 0; r < 16; ++r) {
                const int row = (r & 3) + 8 * (r >> 2) + 4 * hi;
                if (kv0 + row > qg_)      st0[r] = -1e9f;
                if (kv0 + 32 + row > qg_) st1[r] = -1e9f;
            }
        }

        // STATIC-MAX: P = exp2(s - MB). exact (scale cancels in O = PV / l).
        float ts[16];
        #pragma unroll
        for (int r = 0; r < 16; ++r) {
            st0[r] = fexp2(st0[r] - MB);
            st1[r] = fexp2(st1[r] - MB);
            ts[r] = st0[r] + st1[r];
        }
        #pragma unroll
        for (int off = 8; off >= 1; off >>= 1)
            #pragma unroll
            for (int i = 0; i < 8; ++i)
                if (i < off) ts[i] += ts[i + off];
        l_ += ts[0] + __shfl_xor(ts[0], 32);

        // pack P to bf16 words: W[b][s] = rows (2s,2s+1) of kv-block b (lane's set)
        unsigned W0[8], W1[8];
        #pragma unroll
        for (int s = 0; s < 8; ++s) {
            W0[s] = cvtpk(st0[2 * s], st0[2 * s + 1]);
            W1[s] = cvtpk(st1[2 * s], st1[2 * s + 1]);
        }

        // build PV B-frags bq[kb]: P[kv0+kb*16+hi*8+e][q], e=0..7 (R14-verified)
        short8v bq[4];
        #pragma unroll
        for (int kb = 0; kb < 4; ++kb) {
            union { unsigned u[4]; short8v v; } bb;
            #pragma unroll
            for (int j = 0; j < 4; ++j) {
                const unsigned* Wb = (kb >> 1) ? W1 : W0;
                const int s0 = (j & 1) + 4 * (kb & 1);
                const unsigned own  = hi ? Wb[s0 + 2] : Wb[s0];
                const unsigned send = hi ? Wb[s0]     : Wb[s0 + 2];
                const unsigned rec  = (unsigned)__shfl_xor((int)send, 32);
                bb.u[j] = (j >> 1) ? (hi ? own : rec) : (hi ? rec : own);
            }
            bq[kb] = bb.v;
        }

        // O^T += V^T . P^T : two d-32 blocks x four kv-16 blocks
        __builtin_amdgcn_s_setprio(1);
        #pragma unroll
        for (int kb = 0; kb < 4; ++kb) {
            short8v vf0 = *(const short8v*)(vtp + (ktB ^ (kb << 5)));
            short8v vf1 = *(const short8v*)(vtp + (ktB ^ (kb << 5)) + 4096);
            oacc0 = mfma32(vf0, bq[kb], oacc0);
            oacc1 = mfma32(vf1, bq[kb], oacc1);
        }
        __builtin_amdgcn_s_setprio(0);

        __syncthreads();       // drains stage(t+1) vmcnt + protects Kt/Vt[cur]
        cur ^= 1;
    }
#undef STAGE

    // normalize + stage O into Kt region (dead), swizzled; then coalesced out
    const float inv = frcp(l_);
    char* Ob = (char*)Kt;
    const int qr = w * 32 + q;
    #pragma unroll
    for (int s = 0; s < 8; ++s) {
        const int d0a = 2 * (s & 1) + 8 * (s >> 1) + 4 * hi;        // db=0
        unsigned wa = cvtpk(oacc0[2 * s] * inv, oacc0[2 * s + 1] * inv);
        *(unsigned*)(Ob + qr * 128 + ((((d0a >> 3) ^ (qr & 7)) << 4) | ((2 * d0a) & 15))) = wa;
        const int d0b = d0a + 32;                                    // db=1
        unsigned wb = cvtpk(oacc1[2 * s] * inv, oacc1[2 * s + 1] * inv);
        *(unsigned*)(Ob + qr * 128 + ((((d0b >> 3) ^ (qr & 7)) << 4) | ((2 * d0b) & 15))) = wb;
    }
    __syncthreads();
    const int b = bh >> 4, h = bh & 15;
    #pragma unroll
    for (int t = 0; t < 4; ++t) {
        const int c = t * 256 + tid;
        const int qrow = c >> 3, ch = c & 7;
        short8v v = *(const short8v*)(Ob + qrow * 128 + ((ch ^ (qrow & 7)) << 4));
        *(short8v*)&Og[((size_t)(b * S_ + q0b + qrow)) * M_ + h * 64 + ch * 8] = v;
    }
}

// ---------------------------------------------------------------------------
// Fused residual-add + LayerNorm. X bf16, residual fp32; emits fp32 (+bf16).
// ---------------------------------------------------------------------------
template<int EMITB>
__global__ __launch_bounds__(256) void ln_k(
    const ushort* __restrict__ X, const float* __restrict__ Rz,
    const float* __restrict__ g, const float* __restrict__ be,
    float* __restrict__ outf, ushort* __restrict__ outb)
{
    __shared__ float red[8];
    const int row = blockIdx.x, tid = threadIdx.x;
    const int lane = tid & 63, w = tid >> 6;

    ushort4 xu = *(const ushort4*)&X[(size_t)row * M_ + tid * 4];
    float4 rr = ld4(Rz + (size_t)row * M_ + tid * 4);
    float4 x = make_float4(bf2f(xu.x) + rr.x, bf2f(xu.y) + rr.y,
                           bf2f(xu.z) + rr.z, bf2f(xu.w) + rr.w);

    float sm = x.x + x.y + x.z + x.w;
    #pragma unroll
    for (int off = 1; off < 64; off <<= 1) sm += __shfl_xor(sm, off);
    if (lane == 0) red[w] = sm;
    __syncthreads();
    const float mean = (red[0] + red[1] + red[2] + red[3]) * (1.f / M_);

    x.x -= mean; x.y -= mean; x.z -= mean; x.w -= mean;
    float vs = x.x * x.x + x.y * x.y + x.z * x.z + x.w * x.w;
    #pragma unroll
    for (int off = 1; off < 64; off <<= 1) vs += __shfl_xor(vs, off);
    if (lane == 0) red[4 + w] = vs;
    __syncthreads();
    const float var = (red[4] + red[5] + red[6] + red[7]) * (1.f / M_);
    const float rs = rsqrtf(var + 1e-5f);

    float4 gg = ld4(g + tid * 4), bb = ld4(be + tid * 4);
    float4 y = make_float4(x.x * rs * gg.x + bb.x, x.y * rs * gg.y + bb.y,
                           x.z * rs * gg.z + bb.z, x.w * rs * gg.w + bb.w);
    *(float4*)(outf + (size_t)row * M_ + tid * 4) = y;
    if (EMITB) {
        ushort4 ob = { f2bf(y.x), f2bf(y.y), f2bf(y.z), f2bf(y.w) };
        *(ushort4*)&outb[(size_t)row * M_ + tid * 4] = ob;
    }
}

// ---------------------------------------------------------------------------
extern "C" void kernel_launch(void* const* d_in, const int* in_sizes, int n_in,
                              void* d_out, int out_size, void* d_ws, size_t ws_size,
                              hipStream_t stream)
{
    const float* input = (const float*)d_in[0];
    const float* enc   = (const float*)d_in[1];
    const float* Wq1 = (const float*)d_in[2];  const float* bq1 = (const float*)d_in[3];
    const float* Wk1 = (const float*)d_in[4];  const float* bk1 = (const float*)d_in[5];
    const float* Wv1 = (const float*)d_in[6];  const float* bv1 = (const float*)d_in[7];
    const float* Wo1 = (const float*)d_in[8];  const float* bo1 = (const float*)d_in[9];
    const float* ln1g = (const float*)d_in[10]; const float* ln1b = (const float*)d_in[11];
    const float* Wq2 = (const float*)d_in[12]; const float* bq2 = (const float*)d_in[13];
    const float* Wk2 = (const float*)d_in[14]; const float* bk2 = (const float*)d_in[15];
    const float* Wv2 = (const float*)d_in[16]; const float* bv2 = (const float*)d_in[17];
    const float* Wo2 = (const float*)d_in[18]; const float* bo2 = (const float*)d_in[19];
    const float* ln2g = (const float*)d_in[20]; const float* ln2b = (const float*)d_in[21];
    const float* Wf1 = (const float*)d_in[22]; const float* bf1 = (const float*)d_in[23];
    const float* Wf2 = (const float*)d_in[24]; const float* bf2 = (const float*)d_in[25];
    const float* ln3g = (const float*)d_in[26]; const float* ln3b = (const float*)d_in[27];

    const float SC = 0.18033688011112042f;     // 0.125 * log2(e)

    char* W = (char*)d_ws;
    #define OFS(mb) ((void*)(W + (size_t)(mb) * 1024 * 1024))
    ushort* x0b    = (ushort*)OFS(0);
    ushort* encb   = (ushort*)OFS(8);
    ushort* WqkvT1 = (ushort*)OFS(16);
    ushort* Wo1T   = (ushort*)OFS(22);
    ushort* Wq2T   = (ushort*)OFS(24);
    ushort* WkvT2  = (ushort*)OFS(26);
    ushort* Wo2T   = (ushort*)OFS(30);
    ushort* Wf1T   = (ushort*)OFS(32);
    ushort* Wf2T   = (ushort*)OFS(36);
    float*  biasQKV1 = (float*)OFS(40);
    float*  biasKV2  = (float*)((char*)OFS(40) + 16384);
    float*  biasQ2   = (float*)((char*)OFS(40) + 32768);
    ushort* QKV1   = (ushort*)OFS(41);   // [3][B][H][S][D] (V region unused)
    ushort* VT1    = (ushort*)OFS(65);
    ushort* att1b  = (ushort*)OFS(73);
    ushort* o1b    = (ushort*)OFS(81);
    float*  out1f  = (float*)OFS(41);
    ushort* out1b  = (ushort*)OFS(57);
    ushort* Q2     = (ushort*)OFS(65);
    ushort* KV2    = (ushort*)OFS(73);   // [2][B][H][S][D] (V region unused)
    ushort* VT2    = (ushort*)OFS(0);
    ushort* att2b  = (ushort*)OFS(8);
    ushort* o2b    = (ushort*)OFS(65);
    float*  out2f  = (float*)OFS(73);
    ushort* out2b  = (ushort*)OFS(0);
    ushort* ff1b   = (ushort*)OFS(41);
    ushort* ff2b   = (ushort*)OFS(57);
    float*  out    = (float*)d_out;
    const size_t MAT = (size_t)B_ * H_ * S_ * D_;   // 4 Mi elements

    dim3 blk(256);

    // ---- prep (6 launches) ----
    cast2_k<<<8192, blk, 0, stream>>>(input, enc, x0b, encb);
    biasp_k<<<24, blk, 0, stream>>>(bq1, bk1, bv1, bk2, bv2, bq2, biasQKV1, SC);
    wtransH_k<<<dim3(2, 32, 96), blk, 0, stream>>>(Wq1, Wk1, Wv1, Wq2, Wk2, Wv2,
                                                   WqkvT1, Wq2T, WkvT2, SC);
    wtrans_k<<<dim3(32, 32, 2), blk, 0, stream>>>(Wo1, Wo2, Wo1T, Wo2T, 1024, 1024);
    wtrans_k<<<dim3(64, 32, 1), blk, 0, stream>>>(Wf1, Wf1, Wf1T, Wf1T, 1024, 2048);
    wtrans_k<<<dim3(32, 64, 1), blk, 0, stream>>>(Wf2, Wf2, Wf2T, Wf2T, 2048, 1024);

    // ---- masked self-attention ----
    gemm_bf16_k<128, 128, 64, 2, 0><<<dim3(24, 32), blk, 0, stream>>>(
        x0b, WqkvT1, biasQKV1, QKV1, VT1, 2, 3072, 1024);
    fattn_k<1><<<dim3(512), blk, 0, stream>>>(QKV1, QKV1 + MAT, VT1, att1b, S_);
    gemm_bf16_k<64, 64, 128, 1, 0><<<dim3(16, 64), blk, 0, stream>>>(
        att1b, Wo1T, bo1, o1b, nullptr, 9, 1024, 1024);
    ln_k<1><<<dim3(R_), blk, 0, stream>>>(o1b, input, ln1g, ln1b, out1f, out1b);

    // ---- cross-attention ----
    gemm_bf16_k<64, 64, 128, 2, 0><<<dim3(16, 64), blk, 0, stream>>>(
        out1b, Wq2T, biasQ2, Q2, nullptr, 9, 1024, 1024);
    gemm_bf16_k<128, 128, 64, 2, 0><<<dim3(16, 32), blk, 0, stream>>>(
        encb, WkvT2, biasKV2, KV2, VT2, 1, 2048, 1024);
    fattn_k<0><<<dim3(512), blk, 0, stream>>>(Q2, KV2, VT2, att2b, S_);
    gemm_bf16_k<64, 64, 128, 1, 0><<<dim3(16, 64), blk, 0, stream>>>(
        att2b, Wo2T, bo2, o2b, nullptr, 9, 1024, 1024);
    ln_k<1><<<dim3(R_), blk, 0, stream>>>(o2b, out1f, ln2g, ln2b, out2f, out2b);

    // ---- FFN ----
    gemm_bf16_k<128, 64, 64, 1, 1><<<dim3(32, 32), blk, 0, stream>>>(
        out2b, Wf1T, bf1, ff1b, nullptr, 9, 2048, 1024);
    gemm_bf16_k<64, 64, 128, 1, 0><<<dim3(16, 64), blk, 0, stream>>>(
        ff1b, Wf2T, bf2, ff2b, nullptr, 9, 1024, 2048);
    ln_k<0><<<dim3(R_), blk, 0, stream>>>(ff2b, out2f, ln3g, ln3b, out, nullptr);
    #undef OFS
}

// Round 19
// 302.607 us; speedup vs baseline: 1.0850x; 1.0158x over previous
//
#include <hip/hip_runtime.h>
#include <math.h>

#define B_ 2
#define S_ 2048
#define M_ 1024
#define H_ 16
#define D_ 64
#define R_ (B_*S_)          // 4096 rows

typedef __attribute__((ext_vector_type(8))) short short8v;    // 8 bf16 = 4 VGPR
typedef __attribute__((ext_vector_type(4))) float float4v;
typedef __attribute__((ext_vector_type(16))) float float16v; // 32x32 C/D

__device__ __forceinline__ float4 ld4(const float* p) {
    return *(const float4* __restrict__)p;
}

__device__ __forceinline__ ushort f2bf(float f) {            // RNE
    union { float f; unsigned u; } x; x.f = f;
    unsigned u = x.u + 0x7fffu + ((x.u >> 16) & 1u);
    return (ushort)(u >> 16);
}
__device__ __forceinline__ float bf2f(ushort s) {
    union { unsigned u; float f; } x; x.u = ((unsigned)s) << 16; return x.f;
}
__device__ __forceinline__ unsigned cvtpk(float lo, float hi) {
    unsigned r;
    asm("v_cvt_pk_bf16_f32 %0, %1, %2" : "=v"(r) : "v"(lo), "v"(hi));
    return r;
}
#if __has_builtin(__builtin_amdgcn_exp2f)
__device__ __forceinline__ float fexp2(float x) { return __builtin_amdgcn_exp2f(x); }
#else
__device__ __forceinline__ float fexp2(float x) { return exp2f(x); }
#endif
#if __has_builtin(__builtin_amdgcn_rcpf)
__device__ __forceinline__ float frcp(float x) { return __builtin_amdgcn_rcpf(x); }
#else
__device__ __forceinline__ float frcp(float x) { return 1.f / x; }
#endif
__device__ __forceinline__ float4v mfma16(short8v a, short8v b, float4v c) {
    return __builtin_amdgcn_mfma_f32_16x16x32_bf16(a, b, c, 0, 0, 0);
}
__device__ __forceinline__ float16v mfma32(short8v a, short8v b, float16v c) {
    return __builtin_amdgcn_mfma_f32_32x32x16_bf16(a, b, c, 0, 0, 0);
}
__device__ __forceinline__ void glds16(const void* g, void* l) {
    __builtin_amdgcn_global_load_lds(
        (const __attribute__((address_space(1))) void*)g,
        (__attribute__((address_space(3))) void*)l, 16, 0, 0);
}

// ---------------------------------------------------------------------------
// prep kernels (fused)
// ---------------------------------------------------------------------------
__global__ __launch_bounds__(256) void cast2_k(const float* __restrict__ a,
                                               const float* __restrict__ b,
                                               ushort* __restrict__ oa,
                                               ushort* __restrict__ ob) {
    size_t u = (size_t)blockIdx.x * 256 + threadIdx.x;       // float4 units
    const float* in; ushort* out;
    if (u < (1u << 20)) { in = a; out = oa; }
    else { u -= (1u << 20); in = b; out = ob; }
    float4 v = ld4(in + u * 4);
    ushort4 o = { f2bf(v.x), f2bf(v.y), f2bf(v.z), f2bf(v.w) };
    *(ushort4*)&out[u * 4] = o;
}

__global__ __launch_bounds__(256) void biasp_k(
    const float* __restrict__ q1, const float* __restrict__ k1,
    const float* __restrict__ v1, const float* __restrict__ k2,
    const float* __restrict__ v2, const float* __restrict__ q2,
    float* __restrict__ dst, float SCv) {
    const int seg = blockIdx.x >> 2;
    const int li = (blockIdx.x & 3) * 256 + threadIdx.x;
    const float* s; int off; float sc;
    switch (seg) {
        case 0: s = q1; off = 0;    sc = SCv; break;
        case 1: s = k1; off = 1024; sc = 1.f; break;
        case 2: s = v1; off = 2048; sc = 1.f; break;
        case 3: s = k2; off = 4096; sc = 1.f; break;
        case 4: s = v2; off = 5120; sc = 1.f; break;
        default: s = q2; off = 8192; sc = SCv; break;
    }
    dst[off + li] = s[li] * sc;
}

__global__ __launch_bounds__(256) void wtransH_k(
    const float* __restrict__ s0, const float* __restrict__ s1,
    const float* __restrict__ s2, const float* __restrict__ s3,
    const float* __restrict__ s4, const float* __restrict__ s5,
    ushort* __restrict__ oQKV1, ushort* __restrict__ oQ2,
    ushort* __restrict__ oKV2, float SCv) {
    __shared__ float t[32][33];
    const int z = blockIdx.z, s6 = z >> 4, h = z & 15;
    const float* srcs[6] = { s0, s1, s2, s3, s4, s5 };
    const float* ib = srcs[s6] + (size_t)h * 1024 * 64;
    ushort* ob;
    if (s6 < 3)       ob = oQKV1 + (size_t)s6 * (1024 * 1024) + (size_t)h * (64 * 1024);
    else if (s6 == 3) ob = oQ2 + (size_t)h * (64 * 1024);
    else              ob = oKV2 + (size_t)(s6 - 4) * (1024 * 1024) + (size_t)h * (64 * 1024);
    const float scale = (s6 == 0 || s6 == 3) ? SCv : 1.f;
    const int k0 = blockIdx.y * 32, n0 = blockIdx.x * 32;
    const int tx = threadIdx.x & 31, ty = threadIdx.x >> 5;
    #pragma unroll
    for (int i = 0; i < 4; ++i)
        t[ty + i * 8][tx] = ib[(size_t)(k0 + ty + i * 8) * 64 + n0 + tx];
    __syncthreads();
    #pragma unroll
    for (int i = 0; i < 4; ++i)
        ob[(size_t)(n0 + ty + i * 8) * 1024 + k0 + tx] = f2bf(t[tx][ty + i * 8] * scale);
}

__global__ __launch_bounds__(256) void wtrans_k(const float* __restrict__ inA,
                                                const float* __restrict__ inB,
                                                ushort* __restrict__ outA,
                                                ushort* __restrict__ outB,
                                                int K, int N) {
    __shared__ float t[32][33];
    const float* ib = blockIdx.z ? inB : inA;
    ushort* ob = blockIdx.z ? outB : outA;
    const int k0 = blockIdx.y * 32, n0 = blockIdx.x * 32;
    const int tx = threadIdx.x & 31, ty = threadIdx.x >> 5;
    #pragma unroll
    for (int i = 0; i < 4; ++i)
        t[ty + i * 8][tx] = ib[(size_t)(k0 + ty + i * 8) * N + n0 + tx];
    __syncthreads();
    #pragma unroll
    for (int i = 0; i < 4; ++i)
        ob[(size_t)(n0 + ty + i * 8) * K + k0 + tx] = f2bf(t[tx][ty + i * 8]);
}

// ---------------------------------------------------------------------------
// bf16 MFMA GEMM, TMxTN tile, BK templated, 256 thr (4 waves 2x2). XOR-swizzled.
// ---------------------------------------------------------------------------
template<int TM, int TN, int BK, int OUTMODE, int ACT>
__global__ __launch_bounds__(256) void gemm_bf16_k(
    const ushort* __restrict__ A, const ushort* __restrict__ Bt,
    const float* __restrict__ bias, void* __restrict__ C,
    ushort* __restrict__ Cvt, int matV, int N, int K)
{
    constexpr int NI = TM / 32;
    constexpr int NJ = TN / 32;
    constexpr int KS = BK / 32;
    constexpr int CHR = BK / 8;                 // 16B chunks per row
    __shared__ __align__(16) ushort At[TM * BK];
    __shared__ __align__(16) ushort Bts[TN * BK];
    const int tid = threadIdx.x, lane = tid & 63, w = tid >> 6;
    const int wm = w >> 1, wn = w & 1;
    const int q = lane & 15, g = lane >> 4;
    const int m0 = blockIdx.y * TM, n0 = blockIdx.x * TN;

    float4v acc[NI][NJ];
    #pragma unroll
    for (int i = 0; i < NI; ++i)
        #pragma unroll
        for (int j = 0; j < NJ; ++j) acc[i][j] = (float4v){0.f, 0.f, 0.f, 0.f};

    for (int k0 = 0; k0 < K; k0 += BK) {
        #pragma unroll
        for (int t = 0; t < TM * CHR / 256; ++t) {
            const int cb = (w * (TM * CHR / 256) + t) * 64;
            const int c = cb + lane;
            const int row = c / CHR, kc = (c % CHR) ^ (row & (CHR - 1));
            glds16(&A[(size_t)(m0 + row) * K + k0 + kc * 8], &At[cb * 8]);
        }
        #pragma unroll
        for (int t = 0; t < TN * CHR / 256; ++t) {
            const int cb = (w * (TN * CHR / 256) + t) * 64;
            const int c = cb + lane;
            const int row = c / CHR, kc = (c % CHR) ^ (row & (CHR - 1));
            glds16(&Bt[(size_t)(n0 + row) * K + k0 + kc * 8], &Bts[cb * 8]);
        }
        __syncthreads();
        #pragma unroll
        for (int ks = 0; ks < KS; ++ks) {
            short8v af[NI], bf[NJ];
            #pragma unroll
            for (int i = 0; i < NI; ++i) {
                const int row = wm * (TM / 2) + i * 16 + q;
                af[i] = *(const short8v*)((const char*)At +
                        row * (BK * 2) + (((ks * 4 + g) ^ (q & (CHR - 1))) << 4));
            }
            #pragma unroll
            for (int j = 0; j < NJ; ++j) {
                const int row = wn * (TN / 2) + j * 16 + q;
                bf[j] = *(const short8v*)((const char*)Bts +
                        row * (BK * 2) + (((ks * 4 + g) ^ (q & (CHR - 1))) << 4));
            }
            #pragma unroll
            for (int i = 0; i < NI; ++i)
                #pragma unroll
                for (int j = 0; j < NJ; ++j)
                    acc[i][j] = mfma16(af[i], bf[j], acc[i][j]);
        }
        __syncthreads();
    }

    float bcol[NJ];
    #pragma unroll
    for (int j = 0; j < NJ; ++j) bcol[j] = bias[n0 + wn * (TN / 2) + j * 16 + q];

    #pragma unroll
    for (int i = 0; i < NI; ++i) {
        const int rowg0 = m0 + wm * (TM / 2) + i * 16 + g * 4;
        #pragma unroll
        for (int j = 0; j < NJ; ++j) {
            const int colg = n0 + wn * (TN / 2) + j * 16 + q;
            float v[4];
            #pragma unroll
            for (int r = 0; r < 4; ++r) {
                v[r] = acc[i][j][r] + bcol[j];
                if (ACT) v[r] = fmaxf(v[r], 0.f);
            }
            if (OUTMODE == 0) {
                #pragma unroll
                for (int r = 0; r < 4; ++r)
                    ((float*)C)[(size_t)(rowg0 + r) * N + colg] = v[r];
            } else if (OUTMODE == 1) {
                #pragma unroll
                for (int r = 0; r < 4; ++r)
                    ((ushort*)C)[(size_t)(rowg0 + r) * N + colg] = f2bf(v[r]);
            } else {
                const int mat = colg >> 10, h = (colg >> 6) & 15, d = colg & 63;
                const int bb = rowg0 >> 11, s0 = rowg0 & 2047;
                if (mat == matV) {   // V -> transposed layout [bh][d][s]
                    uint2 pv;
                    pv.x = cvtpk(v[0], v[1]);
                    pv.y = cvtpk(v[2], v[3]);
                    *(uint2*)&Cvt[((size_t)(bb * H_ + h) * D_ + d) * S_ + s0] = pv;
                } else {
                    #pragma unroll
                    for (int r = 0; r < 4; ++r)
                        ((ushort*)C)[((((size_t)(mat * B_ + bb) * H_ + h) * S_) + s0 + r) * D_ + d] = f2bf(v[r]);
                }
            }
        }
    }
}

// ---------------------------------------------------------------------------
// Flash attention, 32x32x16 bf16 MFMA, swapped form, STATIC-MAX softmax.
// R16-measured-best: 256 thr = 4 waves, q-tile 128, kv-tile 64 dbuf,
// P = exp2(s - 24) exact; grid 512. 57.4 us/dispatch.
// ---------------------------------------------------------------------------
template<int CAUSAL>
__global__ __launch_bounds__(256, 3) void fattn_k(
    const ushort* __restrict__ Qg, const ushort* __restrict__ Kg,
    const ushort* __restrict__ VTg, ushort* __restrict__ Og, int Skv)
{
    __shared__ __align__(16) ushort Kt[2][64 * 64];   // [kv][d] swizzled, 8 KB x2
    __shared__ __align__(16) ushort Vt[2][64 * 64];   // [d][kv] swizzled, 8 KB x2
    const int tid = threadIdx.x, lane = tid & 63, w = tid >> 6;   // w 0..3
    const int q = lane & 31, hi = lane >> 5;
    const int id = blockIdx.x;
    const int bh = id & 31;
    const int t_ = id >> 5;
    const int qb = CAUSAL ? ((t_ < 8) ? (15 - t_) : (t_ - 8)) : t_;
    const int q0b = qb * 128;
    const int q0w = q0b + w * 32;
    const float MB = 24.f;                            // static exponent bias

    // staging sources (2 chunks per thread per matrix), pre-swizzled
    const int c0 = tid, c1 = tid + 256;
    const ushort* kS0 = Kg + ((size_t)bh * Skv + (c0 >> 3)) * 64 + (((c0 & 7) ^ ((c0 >> 3) & 7)) * 8);
    const ushort* kS1 = Kg + ((size_t)bh * Skv + (c1 >> 3)) * 64 + (((c1 & 7) ^ ((c1 >> 3) & 7)) * 8);
    const ushort* vS0 = VTg + ((size_t)bh * 64 + (c0 >> 3)) * (size_t)Skv + (((c0 & 7) ^ ((c0 >> 3) & 7)) * 8);
    const ushort* vS1 = VTg + ((size_t)bh * 64 + (c1 >> 3)) * (size_t)Skv + (((c1 & 7) ^ ((c1 >> 3) & 7)) * 8);

#define STAGE(nb) do { \
        glds16(kS0, &Kt[nb][(w * 64) * 8]); \
        glds16(kS1, &Kt[nb][(256 + w * 64) * 8]); \
        glds16(vS0, &Vt[nb][(w * 64) * 8]); \
        glds16(vS1, &Vt[nb][(256 + w * 64) * 8]); \
        kS0 += 64 * 64; kS1 += 64 * 64; vS0 += 64; vS1 += 64; } while (0)

    // Q B-fragments (Q pre-scaled by 0.125*log2e): B[k=d][col=q], k=ki*16+hi*8+e
    short8v qf[4];
    #pragma unroll
    for (int ki = 0; ki < 4; ++ki)
        qf[ki] = *(const short8v*)&Qg[((size_t)bh * S_ + q0w + q) * 64 + ki * 16 + hi * 8];

    // LDS byte base: row=q (+b2*4096), chunk=(2ki+hi)^(q&7) => base ^ (ki<<5)
    const int ktB = q * 128 + ((hi ^ (q & 7)) << 4);

    float16v oacc0, oacc1;
    #pragma unroll
    for (int r = 0; r < 16; ++r) { oacc0[r] = 0.f; oacc1[r] = 0.f; }
    float l_ = 0.f;

    const int ktiles = CAUSAL ? (2 * qb + 2) : (Skv >> 6);
    int cur = 0;

    STAGE(0);
    __syncthreads();

    for (int kt = 0; kt < ktiles; ++kt) {
        if (kt + 1 < ktiles) STAGE(cur ^ 1);          // issue-early
        const char* ktp = (const char*)Kt + cur * 8192;
        const char* vtp = (const char*)Vt + cur * 8192;
        const int kv0 = kt * 64;

        // S^T = K . Q^T : two kv-32 blocks, K=16 chunks over d
        float16v st0, st1;
        #pragma unroll
        for (int r = 0; r < 16; ++r) { st0[r] = 0.f; st1[r] = 0.f; }
        __builtin_amdgcn_s_setprio(1);
        #pragma unroll
        for (int ki = 0; ki < 4; ++ki) {
            short8v kf0 = *(const short8v*)(ktp + (ktB ^ (ki << 5)));
            short8v kf1 = *(const short8v*)(ktp + (ktB ^ (ki << 5)) + 4096);
            st0 = mfma32(kf0, qf[ki], st0);
            st1 = mfma32(kf1, qf[ki], st1);
        }
        __builtin_amdgcn_s_setprio(0);

        if (CAUSAL && kv0 + 63 > q0b) {               // diagonal tiles only
            const int qg_ = q0w + q;
            #pragma unroll
            for (int r = 0; r < 16; ++r) {
                const int row = (r & 3) + 8 * (r >> 2) + 4 * hi;
                if (kv0 + row > qg_)      st0[r] = -1e9f;
                if (kv0 + 32 + row > qg_) st1[r] = -1e9f;
            }
        }

        // STATIC-MAX: P = exp2(s - MB). exact (scale cancels in O = PV / l).
        float ts[16];
        #pragma unroll
        for (int r = 0; r < 16; ++r) {
            st0[r] = fexp2(st0[r] - MB);
            st1[r] = fexp2(st1[r] - MB);
            ts[r] = st0[r] + st1[r];
        }
        #pragma unroll
        for (int off = 8; off >= 1; off >>= 1)
            #pragma unroll
            for (int i = 0; i < 8; ++i)
                if (i < off) ts[i] += ts[i + off];
        l_ += ts[0] + __shfl_xor(ts[0], 32);

        // pack P to bf16 words: W[b][s] = rows (2s,2s+1) of kv-block b (lane's set)
        unsigned W0[8], W1[8];
        #pragma unroll
        for (int s = 0; s < 8; ++s) {
            W0[s] = cvtpk(st0[2 * s], st0[2 * s + 1]);
            W1[s] = cvtpk(st1[2 * s], st1[2 * s + 1]);
        }

        // build PV B-frags bq[kb]: P[kv0+kb*16+hi*8+e][q], e=0..7 (R14-verified)
        short8v bq[4];
        #pragma unroll
        for (int kb = 0; kb < 4; ++kb) {
            union { unsigned u[4]; short8v v; } bb;
            #pragma unroll
            for (int j = 0; j < 4; ++j) {
                const unsigned* Wb = (kb >> 1) ? W1 : W0;
                const int s0 = (j & 1) + 4 * (kb & 1);
                const unsigned own  = hi ? Wb[s0 + 2] : Wb[s0];
                const unsigned send = hi ? Wb[s0]     : Wb[s0 + 2];
                const unsigned rec  = (unsigned)__shfl_xor((int)send, 32);
                bb.u[j] = (j >> 1) ? (hi ? own : rec) : (hi ? rec : own);
            }
            bq[kb] = bb.v;
        }

        // O^T += V^T . P^T : two d-32 blocks x four kv-16 blocks
        __builtin_amdgcn_s_setprio(1);
        #pragma unroll
        for (int kb = 0; kb < 4; ++kb) {
            short8v vf0 = *(const short8v*)(vtp + (ktB ^ (kb << 5)));
            short8v vf1 = *(const short8v*)(vtp + (ktB ^ (kb << 5)) + 4096);
            oacc0 = mfma32(vf0, bq[kb], oacc0);
            oacc1 = mfma32(vf1, bq[kb], oacc1);
        }
        __builtin_amdgcn_s_setprio(0);

        __syncthreads();       // drains stage(t+1) vmcnt + protects Kt/Vt[cur]
        cur ^= 1;
    }
#undef STAGE

    // normalize + stage O into Kt region (dead), swizzled; then coalesced out
    const float inv = frcp(l_);
    char* Ob = (char*)Kt;
    const int qr = w * 32 + q;
    #pragma unroll
    for (int s = 0; s < 8; ++s) {
        const int d0a = 2 * (s & 1) + 8 * (s >> 1) + 4 * hi;        // db=0
        unsigned wa = cvtpk(oacc0[2 * s] * inv, oacc0[2 * s + 1] * inv);
        *(unsigned*)(Ob + qr * 128 + ((((d0a >> 3) ^ (qr & 7)) << 4) | ((2 * d0a) & 15))) = wa;
        const int d0b = d0a + 32;                                    // db=1
        unsigned wb = cvtpk(oacc1[2 * s] * inv, oacc1[2 * s + 1] * inv);
        *(unsigned*)(Ob + qr * 128 + ((((d0b >> 3) ^ (qr & 7)) << 4) | ((2 * d0b) & 15))) = wb;
    }
    __syncthreads();
    const int b = bh >> 4, h = bh & 15;
    #pragma unroll
    for (int t = 0; t < 4; ++t) {
        const int c = t * 256 + tid;
        const int qrow = c >> 3, ch = c & 7;
        short8v v = *(const short8v*)(Ob + qrow * 128 + ((ch ^ (qrow & 7)) << 4));
        *(short8v*)&Og[((size_t)(b * S_ + q0b + qrow)) * M_ + h * 64 + ch * 8] = v;
    }
}

// ---------------------------------------------------------------------------
// Fused residual-add + LayerNorm. X bf16, residual fp32; emits fp32 (+bf16).
// ---------------------------------------------------------------------------
template<int EMITB>
__global__ __launch_bounds__(256) void ln_k(
    const ushort* __restrict__ X, const float* __restrict__ Rz,
    const float* __restrict__ g, const float* __restrict__ be,
    float* __restrict__ outf, ushort* __restrict__ outb)
{
    __shared__ float red[8];
    const int row = blockIdx.x, tid = threadIdx.x;
    const int lane = tid & 63, w = tid >> 6;

    ushort4 xu = *(const ushort4*)&X[(size_t)row * M_ + tid * 4];
    float4 rr = ld4(Rz + (size_t)row * M_ + tid * 4);
    float4 x = make_float4(bf2f(xu.x) + rr.x, bf2f(xu.y) + rr.y,
                           bf2f(xu.z) + rr.z, bf2f(xu.w) + rr.w);

    float sm = x.x + x.y + x.z + x.w;
    #pragma unroll
    for (int off = 1; off < 64; off <<= 1) sm += __shfl_xor(sm, off);
    if (lane == 0) red[w] = sm;
    __syncthreads();
    const float mean = (red[0] + red[1] + red[2] + red[3]) * (1.f / M_);

    x.x -= mean; x.y -= mean; x.z -= mean; x.w -= mean;
    float vs = x.x * x.x + x.y * x.y + x.z * x.z + x.w * x.w;
    #pragma unroll
    for (int off = 1; off < 64; off <<= 1) vs += __shfl_xor(vs, off);
    if (lane == 0) red[4 + w] = vs;
    __syncthreads();
    const float var = (red[4] + red[5] + red[6] + red[7]) * (1.f / M_);
    const float rs = rsqrtf(var + 1e-5f);

    float4 gg = ld4(g + tid * 4), bb = ld4(be + tid * 4);
    float4 y = make_float4(x.x * rs * gg.x + bb.x, x.y * rs * gg.y + bb.y,
                           x.z * rs * gg.z + bb.z, x.w * rs * gg.w + bb.w);
    *(float4*)(outf + (size_t)row * M_ + tid * 4) = y;
    if (EMITB) {
        ushort4 ob = { f2bf(y.x), f2bf(y.y), f2bf(y.z), f2bf(y.w) };
        *(ushort4*)&outb[(size_t)row * M_ + tid * 4] = ob;
    }
}

// ---------------------------------------------------------------------------
extern "C" void kernel_launch(void* const* d_in, const int* in_sizes, int n_in,
                              void* d_out, int out_size, void* d_ws, size_t ws_size,
                              hipStream_t stream)
{
    const float* input = (const float*)d_in[0];
    const float* enc   = (const float*)d_in[1];
    const float* Wq1 = (const float*)d_in[2];  const float* bq1 = (const float*)d_in[3];
    const float* Wk1 = (const float*)d_in[4];  const float* bk1 = (const float*)d_in[5];
    const float* Wv1 = (const float*)d_in[6];  const float* bv1 = (const float*)d_in[7];
    const float* Wo1 = (const float*)d_in[8];  const float* bo1 = (const float*)d_in[9];
    const float* ln1g = (const float*)d_in[10]; const float* ln1b = (const float*)d_in[11];
    const float* Wq2 = (const float*)d_in[12]; const float* bq2 = (const float*)d_in[13];
    const float* Wk2 = (const float*)d_in[14]; const float* bk2 = (const float*)d_in[15];
    const float* Wv2 = (const float*)d_in[16]; const float* bv2 = (const float*)d_in[17];
    const float* Wo2 = (const float*)d_in[18]; const float* bo2 = (const float*)d_in[19];
    const float* ln2g = (const float*)d_in[20]; const float* ln2b = (const float*)d_in[21];
    const float* Wf1 = (const float*)d_in[22]; const float* bf1 = (const float*)d_in[23];
    const float* Wf2 = (const float*)d_in[24]; const float* bf2 = (const float*)d_in[25];
    const float* ln3g = (const float*)d_in[26]; const float* ln3b = (const float*)d_in[27];

    const float SC = 0.18033688011112042f;     // 0.125 * log2(e)

    char* W = (char*)d_ws;
    #define OFS(mb) ((void*)(W + (size_t)(mb) * 1024 * 1024))
    ushort* x0b    = (ushort*)OFS(0);
    ushort* encb   = (ushort*)OFS(8);
    ushort* WqkvT1 = (ushort*)OFS(16);
    ushort* Wo1T   = (ushort*)OFS(22);
    ushort* Wq2T   = (ushort*)OFS(24);
    ushort* WkvT2  = (ushort*)OFS(26);
    ushort* Wo2T   = (ushort*)OFS(30);
    ushort* Wf1T   = (ushort*)OFS(32);
    ushort* Wf2T   = (ushort*)OFS(36);
    float*  biasQKV1 = (float*)OFS(40);
    float*  biasKV2  = (float*)((char*)OFS(40) + 16384);
    float*  biasQ2   = (float*)((char*)OFS(40) + 32768);
    ushort* QKV1   = (ushort*)OFS(41);   // [3][B][H][S][D] (V region unused)
    ushort* VT1    = (ushort*)OFS(65);
    ushort* att1b  = (ushort*)OFS(73);
    ushort* o1b    = (ushort*)OFS(81);
    float*  out1f  = (float*)OFS(41);
    ushort* out1b  = (ushort*)OFS(57);
    ushort* Q2     = (ushort*)OFS(65);
    ushort* KV2    = (ushort*)OFS(73);   // [2][B][H][S][D] (V region unused)
    ushort* VT2    = (ushort*)OFS(0);
    ushort* att2b  = (ushort*)OFS(8);
    ushort* o2b    = (ushort*)OFS(65);
    float*  out2f  = (float*)OFS(73);
    ushort* out2b  = (ushort*)OFS(0);
    ushort* ff1b   = (ushort*)OFS(41);
    ushort* ff2b   = (ushort*)OFS(57);
    float*  out    = (float*)d_out;
    const size_t MAT = (size_t)B_ * H_ * S_ * D_;   // 4 Mi elements

    dim3 blk(256);

    // ---- prep (6 launches) ----
    cast2_k<<<8192, blk, 0, stream>>>(input, enc, x0b, encb);
    biasp_k<<<24, blk, 0, stream>>>(bq1, bk1, bv1, bk2, bv2, bq2, biasQKV1, SC);
    wtransH_k<<<dim3(2, 32, 96), blk, 0, stream>>>(Wq1, Wk1, Wv1, Wq2, Wk2, Wv2,
                                                   WqkvT1, Wq2T, WkvT2, SC);
    wtrans_k<<<dim3(32, 32, 2), blk, 0, stream>>>(Wo1, Wo2, Wo1T, Wo2T, 1024, 1024);
    wtrans_k<<<dim3(64, 32, 1), blk, 0, stream>>>(Wf1, Wf1, Wf1T, Wf1T, 1024, 2048);
    wtrans_k<<<dim3(32, 64, 1), blk, 0, stream>>>(Wf2, Wf2, Wf2T, Wf2T, 2048, 1024);

    // ---- masked self-attention ----
    gemm_bf16_k<128, 128, 64, 2, 0><<<dim3(24, 32), blk, 0, stream>>>(
        x0b, WqkvT1, biasQKV1, QKV1, VT1, 2, 3072, 1024);
    fattn_k<1><<<dim3(512), blk, 0, stream>>>(QKV1, QKV1 + MAT, VT1, att1b, S_);
    gemm_bf16_k<64, 64, 64, 1, 0><<<dim3(16, 64), blk, 0, stream>>>(
        att1b, Wo1T, bo1, o1b, nullptr, 9, 1024, 1024);
    ln_k<1><<<dim3(R_), blk, 0, stream>>>(o1b, input, ln1g, ln1b, out1f, out1b);

    // ---- cross-attention ----
    gemm_bf16_k<64, 64, 64, 2, 0><<<dim3(16, 64), blk, 0, stream>>>(
        out1b, Wq2T, biasQ2, Q2, nullptr, 9, 1024, 1024);
    gemm_bf16_k<128, 128, 64, 2, 0><<<dim3(16, 32), blk, 0, stream>>>(
        encb, WkvT2, biasKV2, KV2, VT2, 1, 2048, 1024);
    fattn_k<0><<<dim3(512), blk, 0, stream>>>(Q2, KV2, VT2, att2b, S_);
    gemm_bf16_k<64, 64, 64, 1, 0><<<dim3(16, 64), blk, 0, stream>>>(
        att2b, Wo2T, bo2, o2b, nullptr, 9, 1024, 1024);
    ln_k<1><<<dim3(R_), blk, 0, stream>>>(o2b, out1f, ln2g, ln2b, out2f, out2b);

    // ---- FFN ----
    gemm_bf16_k<128, 64, 64, 1, 1><<<dim3(32, 32), blk, 0, stream>>>(
        out2b, Wf1T, bf1, ff1b, nullptr, 9, 2048, 1024);
    gemm_bf16_k<64, 64, 64, 1, 0><<<dim3(16, 64), blk, 0, stream>>>(
        ff1b, Wf2T, bf2, ff2b, nullptr, 9, 1024, 2048);
    ln_k<0><<<dim3(R_), blk, 0, stream>>>(ff2b, out2f, ln3g, ln3b, out, nullptr);
    #undef OFS
}

// Round 20
// 298.191 us; speedup vs baseline: 1.1011x; 1.0148x over previous
//
#include <hip/hip_runtime.h>
#include <math.h>

#define B_ 2
#define S_ 2048
#define M_ 1024
#define H_ 16
#define D_ 64
#define R_ (B_*S_)          // 4096 rows

typedef __attribute__((ext_vector_type(8))) short short8v;    // 8 bf16 = 4 VGPR
typedef __attribute__((ext_vector_type(4))) float float4v;
typedef __attribute__((ext_vector_type(16))) float float16v; // 32x32 C/D

__device__ __forceinline__ float4 ld4(const float* p) {
    return *(const float4* __restrict__)p;
}

__device__ __forceinline__ ushort f2bf(float f) {            // RNE
    union { float f; unsigned u; } x; x.f = f;
    unsigned u = x.u + 0x7fffu + ((x.u >> 16) & 1u);
    return (ushort)(u >> 16);
}
__device__ __forceinline__ float bf2f(ushort s) {
    union { unsigned u; float f; } x; x.u = ((unsigned)s) << 16; return x.f;
}
__device__ __forceinline__ unsigned cvtpk(float lo, float hi) {
    unsigned r;
    asm("v_cvt_pk_bf16_f32 %0, %1, %2" : "=v"(r) : "v"(lo), "v"(hi));
    return r;
}
#if __has_builtin(__builtin_amdgcn_exp2f)
__device__ __forceinline__ float fexp2(float x) { return __builtin_amdgcn_exp2f(x); }
#else
__device__ __forceinline__ float fexp2(float x) { return exp2f(x); }
#endif
#if __has_builtin(__builtin_amdgcn_rcpf)
__device__ __forceinline__ float frcp(float x) { return __builtin_amdgcn_rcpf(x); }
#else
__device__ __forceinline__ float frcp(float x) { return 1.f / x; }
#endif
__device__ __forceinline__ float4v mfma16(short8v a, short8v b, float4v c) {
    return __builtin_amdgcn_mfma_f32_16x16x32_bf16(a, b, c, 0, 0, 0);
}
__device__ __forceinline__ float16v mfma32(short8v a, short8v b, float16v c) {
    return __builtin_amdgcn_mfma_f32_32x32x16_bf16(a, b, c, 0, 0, 0);
}
__device__ __forceinline__ void glds16(const void* g, void* l) {
    __builtin_amdgcn_global_load_lds(
        (const __attribute__((address_space(1))) void*)g,
        (__attribute__((address_space(3))) void*)l, 16, 0, 0);
}

// ---------------------------------------------------------------------------
// prep kernels (fused)
// ---------------------------------------------------------------------------
__global__ __launch_bounds__(256) void cast2_k(const float* __restrict__ a,
                                               const float* __restrict__ b,
                                               ushort* __restrict__ oa,
                                               ushort* __restrict__ ob) {
    size_t u = (size_t)blockIdx.x * 256 + threadIdx.x;       // float4 units
    const float* in; ushort* out;
    if (u < (1u << 20)) { in = a; out = oa; }
    else { u -= (1u << 20); in = b; out = ob; }
    float4 v = ld4(in + u * 4);
    ushort4 o = { f2bf(v.x), f2bf(v.y), f2bf(v.z), f2bf(v.w) };
    *(ushort4*)&out[u * 4] = o;
}

__global__ __launch_bounds__(256) void biasp_k(
    const float* __restrict__ q1, const float* __restrict__ k1,
    const float* __restrict__ v1, const float* __restrict__ k2,
    const float* __restrict__ v2, const float* __restrict__ q2,
    float* __restrict__ dst, float SCv) {
    const int seg = blockIdx.x >> 2;
    const int li = (blockIdx.x & 3) * 256 + threadIdx.x;
    const float* s; int off; float sc;
    switch (seg) {
        case 0: s = q1; off = 0;    sc = SCv; break;
        case 1: s = k1; off = 1024; sc = 1.f; break;
        case 2: s = v1; off = 2048; sc = 1.f; break;
        case 3: s = k2; off = 4096; sc = 1.f; break;
        case 4: s = v2; off = 5120; sc = 1.f; break;
        default: s = q2; off = 8192; sc = SCv; break;
    }
    dst[off + li] = s[li] * sc;
}

__global__ __launch_bounds__(256) void wtransH_k(
    const float* __restrict__ s0, const float* __restrict__ s1,
    const float* __restrict__ s2, const float* __restrict__ s3,
    const float* __restrict__ s4, const float* __restrict__ s5,
    ushort* __restrict__ oQKV1, ushort* __restrict__ oQ2,
    ushort* __restrict__ oKV2, float SCv) {
    __shared__ float t[32][33];
    const int z = blockIdx.z, s6 = z >> 4, h = z & 15;
    const float* srcs[6] = { s0, s1, s2, s3, s4, s5 };
    const float* ib = srcs[s6] + (size_t)h * 1024 * 64;
    ushort* ob;
    if (s6 < 3)       ob = oQKV1 + (size_t)s6 * (1024 * 1024) + (size_t)h * (64 * 1024);
    else if (s6 == 3) ob = oQ2 + (size_t)h * (64 * 1024);
    else              ob = oKV2 + (size_t)(s6 - 4) * (1024 * 1024) + (size_t)h * (64 * 1024);
    const float scale = (s6 == 0 || s6 == 3) ? SCv : 1.f;
    const int k0 = blockIdx.y * 32, n0 = blockIdx.x * 32;
    const int tx = threadIdx.x & 31, ty = threadIdx.x >> 5;
    #pragma unroll
    for (int i = 0; i < 4; ++i)
        t[ty + i * 8][tx] = ib[(size_t)(k0 + ty + i * 8) * 64 + n0 + tx];
    __syncthreads();
    #pragma unroll
    for (int i = 0; i < 4; ++i)
        ob[(size_t)(n0 + ty + i * 8) * 1024 + k0 + tx] = f2bf(t[tx][ty + i * 8] * scale);
}

__global__ __launch_bounds__(256) void wtrans_k(const float* __restrict__ inA,
                                                const float* __restrict__ inB,
                                                ushort* __restrict__ outA,
                                                ushort* __restrict__ outB,
                                                int K, int N) {
    __shared__ float t[32][33];
    const float* ib = blockIdx.z ? inB : inA;
    ushort* ob = blockIdx.z ? outB : outA;
    const int k0 = blockIdx.y * 32, n0 = blockIdx.x * 32;
    const int tx = threadIdx.x & 31, ty = threadIdx.x >> 5;
    #pragma unroll
    for (int i = 0; i < 4; ++i)
        t[ty + i * 8][tx] = ib[(size_t)(k0 + ty + i * 8) * N + n0 + tx];
    __syncthreads();
    #pragma unroll
    for (int i = 0; i < 4; ++i)
        ob[(size_t)(n0 + ty + i * 8) * K + k0 + tx] = f2bf(t[tx][ty + i * 8]);
}

// ---------------------------------------------------------------------------
// bf16 MFMA GEMM, TMxTN tile, BK templated, 256 thr (4 waves 2x2). XOR-swizzled.
// ---------------------------------------------------------------------------
template<int TM, int TN, int BK, int OUTMODE, int ACT>
__global__ __launch_bounds__(256) void gemm_bf16_k(
    const ushort* __restrict__ A, const ushort* __restrict__ Bt,
    const float* __restrict__ bias, void* __restrict__ C,
    ushort* __restrict__ Cvt, int matV, int N, int K)
{
    constexpr int NI = TM / 32;
    constexpr int NJ = TN / 32;
    constexpr int KS = BK / 32;
    constexpr int CHR = BK / 8;                 // 16B chunks per row
    __shared__ __align__(16) ushort At[TM * BK];
    __shared__ __align__(16) ushort Bts[TN * BK];
    const int tid = threadIdx.x, lane = tid & 63, w = tid >> 6;
    const int wm = w >> 1, wn = w & 1;
    const int q = lane & 15, g = lane >> 4;
    const int m0 = blockIdx.y * TM, n0 = blockIdx.x * TN;

    float4v acc[NI][NJ];
    #pragma unroll
    for (int i = 0; i < NI; ++i)
        #pragma unroll
        for (int j = 0; j < NJ; ++j) acc[i][j] = (float4v){0.f, 0.f, 0.f, 0.f};

    for (int k0 = 0; k0 < K; k0 += BK) {
        #pragma unroll
        for (int t = 0; t < TM * CHR / 256; ++t) {
            const int cb = (w * (TM * CHR / 256) + t) * 64;
            const int c = cb + lane;
            const int row = c / CHR, kc = (c % CHR) ^ (row & (CHR - 1));
            glds16(&A[(size_t)(m0 + row) * K + k0 + kc * 8], &At[cb * 8]);
        }
        #pragma unroll
        for (int t = 0; t < TN * CHR / 256; ++t) {
            const int cb = (w * (TN * CHR / 256) + t) * 64;
            const int c = cb + lane;
            const int row = c / CHR, kc = (c % CHR) ^ (row & (CHR - 1));
            glds16(&Bt[(size_t)(n0 + row) * K + k0 + kc * 8], &Bts[cb * 8]);
        }
        __syncthreads();
        #pragma unroll
        for (int ks = 0; ks < KS; ++ks) {
            short8v af[NI], bf[NJ];
            #pragma unroll
            for (int i = 0; i < NI; ++i) {
                const int row = wm * (TM / 2) + i * 16 + q;
                af[i] = *(const short8v*)((const char*)At +
                        row * (BK * 2) + (((ks * 4 + g) ^ (q & (CHR - 1))) << 4));
            }
            #pragma unroll
            for (int j = 0; j < NJ; ++j) {
                const int row = wn * (TN / 2) + j * 16 + q;
                bf[j] = *(const short8v*)((const char*)Bts +
                        row * (BK * 2) + (((ks * 4 + g) ^ (q & (CHR - 1))) << 4));
            }
            #pragma unroll
            for (int i = 0; i < NI; ++i)
                #pragma unroll
                for (int j = 0; j < NJ; ++j)
                    acc[i][j] = mfma16(af[i], bf[j], acc[i][j]);
        }
        __syncthreads();
    }

    float bcol[NJ];
    #pragma unroll
    for (int j = 0; j < NJ; ++j) bcol[j] = bias[n0 + wn * (TN / 2) + j * 16 + q];

    #pragma unroll
    for (int i = 0; i < NI; ++i) {
        const int rowg0 = m0 + wm * (TM / 2) + i * 16 + g * 4;
        #pragma unroll
        for (int j = 0; j < NJ; ++j) {
            const int colg = n0 + wn * (TN / 2) + j * 16 + q;
            float v[4];
            #pragma unroll
            for (int r = 0; r < 4; ++r) {
                v[r] = acc[i][j][r] + bcol[j];
                if (ACT) v[r] = fmaxf(v[r], 0.f);
            }
            if (OUTMODE == 0) {
                #pragma unroll
                for (int r = 0; r < 4; ++r)
                    ((float*)C)[(size_t)(rowg0 + r) * N + colg] = v[r];
            } else if (OUTMODE == 1) {
                #pragma unroll
                for (int r = 0; r < 4; ++r)
                    ((ushort*)C)[(size_t)(rowg0 + r) * N + colg] = f2bf(v[r]);
            } else {
                const int mat = colg >> 10, h = (colg >> 6) & 15, d = colg & 63;
                const int bb = rowg0 >> 11, s0 = rowg0 & 2047;
                if (mat == matV) {   // V -> transposed layout [bh][d][s]
                    uint2 pv;
                    pv.x = cvtpk(v[0], v[1]);
                    pv.y = cvtpk(v[2], v[3]);
                    *(uint2*)&Cvt[((size_t)(bb * H_ + h) * D_ + d) * S_ + s0] = pv;
                } else {
                    #pragma unroll
                    for (int r = 0; r < 4; ++r)
                        ((ushort*)C)[((((size_t)(mat * B_ + bb) * H_ + h) * S_) + s0 + r) * D_ + d] = f2bf(v[r]);
                }
            }
        }
    }
}

// ---------------------------------------------------------------------------
// Flash attention, 32x32x16 bf16 MFMA, swapped form, STATIC-MAX softmax.
// R20: kv-tile 128 (two sequential 64-halves inside ONE barrier interval):
// halves per-kv barrier/drain/prefetch fixed costs (the R12 lever).
// Registers identical to R16 path (st reused across halves). LDS 64 KB,
// grid 512 = 2 blk/CU (unchanged). K half at ktp + h*8192 (swizzle invariant:
// (h*64+q)&7 == q&7). V rows widen to 256 B, chunk invol ch^(rv&15).
// ---------------------------------------------------------------------------
template<int CAUSAL>
__global__ __launch_bounds__(256, 2) void fattn_k(
    const ushort* __restrict__ Qg, const ushort* __restrict__ Kg,
    const ushort* __restrict__ VTg, ushort* __restrict__ Og, int Skv)
{
    __shared__ __align__(16) ushort Kt[2][128 * 64];  // [kv][d] swizzled, 16 KB x2
    __shared__ __align__(16) ushort Vt[2][64 * 128];  // [d][kv] swizzled, 16 KB x2
    const int tid = threadIdx.x, lane = tid & 63, w = tid >> 6;   // w 0..3
    const int q = lane & 31, hi = lane >> 5;
    const int id = blockIdx.x;
    const int bh = id & 31;
    const int t_ = id >> 5;
    const int qb = CAUSAL ? ((t_ < 8) ? (15 - t_) : (t_ - 8)) : t_;
    const int q0b = qb * 128;
    const int q0w = q0b + w * 32;
    const float MB = 24.f;                            // static exponent bias

    // staging sources: K 1024 chunks (4/thr), V 1024 chunks (4/thr), pre-swizzled
    const ushort* kS[4]; const ushort* vS[4];
    #pragma unroll
    for (int i = 0; i < 4; ++i) {
        const int c = i * 256 + tid;
        const int rk = c >> 3, chk = c & 7;
        kS[i] = Kg + ((size_t)bh * Skv + rk) * 64 + ((chk ^ (rk & 7)) * 8);
        const int rv = c >> 4, chv = c & 15;
        vS[i] = VTg + ((size_t)bh * 64 + rv) * (size_t)Skv + ((chv ^ (rv & 15)) * 8);
    }

#define STAGE(nb) do { \
        glds16(kS[0], &Kt[nb][(tid) * 8]); \
        glds16(kS[1], &Kt[nb][(tid + 256) * 8]); \
        glds16(kS[2], &Kt[nb][(tid + 512) * 8]); \
        glds16(kS[3], &Kt[nb][(tid + 768) * 8]); \
        glds16(vS[0], &Vt[nb][(tid) * 8]); \
        glds16(vS[1], &Vt[nb][(tid + 256) * 8]); \
        glds16(vS[2], &Vt[nb][(tid + 512) * 8]); \
        glds16(vS[3], &Vt[nb][(tid + 768) * 8]); \
        kS[0] += 128 * 64; kS[1] += 128 * 64; kS[2] += 128 * 64; kS[3] += 128 * 64; \
        vS[0] += 128; vS[1] += 128; vS[2] += 128; vS[3] += 128; } while (0)

    // Q B-fragments (Q pre-scaled by 0.125*log2e): B[k=d][col=q], k=ki*16+hi*8+e
    short8v qf[4];
    #pragma unroll
    for (int ki = 0; ki < 4; ++ki)
        qf[ki] = *(const short8v*)&Qg[((size_t)bh * S_ + q0w + q) * 64 + ki * 16 + hi * 8];

    // K LDS base (within a 64-kv half): row=q, chunk=(2ki+hi)^(q&7) -> ^ (ki<<5)
    const int ktB = q * 128 + ((hi ^ (q & 7)) << 4);
    // V LDS base: row=d=q(+32), 256B rows, kv-chunk x = h*8+2kb+hi at x^(q&15)
    // byte = row*256 + ((x ^ (row&15)) << 4); row&15 == q&15 for both rows.

    float16v oacc0, oacc1;
    #pragma unroll
    for (int r = 0; r < 16; ++r) { oacc0[r] = 0.f; oacc1[r] = 0.f; }
    float l_ = 0.f;

    const int ktiles = CAUSAL ? (qb + 1) : (Skv >> 7);
    int cur = 0;

    STAGE(0);
    __syncthreads();

    for (int kt = 0; kt < ktiles; ++kt) {
        if (kt + 1 < ktiles) STAGE(cur ^ 1);          // issue-early
        const char* ktp = (const char*)Kt[cur];
        const char* vtp = (const char*)Vt[cur];

        #pragma unroll
        for (int h = 0; h < 2; ++h) {                 // two 64-kv halves
            const int kv0 = kt * 128 + h * 64;
            const char* ktph = ktp + h * 8192;        // rows h*64..h*64+63

            // S^T = K . Q^T : two kv-32 blocks, K=16 chunks over d
            float16v st0, st1;
            #pragma unroll
            for (int r = 0; r < 16; ++r) { st0[r] = 0.f; st1[r] = 0.f; }
            __builtin_amdgcn_s_setprio(1);
            #pragma unroll
            for (int ki = 0; ki < 4; ++ki) {
                short8v kf0 = *(const short8v*)(ktph + (ktB ^ (ki << 5)));
                short8v kf1 = *(const short8v*)(ktph + (ktB ^ (ki << 5)) + 4096);
                st0 = mfma32(kf0, qf[ki], st0);
                st1 = mfma32(kf1, qf[ki], st1);
            }
            __builtin_amdgcn_s_setprio(0);

            if (CAUSAL && kv0 + 63 > q0b) {           // diagonal-region halves only
                const int qg_ = q0w + q;
                #pragma unroll
                for (int r = 0; r < 16; ++r) {
                    const int row = (r & 3) + 8 * (r >> 2) + 4 * hi;
                    if (kv0 + row > qg_)      st0[r] = -1e9f;
                    if (kv0 + 32 + row > qg_) st1[r] = -1e9f;
                }
            }

            // STATIC-MAX: P = exp2(s - MB), exact (scale cancels in O = PV/l)
            float ts[16];
            #pragma unroll
            for (int r = 0; r < 16; ++r) {
                st0[r] = fexp2(st0[r] - MB);
                st1[r] = fexp2(st1[r] - MB);
                ts[r] = st0[r] + st1[r];
            }
            #pragma unroll
            for (int off = 8; off >= 1; off >>= 1)
                #pragma unroll
                for (int i = 0; i < 8; ++i)
                    if (i < off) ts[i] += ts[i + off];
            l_ += ts[0] + __shfl_xor(ts[0], 32);

            // pack P to bf16 words
            unsigned W0[8], W1[8];
            #pragma unroll
            for (int s = 0; s < 8; ++s) {
                W0[s] = cvtpk(st0[2 * s], st0[2 * s + 1]);
                W1[s] = cvtpk(st1[2 * s], st1[2 * s + 1]);
            }

            // build PV B-frags bq[kb]: P[kv0+kb*16+hi*8+e][q] (R14-verified)
            short8v bq[4];
            #pragma unroll
            for (int kb = 0; kb < 4; ++kb) {
                union { unsigned u[4]; short8v v; } bb;
                #pragma unroll
                for (int j = 0; j < 4; ++j) {
                    const unsigned* Wb = (kb >> 1) ? W1 : W0;
                    const int s0 = (j & 1) + 4 * (kb & 1);
                    const unsigned own  = hi ? Wb[s0 + 2] : Wb[s0];
                    const unsigned send = hi ? Wb[s0]     : Wb[s0 + 2];
                    const unsigned rec  = (unsigned)__shfl_xor((int)send, 32);
                    bb.u[j] = (j >> 1) ? (hi ? own : rec) : (hi ? rec : own);
                }
                bq[kb] = bb.v;
            }

            // O^T += V^T . P^T : kv-chunk x = h*8 + 2kb + hi on 256B rows
            __builtin_amdgcn_s_setprio(1);
            #pragma unroll
            for (int kb = 0; kb < 4; ++kb) {
                const int x = h * 8 + 2 * kb + hi;
                short8v vf0 = *(const short8v*)(vtp +
                              q * 256 + ((x ^ (q & 15)) << 4));
                short8v vf1 = *(const short8v*)(vtp +
                              (32 + q) * 256 + ((x ^ (q & 15)) << 4));
                oacc0 = mfma32(vf0, bq[kb], oacc0);
                oacc1 = mfma32(vf1, bq[kb], oacc1);
            }
            __builtin_amdgcn_s_setprio(0);
        }

        __syncthreads();       // ONE drain+barrier per 128 kv (was per 64)
        cur ^= 1;
    }
#undef STAGE

    // normalize + stage O into Kt region (dead), swizzled; then coalesced out
    const float inv = frcp(l_);
    char* Ob = (char*)Kt;
    const int qr = w * 32 + q;
    #pragma unroll
    for (int s = 0; s < 8; ++s) {
        const int d0a = 2 * (s & 1) + 8 * (s >> 1) + 4 * hi;        // db=0
        unsigned wa = cvtpk(oacc0[2 * s] * inv, oacc0[2 * s + 1] * inv);
        *(unsigned*)(Ob + qr * 128 + ((((d0a >> 3) ^ (qr & 7)) << 4) | ((2 * d0a) & 15))) = wa;
        const int d0b = d0a + 32;                                    // db=1
        unsigned wb = cvtpk(oacc1[2 * s] * inv, oacc1[2 * s + 1] * inv);
        *(unsigned*)(Ob + qr * 128 + ((((d0b >> 3) ^ (qr & 7)) << 4) | ((2 * d0b) & 15))) = wb;
    }
    __syncthreads();
    const int b = bh >> 4, h2 = bh & 15;
    #pragma unroll
    for (int t = 0; t < 4; ++t) {
        const int c = t * 256 + tid;
        const int qrow = c >> 3, ch = c & 7;
        short8v v = *(const short8v*)(Ob + qrow * 128 + ((ch ^ (qrow & 7)) << 4));
        *(short8v*)&Og[((size_t)(b * S_ + q0b + qrow)) * M_ + h2 * 64 + ch * 8] = v;
    }
}

// ---------------------------------------------------------------------------
// Fused residual-add + LayerNorm. X bf16, residual fp32; emits fp32 (+bf16).
// ---------------------------------------------------------------------------
template<int EMITB>
__global__ __launch_bounds__(256) void ln_k(
    const ushort* __restrict__ X, const float* __restrict__ Rz,
    const float* __restrict__ g, const float* __restrict__ be,
    float* __restrict__ outf, ushort* __restrict__ outb)
{
    __shared__ float red[8];
    const int row = blockIdx.x, tid = threadIdx.x;
    const int lane = tid & 63, w = tid >> 6;

    ushort4 xu = *(const ushort4*)&X[(size_t)row * M_ + tid * 4];
    float4 rr = ld4(Rz + (size_t)row * M_ + tid * 4);
    float4 x = make_float4(bf2f(xu.x) + rr.x, bf2f(xu.y) + rr.y,
                           bf2f(xu.z) + rr.z, bf2f(xu.w) + rr.w);

    float sm = x.x + x.y + x.z + x.w;
    #pragma unroll
    for (int off = 1; off < 64; off <<= 1) sm += __shfl_xor(sm, off);
    if (lane == 0) red[w] = sm;
    __syncthreads();
    const float mean = (red[0] + red[1] + red[2] + red[3]) * (1.f / M_);

    x.x -= mean; x.y -= mean; x.z -= mean; x.w -= mean;
    float vs = x.x * x.x + x.y * x.y + x.z * x.z + x.w * x.w;
    #pragma unroll
    for (int off = 1; off < 64; off <<= 1) vs += __shfl_xor(vs, off);
    if (lane == 0) red[4 + w] = vs;
    __syncthreads();
    const float var = (red[4] + red[5] + red[6] + red[7]) * (1.f / M_);
    const float rs = rsqrtf(var + 1e-5f);

    float4 gg = ld4(g + tid * 4), bb = ld4(be + tid * 4);
    float4 y = make_float4(x.x * rs * gg.x + bb.x, x.y * rs * gg.y + bb.y,
                           x.z * rs * gg.z + bb.z, x.w * rs * gg.w + bb.w);
    *(float4*)(outf + (size_t)row * M_ + tid * 4) = y;
    if (EMITB) {
        ushort4 ob = { f2bf(y.x), f2bf(y.y), f2bf(y.z), f2bf(y.w) };
        *(ushort4*)&outb[(size_t)row * M_ + tid * 4] = ob;
    }
}

// ---------------------------------------------------------------------------
extern "C" void kernel_launch(void* const* d_in, const int* in_sizes, int n_in,
                              void* d_out, int out_size, void* d_ws, size_t ws_size,
                              hipStream_t stream)
{
    const float* input = (const float*)d_in[0];
    const float* enc   = (const float*)d_in[1];
    const float* Wq1 = (const float*)d_in[2];  const float* bq1 = (const float*)d_in[3];
    const float* Wk1 = (const float*)d_in[4];  const float* bk1 = (const float*)d_in[5];
    const float* Wv1 = (const float*)d_in[6];  const float* bv1 = (const float*)d_in[7];
    const float* Wo1 = (const float*)d_in[8];  const float* bo1 = (const float*)d_in[9];
    const float* ln1g = (const float*)d_in[10]; const float* ln1b = (const float*)d_in[11];
    const float* Wq2 = (const float*)d_in[12]; const float* bq2 = (const float*)d_in[13];
    const float* Wk2 = (const float*)d_in[14]; const float* bk2 = (const float*)d_in[15];
    const float* Wv2 = (const float*)d_in[16]; const float* bv2 = (const float*)d_in[17];
    const float* Wo2 = (const float*)d_in[18]; const float* bo2 = (const float*)d_in[19];
    const float* ln2g = (const float*)d_in[20]; const float* ln2b = (const float*)d_in[21];
    const float* Wf1 = (const float*)d_in[22]; const float* bf1 = (const float*)d_in[23];
    const float* Wf2 = (const float*)d_in[24]; const float* bf2 = (const float*)d_in[25];
    const float* ln3g = (const float*)d_in[26]; const float* ln3b = (const float*)d_in[27];

    const float SC = 0.18033688011112042f;     // 0.125 * log2(e)

    char* W = (char*)d_ws;
    #define OFS(mb) ((void*)(W + (size_t)(mb) * 1024 * 1024))
    ushort* x0b    = (ushort*)OFS(0);
    ushort* encb   = (ushort*)OFS(8);
    ushort* WqkvT1 = (ushort*)OFS(16);
    ushort* Wo1T   = (ushort*)OFS(22);
    ushort* Wq2T   = (ushort*)OFS(24);
    ushort* WkvT2  = (ushort*)OFS(26);
    ushort* Wo2T   = (ushort*)OFS(30);
    ushort* Wf1T   = (ushort*)OFS(32);
    ushort* Wf2T   = (ushort*)OFS(36);
    float*  biasQKV1 = (float*)OFS(40);
    float*  biasKV2  = (float*)((char*)OFS(40) + 16384);
    float*  biasQ2   = (float*)((char*)OFS(40) + 32768);
    ushort* QKV1   = (ushort*)OFS(41);   // [3][B][H][S][D] (V region unused)
    ushort* VT1    = (ushort*)OFS(65);
    ushort* att1b  = (ushort*)OFS(73);
    ushort* o1b    = (ushort*)OFS(81);
    float*  out1f  = (float*)OFS(41);
    ushort* out1b  = (ushort*)OFS(57);
    ushort* Q2     = (ushort*)OFS(65);
    ushort* KV2    = (ushort*)OFS(73);   // [2][B][H][S][D] (V region unused)
    ushort* VT2    = (ushort*)OFS(0);
    ushort* att2b  = (ushort*)OFS(8);
    ushort* o2b    = (ushort*)OFS(65);
    float*  out2f  = (float*)OFS(73);
    ushort* out2b  = (ushort*)OFS(0);
    ushort* ff1b   = (ushort*)OFS(41);
    ushort* ff2b   = (ushort*)OFS(57);
    float*  out    = (float*)d_out;
    const size_t MAT = (size_t)B_ * H_ * S_ * D_;   // 4 Mi elements

    dim3 blk(256);

    // ---- prep (6 launches) ----
    cast2_k<<<8192, blk, 0, stream>>>(input, enc, x0b, encb);
    biasp_k<<<24, blk, 0, stream>>>(bq1, bk1, bv1, bk2, bv2, bq2, biasQKV1, SC);
    wtransH_k<<<dim3(2, 32, 96), blk, 0, stream>>>(Wq1, Wk1, Wv1, Wq2, Wk2, Wv2,
                                                   WqkvT1, Wq2T, WkvT2, SC);
    wtrans_k<<<dim3(32, 32, 2), blk, 0, stream>>>(Wo1, Wo2, Wo1T, Wo2T, 1024, 1024);
    wtrans_k<<<dim3(64, 32, 1), blk, 0, stream>>>(Wf1, Wf1, Wf1T, Wf1T, 1024, 2048);
    wtrans_k<<<dim3(32, 64, 1), blk, 0, stream>>>(Wf2, Wf2, Wf2T, Wf2T, 2048, 1024);

    // ---- masked self-attention ----
    gemm_bf16_k<128, 128, 64, 2, 0><<<dim3(24, 32), blk, 0, stream>>>(
        x0b, WqkvT1, biasQKV1, QKV1, VT1, 2, 3072, 1024);
    fattn_k<1><<<dim3(512), blk, 0, stream>>>(QKV1, QKV1 + MAT, VT1, att1b, S_);
    gemm_bf16_k<64, 64, 64, 1, 0><<<dim3(16, 64), blk, 0, stream>>>(
        att1b, Wo1T, bo1, o1b, nullptr, 9, 1024, 1024);
    ln_k<1><<<dim3(R_), blk, 0, stream>>>(o1b, input, ln1g, ln1b, out1f, out1b);

    // ---- cross-attention ----
    gemm_bf16_k<64, 64, 64, 2, 0><<<dim3(16, 64), blk, 0, stream>>>(
        out1b, Wq2T, biasQ2, Q2, nullptr, 9, 1024, 1024);
    gemm_bf16_k<128, 128, 64, 2, 0><<<dim3(16, 32), blk, 0, stream>>>(
        encb, WkvT2, biasKV2, KV2, VT2, 1, 2048, 1024);
    fattn_k<0><<<dim3(512), blk, 0, stream>>>(Q2, KV2, VT2, att2b, S_);
    gemm_bf16_k<64, 64, 64, 1, 0><<<dim3(16, 64), blk, 0, stream>>>(
        att2b, Wo2T, bo2, o2b, nullptr, 9, 1024, 1024);
    ln_k<1><<<dim3(R_), blk, 0, stream>>>(o2b, out1f, ln2g, ln2b, out2f, out2b);

    // ---- FFN ----
    gemm_bf16_k<128, 64, 64, 1, 1><<<dim3(32, 32), blk, 0, stream>>>(
        out2b, Wf1T, bf1, ff1b, nullptr, 9, 2048, 1024);
    gemm_bf16_k<64, 64, 64, 1, 0><<<dim3(16, 64), blk, 0, stream>>>(
        ff1b, Wf2T, bf2, ff2b, nullptr, 9, 1024, 2048);
    ln_k<0><<<dim3(R_), blk, 0, stream>>>(ff2b, out2f, ln3g, ln3b, out, nullptr);
    #undef OFS
}

// Round 21
// 291.626 us; speedup vs baseline: 1.1258x; 1.0225x over previous
//
#include <hip/hip_runtime.h>
#include <math.h>

#define B_ 2
#define S_ 2048
#define M_ 1024
#define H_ 16
#define D_ 64
#define R_ (B_*S_)          // 4096 rows

typedef __attribute__((ext_vector_type(8))) short short8v;    // 8 bf16 = 4 VGPR
typedef __attribute__((ext_vector_type(4))) float float4v;
typedef __attribute__((ext_vector_type(16))) float float16v; // 32x32 C/D

__device__ __forceinline__ float4 ld4(const float* p) {
    return *(const float4* __restrict__)p;
}

__device__ __forceinline__ ushort f2bf(float f) {            // RNE
    union { float f; unsigned u; } x; x.f = f;
    unsigned u = x.u + 0x7fffu + ((x.u >> 16) & 1u);
    return (ushort)(u >> 16);
}
__device__ __forceinline__ float bf2f(ushort s) {
    union { unsigned u; float f; } x; x.u = ((unsigned)s) << 16; return x.f;
}
__device__ __forceinline__ unsigned cvtpk(float lo, float hi) {
    unsigned r;
    asm("v_cvt_pk_bf16_f32 %0, %1, %2" : "=v"(r) : "v"(lo), "v"(hi));
    return r;
}
#if __has_builtin(__builtin_amdgcn_exp2f)
__device__ __forceinline__ float fexp2(float x) { return __builtin_amdgcn_exp2f(x); }
#else
__device__ __forceinline__ float fexp2(float x) { return exp2f(x); }
#endif
#if __has_builtin(__builtin_amdgcn_rcpf)
__device__ __forceinline__ float frcp(float x) { return __builtin_amdgcn_rcpf(x); }
#else
__device__ __forceinline__ float frcp(float x) { return 1.f / x; }
#endif
__device__ __forceinline__ float4v mfma16(short8v a, short8v b, float4v c) {
    return __builtin_amdgcn_mfma_f32_16x16x32_bf16(a, b, c, 0, 0, 0);
}
__device__ __forceinline__ float16v mfma32(short8v a, short8v b, float16v c) {
    return __builtin_amdgcn_mfma_f32_32x32x16_bf16(a, b, c, 0, 0, 0);
}
__device__ __forceinline__ void glds16(const void* g, void* l) {
    __builtin_amdgcn_global_load_lds(
        (const __attribute__((address_space(1))) void*)g,
        (__attribute__((address_space(3))) void*)l, 16, 0, 0);
}

// ---------------------------------------------------------------------------
// prep kernels (fused)
// ---------------------------------------------------------------------------
__global__ __launch_bounds__(256) void cast2_k(const float* __restrict__ a,
                                               const float* __restrict__ b,
                                               ushort* __restrict__ oa,
                                               ushort* __restrict__ ob) {
    size_t u = (size_t)blockIdx.x * 256 + threadIdx.x;       // float4 units
    const float* in; ushort* out;
    if (u < (1u << 20)) { in = a; out = oa; }
    else { u -= (1u << 20); in = b; out = ob; }
    float4 v = ld4(in + u * 4);
    ushort4 o = { f2bf(v.x), f2bf(v.y), f2bf(v.z), f2bf(v.w) };
    *(ushort4*)&out[u * 4] = o;
}

__global__ __launch_bounds__(256) void biasp_k(
    const float* __restrict__ q1, const float* __restrict__ k1,
    const float* __restrict__ v1, const float* __restrict__ k2,
    const float* __restrict__ v2, const float* __restrict__ q2,
    float* __restrict__ dst, float SCv) {
    const int seg = blockIdx.x >> 2;
    const int li = (blockIdx.x & 3) * 256 + threadIdx.x;
    const float* s; int off; float sc;
    switch (seg) {
        case 0: s = q1; off = 0;    sc = SCv; break;
        case 1: s = k1; off = 1024; sc = 1.f; break;
        case 2: s = v1; off = 2048; sc = 1.f; break;
        case 3: s = k2; off = 4096; sc = 1.f; break;
        case 4: s = v2; off = 5120; sc = 1.f; break;
        default: s = q2; off = 8192; sc = SCv; break;
    }
    dst[off + li] = s[li] * sc;
}

__global__ __launch_bounds__(256) void wtransH_k(
    const float* __restrict__ s0, const float* __restrict__ s1,
    const float* __restrict__ s2, const float* __restrict__ s3,
    const float* __restrict__ s4, const float* __restrict__ s5,
    ushort* __restrict__ oQKV1, ushort* __restrict__ oQ2,
    ushort* __restrict__ oKV2, float SCv) {
    __shared__ float t[32][33];
    const int z = blockIdx.z, s6 = z >> 4, h = z & 15;
    const float* srcs[6] = { s0, s1, s2, s3, s4, s5 };
    const float* ib = srcs[s6] + (size_t)h * 1024 * 64;
    ushort* ob;
    if (s6 < 3)       ob = oQKV1 + (size_t)s6 * (1024 * 1024) + (size_t)h * (64 * 1024);
    else if (s6 == 3) ob = oQ2 + (size_t)h * (64 * 1024);
    else              ob = oKV2 + (size_t)(s6 - 4) * (1024 * 1024) + (size_t)h * (64 * 1024);
    const float scale = (s6 == 0 || s6 == 3) ? SCv : 1.f;
    const int k0 = blockIdx.y * 32, n0 = blockIdx.x * 32;
    const int tx = threadIdx.x & 31, ty = threadIdx.x >> 5;
    #pragma unroll
    for (int i = 0; i < 4; ++i)
        t[ty + i * 8][tx] = ib[(size_t)(k0 + ty + i * 8) * 64 + n0 + tx];
    __syncthreads();
    #pragma unroll
    for (int i = 0; i < 4; ++i)
        ob[(size_t)(n0 + ty + i * 8) * 1024 + k0 + tx] = f2bf(t[tx][ty + i * 8] * scale);
}

__global__ __launch_bounds__(256) void wtrans_k(const float* __restrict__ inA,
                                                const float* __restrict__ inB,
                                                ushort* __restrict__ outA,
                                                ushort* __restrict__ outB,
                                                int K, int N) {
    __shared__ float t[32][33];
    const float* ib = blockIdx.z ? inB : inA;
    ushort* ob = blockIdx.z ? outB : outA;
    const int k0 = blockIdx.y * 32, n0 = blockIdx.x * 32;
    const int tx = threadIdx.x & 31, ty = threadIdx.x >> 5;
    #pragma unroll
    for (int i = 0; i < 4; ++i)
        t[ty + i * 8][tx] = ib[(size_t)(k0 + ty + i * 8) * N + n0 + tx];
    __syncthreads();
    #pragma unroll
    for (int i = 0; i < 4; ++i)
        ob[(size_t)(n0 + ty + i * 8) * K + k0 + tx] = f2bf(t[tx][ty + i * 8]);
}

// ---------------------------------------------------------------------------
// bf16 MFMA GEMM, TMxTN tile, BK templated, 256 thr (4 waves 2x2). XOR-swizzled.
// ---------------------------------------------------------------------------
template<int TM, int TN, int BK, int OUTMODE, int ACT>
__global__ __launch_bounds__(256) void gemm_bf16_k(
    const ushort* __restrict__ A, const ushort* __restrict__ Bt,
    const float* __restrict__ bias, void* __restrict__ C,
    ushort* __restrict__ Cvt, int matV, int N, int K)
{
    constexpr int NI = TM / 32;
    constexpr int NJ = TN / 32;
    constexpr int KS = BK / 32;
    constexpr int CHR = BK / 8;                 // 16B chunks per row
    __shared__ __align__(16) ushort At[TM * BK];
    __shared__ __align__(16) ushort Bts[TN * BK];
    const int tid = threadIdx.x, lane = tid & 63, w = tid >> 6;
    const int wm = w >> 1, wn = w & 1;
    const int q = lane & 15, g = lane >> 4;
    const int m0 = blockIdx.y * TM, n0 = blockIdx.x * TN;

    float4v acc[NI][NJ];
    #pragma unroll
    for (int i = 0; i < NI; ++i)
        #pragma unroll
        for (int j = 0; j < NJ; ++j) acc[i][j] = (float4v){0.f, 0.f, 0.f, 0.f};

    for (int k0 = 0; k0 < K; k0 += BK) {
        #pragma unroll
        for (int t = 0; t < TM * CHR / 256; ++t) {
            const int cb = (w * (TM * CHR / 256) + t) * 64;
            const int c = cb + lane;
            const int row = c / CHR, kc = (c % CHR) ^ (row & (CHR - 1));
            glds16(&A[(size_t)(m0 + row) * K + k0 + kc * 8], &At[cb * 8]);
        }
        #pragma unroll
        for (int t = 0; t < TN * CHR / 256; ++t) {
            const int cb = (w * (TN * CHR / 256) + t) * 64;
            const int c = cb + lane;
            const int row = c / CHR, kc = (c % CHR) ^ (row & (CHR - 1));
            glds16(&Bt[(size_t)(n0 + row) * K + k0 + kc * 8], &Bts[cb * 8]);
        }
        __syncthreads();
        #pragma unroll
        for (int ks = 0; ks < KS; ++ks) {
            short8v af[NI], bf[NJ];
            #pragma unroll
            for (int i = 0; i < NI; ++i) {
                const int row = wm * (TM / 2) + i * 16 + q;
                af[i] = *(const short8v*)((const char*)At +
                        row * (BK * 2) + (((ks * 4 + g) ^ (q & (CHR - 1))) << 4));
            }
            #pragma unroll
            for (int j = 0; j < NJ; ++j) {
                const int row = wn * (TN / 2) + j * 16 + q;
                bf[j] = *(const short8v*)((const char*)Bts +
                        row * (BK * 2) + (((ks * 4 + g) ^ (q & (CHR - 1))) << 4));
            }
            #pragma unroll
            for (int i = 0; i < NI; ++i)
                #pragma unroll
                for (int j = 0; j < NJ; ++j)
                    acc[i][j] = mfma16(af[i], bf[j], acc[i][j]);
        }
        __syncthreads();
    }

    float bcol[NJ];
    #pragma unroll
    for (int j = 0; j < NJ; ++j) bcol[j] = bias[n0 + wn * (TN / 2) + j * 16 + q];

    #pragma unroll
    for (int i = 0; i < NI; ++i) {
        const int rowg0 = m0 + wm * (TM / 2) + i * 16 + g * 4;
        #pragma unroll
        for (int j = 0; j < NJ; ++j) {
            const int colg = n0 + wn * (TN / 2) + j * 16 + q;
            float v[4];
            #pragma unroll
            for (int r = 0; r < 4; ++r) {
                v[r] = acc[i][j][r] + bcol[j];
                if (ACT) v[r] = fmaxf(v[r], 0.f);
            }
            if (OUTMODE == 0) {
                #pragma unroll
                for (int r = 0; r < 4; ++r)
                    ((float*)C)[(size_t)(rowg0 + r) * N + colg] = v[r];
            } else if (OUTMODE == 1) {
                #pragma unroll
                for (int r = 0; r < 4; ++r)
                    ((ushort*)C)[(size_t)(rowg0 + r) * N + colg] = f2bf(v[r]);
            } else {
                const int mat = colg >> 10, h = (colg >> 6) & 15, d = colg & 63;
                const int bb = rowg0 >> 11, s0 = rowg0 & 2047;
                if (mat == matV) {   // V -> transposed layout [bh][d][s]
                    uint2 pv;
                    pv.x = cvtpk(v[0], v[1]);
                    pv.y = cvtpk(v[2], v[3]);
                    *(uint2*)&Cvt[((size_t)(bb * H_ + h) * D_ + d) * S_ + s0] = pv;
                } else {
                    #pragma unroll
                    for (int r = 0; r < 4; ++r)
                        ((ushort*)C)[((((size_t)(mat * B_ + bb) * H_ + h) * S_) + s0 + r) * D_ + d] = f2bf(v[r]);
                }
            }
        }
    }
}

// ---------------------------------------------------------------------------
// Flash attention, 32x32x16 bf16 MFMA, swapped form, STATIC-MAX softmax.
// R20-measured-best: kv-tile 128 (two 64-halves per barrier interval).
// ---------------------------------------------------------------------------
template<int CAUSAL>
__global__ __launch_bounds__(256, 2) void fattn_k(
    const ushort* __restrict__ Qg, const ushort* __restrict__ Kg,
    const ushort* __restrict__ VTg, ushort* __restrict__ Og, int Skv)
{
    __shared__ __align__(16) ushort Kt[2][128 * 64];  // [kv][d] swizzled, 16 KB x2
    __shared__ __align__(16) ushort Vt[2][64 * 128];  // [d][kv] swizzled, 16 KB x2
    const int tid = threadIdx.x, lane = tid & 63, w = tid >> 6;   // w 0..3
    const int q = lane & 31, hi = lane >> 5;
    const int id = blockIdx.x;
    const int bh = id & 31;
    const int t_ = id >> 5;
    const int qb = CAUSAL ? ((t_ < 8) ? (15 - t_) : (t_ - 8)) : t_;
    const int q0b = qb * 128;
    const int q0w = q0b + w * 32;
    const float MB = 24.f;                            // static exponent bias

    // staging sources: K 1024 chunks (4/thr), V 1024 chunks (4/thr), pre-swizzled
    const ushort* kS[4]; const ushort* vS[4];
    #pragma unroll
    for (int i = 0; i < 4; ++i) {
        const int c = i * 256 + tid;
        const int rk = c >> 3, chk = c & 7;
        kS[i] = Kg + ((size_t)bh * Skv + rk) * 64 + ((chk ^ (rk & 7)) * 8);
        const int rv = c >> 4, chv = c & 15;
        vS[i] = VTg + ((size_t)bh * 64 + rv) * (size_t)Skv + ((chv ^ (rv & 15)) * 8);
    }

#define STAGE(nb) do { \
        glds16(kS[0], &Kt[nb][(tid) * 8]); \
        glds16(kS[1], &Kt[nb][(tid + 256) * 8]); \
        glds16(kS[2], &Kt[nb][(tid + 512) * 8]); \
        glds16(kS[3], &Kt[nb][(tid + 768) * 8]); \
        glds16(vS[0], &Vt[nb][(tid) * 8]); \
        glds16(vS[1], &Vt[nb][(tid + 256) * 8]); \
        glds16(vS[2], &Vt[nb][(tid + 512) * 8]); \
        glds16(vS[3], &Vt[nb][(tid + 768) * 8]); \
        kS[0] += 128 * 64; kS[1] += 128 * 64; kS[2] += 128 * 64; kS[3] += 128 * 64; \
        vS[0] += 128; vS[1] += 128; vS[2] += 128; vS[3] += 128; } while (0)

    // Q B-fragments (Q pre-scaled by 0.125*log2e): B[k=d][col=q], k=ki*16+hi*8+e
    short8v qf[4];
    #pragma unroll
    for (int ki = 0; ki < 4; ++ki)
        qf[ki] = *(const short8v*)&Qg[((size_t)bh * S_ + q0w + q) * 64 + ki * 16 + hi * 8];

    // K LDS base (within a 64-kv half): row=q, chunk=(2ki+hi)^(q&7) -> ^ (ki<<5)
    const int ktB = q * 128 + ((hi ^ (q & 7)) << 4);

    float16v oacc0, oacc1;
    #pragma unroll
    for (int r = 0; r < 16; ++r) { oacc0[r] = 0.f; oacc1[r] = 0.f; }
    float l_ = 0.f;

    const int ktiles = CAUSAL ? (qb + 1) : (Skv >> 7);
    int cur = 0;

    STAGE(0);
    __syncthreads();

    for (int kt = 0; kt < ktiles; ++kt) {
        if (kt + 1 < ktiles) STAGE(cur ^ 1);          // issue-early
        const char* ktp = (const char*)Kt[cur];
        const char* vtp = (const char*)Vt[cur];

        #pragma unroll
        for (int h = 0; h < 2; ++h) {                 // two 64-kv halves
            const int kv0 = kt * 128 + h * 64;
            const char* ktph = ktp + h * 8192;        // rows h*64..h*64+63

            // S^T = K . Q^T : two kv-32 blocks, K=16 chunks over d
            float16v st0, st1;
            #pragma unroll
            for (int r = 0; r < 16; ++r) { st0[r] = 0.f; st1[r] = 0.f; }
            __builtin_amdgcn_s_setprio(1);
            #pragma unroll
            for (int ki = 0; ki < 4; ++ki) {
                short8v kf0 = *(const short8v*)(ktph + (ktB ^ (ki << 5)));
                short8v kf1 = *(const short8v*)(ktph + (ktB ^ (ki << 5)) + 4096);
                st0 = mfma32(kf0, qf[ki], st0);
                st1 = mfma32(kf1, qf[ki], st1);
            }
            __builtin_amdgcn_s_setprio(0);

            if (CAUSAL && kv0 + 63 > q0b) {           // diagonal-region halves only
                const int qg_ = q0w + q;
                #pragma unroll
                for (int r = 0; r < 16; ++r) {
                    const int row = (r & 3) + 8 * (r >> 2) + 4 * hi;
                    if (kv0 + row > qg_)      st0[r] = -1e9f;
                    if (kv0 + 32 + row > qg_) st1[r] = -1e9f;
                }
            }

            // STATIC-MAX: P = exp2(s - MB), exact (scale cancels in O = PV/l)
            float ts[16];
            #pragma unroll
            for (int r = 0; r < 16; ++r) {
                st0[r] = fexp2(st0[r] - MB);
                st1[r] = fexp2(st1[r] - MB);
                ts[r] = st0[r] + st1[r];
            }
            #pragma unroll
            for (int off = 8; off >= 1; off >>= 1)
                #pragma unroll
                for (int i = 0; i < 8; ++i)
                    if (i < off) ts[i] += ts[i + off];
            l_ += ts[0] + __shfl_xor(ts[0], 32);

            // pack P to bf16 words
            unsigned W0[8], W1[8];
            #pragma unroll
            for (int s = 0; s < 8; ++s) {
                W0[s] = cvtpk(st0[2 * s], st0[2 * s + 1]);
                W1[s] = cvtpk(st1[2 * s], st1[2 * s + 1]);
            }

            // build PV B-frags bq[kb]: P[kv0+kb*16+hi*8+e][q] (R14-verified)
            short8v bq[4];
            #pragma unroll
            for (int kb = 0; kb < 4; ++kb) {
                union { unsigned u[4]; short8v v; } bb;
                #pragma unroll
                for (int j = 0; j < 4; ++j) {
                    const unsigned* Wb = (kb >> 1) ? W1 : W0;
                    const int s0 = (j & 1) + 4 * (kb & 1);
                    const unsigned own  = hi ? Wb[s0 + 2] : Wb[s0];
                    const unsigned send = hi ? Wb[s0]     : Wb[s0 + 2];
                    const unsigned rec  = (unsigned)__shfl_xor((int)send, 32);
                    bb.u[j] = (j >> 1) ? (hi ? own : rec) : (hi ? rec : own);
                }
                bq[kb] = bb.v;
            }

            // O^T += V^T . P^T : kv-chunk x = h*8 + 2kb + hi on 256B rows
            __builtin_amdgcn_s_setprio(1);
            #pragma unroll
            for (int kb = 0; kb < 4; ++kb) {
                const int x = h * 8 + 2 * kb + hi;
                short8v vf0 = *(const short8v*)(vtp +
                              q * 256 + ((x ^ (q & 15)) << 4));
                short8v vf1 = *(const short8v*)(vtp +
                              (32 + q) * 256 + ((x ^ (q & 15)) << 4));
                oacc0 = mfma32(vf0, bq[kb], oacc0);
                oacc1 = mfma32(vf1, bq[kb], oacc1);
            }
            __builtin_amdgcn_s_setprio(0);
        }

        __syncthreads();       // ONE drain+barrier per 128 kv
        cur ^= 1;
    }
#undef STAGE

    // normalize + stage O into Kt region (dead), swizzled; then coalesced out
    const float inv = frcp(l_);
    char* Ob = (char*)Kt;
    const int qr = w * 32 + q;
    #pragma unroll
    for (int s = 0; s < 8; ++s) {
        const int d0a = 2 * (s & 1) + 8 * (s >> 1) + 4 * hi;        // db=0
        unsigned wa = cvtpk(oacc0[2 * s] * inv, oacc0[2 * s + 1] * inv);
        *(unsigned*)(Ob + qr * 128 + ((((d0a >> 3) ^ (qr & 7)) << 4) | ((2 * d0a) & 15))) = wa;
        const int d0b = d0a + 32;                                    // db=1
        unsigned wb = cvtpk(oacc1[2 * s] * inv, oacc1[2 * s + 1] * inv);
        *(unsigned*)(Ob + qr * 128 + ((((d0b >> 3) ^ (qr & 7)) << 4) | ((2 * d0b) & 15))) = wb;
    }
    __syncthreads();
    const int b = bh >> 4, h2 = bh & 15;
    #pragma unroll
    for (int t = 0; t < 4; ++t) {
        const int c = t * 256 + tid;
        const int qrow = c >> 3, ch = c & 7;
        short8v v = *(const short8v*)(Ob + qrow * 128 + ((ch ^ (qrow & 7)) << 4));
        *(short8v*)&Og[((size_t)(b * S_ + q0b + qrow)) * M_ + h2 * 64 + ch * 8] = v;
    }
}

// ---------------------------------------------------------------------------
// Fused residual-add + LayerNorm, bf16 residual chain.
// X bf16, Rz bf16; OUTF=0: emit bf16; OUTF=1: emit fp32 (final output).
// ---------------------------------------------------------------------------
template<int OUTF>
__global__ __launch_bounds__(256) void ln_k(
    const ushort* __restrict__ X, const ushort* __restrict__ Rz,
    const float* __restrict__ g, const float* __restrict__ be,
    ushort* __restrict__ outb, float* __restrict__ outf)
{
    __shared__ float red[8];
    const int row = blockIdx.x, tid = threadIdx.x;
    const int lane = tid & 63, w = tid >> 6;

    ushort4 xu = *(const ushort4*)&X[(size_t)row * M_ + tid * 4];
    ushort4 ru = *(const ushort4*)&Rz[(size_t)row * M_ + tid * 4];
    float4 x = make_float4(bf2f(xu.x) + bf2f(ru.x), bf2f(xu.y) + bf2f(ru.y),
                           bf2f(xu.z) + bf2f(ru.z), bf2f(xu.w) + bf2f(ru.w));

    float sm = x.x + x.y + x.z + x.w;
    #pragma unroll
    for (int off = 1; off < 64; off <<= 1) sm += __shfl_xor(sm, off);
    if (lane == 0) red[w] = sm;
    __syncthreads();
    const float mean = (red[0] + red[1] + red[2] + red[3]) * (1.f / M_);

    x.x -= mean; x.y -= mean; x.z -= mean; x.w -= mean;
    float vs = x.x * x.x + x.y * x.y + x.z * x.z + x.w * x.w;
    #pragma unroll
    for (int off = 1; off < 64; off <<= 1) vs += __shfl_xor(vs, off);
    if (lane == 0) red[4 + w] = vs;
    __syncthreads();
    const float var = (red[4] + red[5] + red[6] + red[7]) * (1.f / M_);
    const float rs = rsqrtf(var + 1e-5f);

    float4 gg = ld4(g + tid * 4), bb = ld4(be + tid * 4);
    float4 y = make_float4(x.x * rs * gg.x + bb.x, x.y * rs * gg.y + bb.y,
                           x.z * rs * gg.z + bb.z, x.w * rs * gg.w + bb.w);
    if (OUTF) {
        *(float4*)(outf + (size_t)row * M_ + tid * 4) = y;
    } else {
        ushort4 ob = { f2bf(y.x), f2bf(y.y), f2bf(y.z), f2bf(y.w) };
        *(ushort4*)&outb[(size_t)row * M_ + tid * 4] = ob;
    }
}

// ---------------------------------------------------------------------------
extern "C" void kernel_launch(void* const* d_in, const int* in_sizes, int n_in,
                              void* d_out, int out_size, void* d_ws, size_t ws_size,
                              hipStream_t stream)
{
    const float* input = (const float*)d_in[0];
    const float* enc   = (const float*)d_in[1];
    const float* Wq1 = (const float*)d_in[2];  const float* bq1 = (const float*)d_in[3];
    const float* Wk1 = (const float*)d_in[4];  const float* bk1 = (const float*)d_in[5];
    const float* Wv1 = (const float*)d_in[6];  const float* bv1 = (const float*)d_in[7];
    const float* Wo1 = (const float*)d_in[8];  const float* bo1 = (const float*)d_in[9];
    const float* ln1g = (const float*)d_in[10]; const float* ln1b = (const float*)d_in[11];
    const float* Wq2 = (const float*)d_in[12]; const float* bq2 = (const float*)d_in[13];
    const float* Wk2 = (const float*)d_in[14]; const float* bk2 = (const float*)d_in[15];
    const float* Wv2 = (const float*)d_in[16]; const float* bv2 = (const float*)d_in[17];
    const float* Wo2 = (const float*)d_in[18]; const float* bo2 = (const float*)d_in[19];
    const float* ln2g = (const float*)d_in[20]; const float* ln2b = (const float*)d_in[21];
    const float* Wf1 = (const float*)d_in[22]; const float* bf1 = (const float*)d_in[23];
    const float* Wf2 = (const float*)d_in[24]; const float* bf2 = (const float*)d_in[25];
    const float* ln3g = (const float*)d_in[26]; const float* ln3b = (const float*)d_in[27];

    const float SC = 0.18033688011112042f;     // 0.125 * log2(e)

    char* W = (char*)d_ws;
    #define OFS(mb) ((void*)(W + (size_t)(mb) * 1024 * 1024))
    ushort* x0b    = (ushort*)OFS(0);    // alive through ln1 (residual)
    ushort* encb   = (ushort*)OFS(8);
    ushort* WqkvT1 = (ushort*)OFS(16);
    ushort* Wo1T   = (ushort*)OFS(22);
    ushort* Wq2T   = (ushort*)OFS(24);
    ushort* WkvT2  = (ushort*)OFS(26);
    ushort* Wo2T   = (ushort*)OFS(30);
    ushort* Wf1T   = (ushort*)OFS(32);
    ushort* Wf2T   = (ushort*)OFS(36);
    float*  biasQKV1 = (float*)OFS(40);
    float*  biasKV2  = (float*)((char*)OFS(40) + 16384);
    float*  biasQ2   = (float*)((char*)OFS(40) + 32768);
    ushort* QKV1   = (ushort*)OFS(41);   // [3][B][H][S][D] (V region unused)
    ushort* VT1    = (ushort*)OFS(65);
    ushort* att1b  = (ushort*)OFS(73);
    ushort* o1b    = (ushort*)OFS(81);
    ushort* out1b  = (ushort*)OFS(57);   // bf16 residual 1 (alive thru ln2)
    ushort* Q2     = (ushort*)OFS(65);
    ushort* KV2    = (ushort*)OFS(73);   // [2][B][H][S][D] (V region unused)
    ushort* VT2    = (ushort*)OFS(90);   // moved off 0: x0b alive until ln1
    ushort* att2b  = (ushort*)OFS(8);
    ushort* o2b    = (ushort*)OFS(65);
    ushort* out2b  = (ushort*)OFS(0);    // bf16 residual 2 (x0b dead after ln1)
    ushort* ff1b   = (ushort*)OFS(41);
    ushort* ff2b   = (ushort*)OFS(81);   // o1b dead after ln1
    float*  out    = (float*)d_out;
    const size_t MAT = (size_t)B_ * H_ * S_ * D_;   // 4 Mi elements

    dim3 blk(256);

    // ---- prep (6 launches) ----
    cast2_k<<<8192, blk, 0, stream>>>(input, enc, x0b, encb);
    biasp_k<<<24, blk, 0, stream>>>(bq1, bk1, bv1, bk2, bv2, bq2, biasQKV1, SC);
    wtransH_k<<<dim3(2, 32, 96), blk, 0, stream>>>(Wq1, Wk1, Wv1, Wq2, Wk2, Wv2,
                                                   WqkvT1, Wq2T, WkvT2, SC);
    wtrans_k<<<dim3(32, 32, 2), blk, 0, stream>>>(Wo1, Wo2, Wo1T, Wo2T, 1024, 1024);
    wtrans_k<<<dim3(64, 32, 1), blk, 0, stream>>>(Wf1, Wf1, Wf1T, Wf1T, 1024, 2048);
    wtrans_k<<<dim3(32, 64, 1), blk, 0, stream>>>(Wf2, Wf2, Wf2T, Wf2T, 2048, 1024);

    // ---- masked self-attention ----
    gemm_bf16_k<128, 128, 64, 2, 0><<<dim3(24, 32), blk, 0, stream>>>(
        x0b, WqkvT1, biasQKV1, QKV1, VT1, 2, 3072, 1024);
    fattn_k<1><<<dim3(512), blk, 0, stream>>>(QKV1, QKV1 + MAT, VT1, att1b, S_);
    gemm_bf16_k<64, 64, 64, 1, 0><<<dim3(16, 64), blk, 0, stream>>>(
        att1b, Wo1T, bo1, o1b, nullptr, 9, 1024, 1024);
    ln_k<0><<<dim3(R_), blk, 0, stream>>>(o1b, x0b, ln1g, ln1b, out1b, nullptr);

    // ---- cross-attention ----
    gemm_bf16_k<64, 64, 64, 2, 0><<<dim3(16, 64), blk, 0, stream>>>(
        out1b, Wq2T, biasQ2, Q2, nullptr, 9, 1024, 1024);
    gemm_bf16_k<128, 128, 64, 2, 0><<<dim3(16, 32), blk, 0, stream>>>(
        encb, WkvT2, biasKV2, KV2, VT2, 1, 2048, 1024);
    fattn_k<0><<<dim3(512), blk, 0, stream>>>(Q2, KV2, VT2, att2b, S_);
    gemm_bf16_k<64, 64, 64, 1, 0><<<dim3(16, 64), blk, 0, stream>>>(
        att2b, Wo2T, bo2, o2b, nullptr, 9, 1024, 1024);
    ln_k<0><<<dim3(R_), blk, 0, stream>>>(o2b, out1b, ln2g, ln2b, out2b, nullptr);

    // ---- FFN ----
    gemm_bf16_k<128, 64, 64, 1, 1><<<dim3(32, 32), blk, 0, stream>>>(
        out2b, Wf1T, bf1, ff1b, nullptr, 9, 2048, 1024);
    gemm_bf16_k<64, 64, 64, 1, 0><<<dim3(16, 64), blk, 0, stream>>>(
        ff1b, Wf2T, bf2, ff2b, nullptr, 9, 1024, 2048);
    ln_k<1><<<dim3(R_), blk, 0, stream>>>(ff2b, out2b, ln3g, ln3b, nullptr, out);
    #undef OFS
}

// Round 22
// 282.800 us; speedup vs baseline: 1.1610x; 1.0312x over previous
//
#include <hip/hip_runtime.h>
#include <math.h>

#define B_ 2
#define S_ 2048
#define M_ 1024
#define H_ 16
#define D_ 64
#define R_ (B_*S_)          // 4096 rows

typedef __attribute__((ext_vector_type(8))) short short8v;    // 8 bf16 = 4 VGPR
typedef __attribute__((ext_vector_type(4))) float float4v;
typedef __attribute__((ext_vector_type(16))) float float16v; // 32x32 C/D

__device__ __forceinline__ float4 ld4(const float* p) {
    return *(const float4* __restrict__)p;
}

__device__ __forceinline__ ushort f2bf(float f) {            // RNE
    union { float f; unsigned u; } x; x.f = f;
    unsigned u = x.u + 0x7fffu + ((x.u >> 16) & 1u);
    return (ushort)(u >> 16);
}
__device__ __forceinline__ float bf2f(ushort s) {
    union { unsigned u; float f; } x; x.u = ((unsigned)s) << 16; return x.f;
}
__device__ __forceinline__ unsigned cvtpk(float lo, float hi) {
    unsigned r;
    asm("v_cvt_pk_bf16_f32 %0, %1, %2" : "=v"(r) : "v"(lo), "v"(hi));
    return r;
}
#if __has_builtin(__builtin_amdgcn_exp2f)
__device__ __forceinline__ float fexp2(float x) { return __builtin_amdgcn_exp2f(x); }
#else
__device__ __forceinline__ float fexp2(float x) { return exp2f(x); }
#endif
#if __has_builtin(__builtin_amdgcn_rcpf)
__device__ __forceinline__ float frcp(float x) { return __builtin_amdgcn_rcpf(x); }
#else
__device__ __forceinline__ float frcp(float x) { return 1.f / x; }
#endif
__device__ __forceinline__ float4v mfma16(short8v a, short8v b, float4v c) {
    return __builtin_amdgcn_mfma_f32_16x16x32_bf16(a, b, c, 0, 0, 0);
}
__device__ __forceinline__ float16v mfma32(short8v a, short8v b, float16v c) {
    return __builtin_amdgcn_mfma_f32_32x32x16_bf16(a, b, c, 0, 0, 0);
}
__device__ __forceinline__ void glds16(const void* g, void* l) {
    __builtin_amdgcn_global_load_lds(
        (const __attribute__((address_space(1))) void*)g,
        (__attribute__((address_space(3))) void*)l, 16, 0, 0);
}

// ---------------------------------------------------------------------------
// Fully fused prep: one launch, block-range dispatch (branches block-uniform).
// [0,8192)        cast input+enc -> bf16
// [8192,8216)     bias packs (6 segments, scaled)
// [8216,14360)    head-stacked weight transposes (6 x 16 heads)
// [14360,16408)   Wo1/Wo2 transpose pair
// [16408,18456)   Wf1 transpose
// [18456,20504)   Wf2 transpose
// ---------------------------------------------------------------------------
__device__ __forceinline__ void trans32(const float* __restrict__ ib,
                                        ushort* __restrict__ ob,
                                        int K, int N, int k0, int n0,
                                        float scale, float t[32][33], int tid) {
    const int tx = tid & 31, ty = tid >> 5;
    #pragma unroll
    for (int i = 0; i < 4; ++i)
        t[ty + i * 8][tx] = ib[(size_t)(k0 + ty + i * 8) * N + n0 + tx];
    __syncthreads();
    #pragma unroll
    for (int i = 0; i < 4; ++i)
        ob[(size_t)(n0 + ty + i * 8) * K + k0 + tx] = f2bf(t[tx][ty + i * 8] * scale);
}

__global__ __launch_bounds__(256) void prep_k(
    const float* __restrict__ input, const float* __restrict__ enc,
    ushort* __restrict__ x0b, ushort* __restrict__ encb,
    const float* __restrict__ bq1, const float* __restrict__ bk1,
    const float* __restrict__ bv1, const float* __restrict__ bk2,
    const float* __restrict__ bv2, const float* __restrict__ bq2,
    float* __restrict__ biasDst,
    const float* __restrict__ Wq1, const float* __restrict__ Wk1,
    const float* __restrict__ Wv1, const float* __restrict__ Wq2,
    const float* __restrict__ Wk2, const float* __restrict__ Wv2,
    ushort* __restrict__ oQKV1, ushort* __restrict__ oQ2,
    ushort* __restrict__ oKV2,
    const float* __restrict__ Wo1, const float* __restrict__ Wo2,
    ushort* __restrict__ Wo1T, ushort* __restrict__ Wo2T,
    const float* __restrict__ Wf1, ushort* __restrict__ Wf1T,
    const float* __restrict__ Wf2, ushort* __restrict__ Wf2T,
    float SCv)
{
    __shared__ float t[32][33];
    const int blk = blockIdx.x, tid = threadIdx.x;

    if (blk < 8192) {                       // input/enc cast
        size_t u = (size_t)blk * 256 + tid;
        const float* in; ushort* out;
        if (u < (1u << 20)) { in = input; out = x0b; }
        else { u -= (1u << 20); in = enc; out = encb; }
        float4 v = ld4(in + u * 4);
        ushort4 o = { f2bf(v.x), f2bf(v.y), f2bf(v.z), f2bf(v.w) };
        *(ushort4*)&out[u * 4] = o;
    } else if (blk < 8216) {                // bias packs
        const int lb = blk - 8192;
        const int seg = lb >> 2;
        const int li = (lb & 3) * 256 + tid;
        const float* s; int off; float sc;
        switch (seg) {
            case 0: s = bq1; off = 0;    sc = SCv; break;
            case 1: s = bk1; off = 1024; sc = 1.f; break;
            case 2: s = bv1; off = 2048; sc = 1.f; break;
            case 3: s = bk2; off = 4096; sc = 1.f; break;
            case 4: s = bv2; off = 5120; sc = 1.f; break;
            default: s = bq2; off = 8192; sc = SCv; break;
        }
        biasDst[off + li] = s[li] * sc;
    } else if (blk < 14360) {               // head-stacked weight transposes
        const int local = blk - 8216;
        const int x = local & 1, y = (local >> 1) & 31, z = local >> 6;
        const int s6 = z >> 4, h = z & 15;
        const float* srcs[6] = { Wq1, Wk1, Wv1, Wq2, Wk2, Wv2 };
        const float* ib = srcs[s6] + (size_t)h * 1024 * 64;
        ushort* ob;
        if (s6 < 3)       ob = oQKV1 + (size_t)s6 * (1024 * 1024) + (size_t)h * (64 * 1024);
        else if (s6 == 3) ob = oQ2 + (size_t)h * (64 * 1024);
        else              ob = oKV2 + (size_t)(s6 - 4) * (1024 * 1024) + (size_t)h * (64 * 1024);
        const float scale = (s6 == 0 || s6 == 3) ? SCv : 1.f;
        trans32(ib, ob, 1024, 64, y * 32, x * 32, scale, t, tid);
    } else if (blk < 16408) {               // Wo1/Wo2
        const int local = blk - 14360;
        const int x = local & 31, y = (local >> 5) & 31, z = local >> 10;
        trans32(z ? Wo2 : Wo1, z ? Wo2T : Wo1T, 1024, 1024, y * 32, x * 32, 1.f, t, tid);
    } else if (blk < 18456) {               // Wf1 (K=1024, N=2048)
        const int local = blk - 16408;
        const int x = local & 63, y = local >> 6;
        trans32(Wf1, Wf1T, 1024, 2048, y * 32, x * 32, 1.f, t, tid);
    } else {                                // Wf2 (K=2048, N=1024)
        const int local = blk - 18456;
        const int x = local & 31, y = local >> 5;
        trans32(Wf2, Wf2T, 2048, 1024, y * 32, x * 32, 1.f, t, tid);
    }
}

// ---------------------------------------------------------------------------
// bf16 MFMA GEMM, TMxTN tile, BK templated, 256 thr (4 waves 2x2). XOR-swizzled.
// ---------------------------------------------------------------------------
template<int TM, int TN, int BK, int OUTMODE, int ACT>
__global__ __launch_bounds__(256) void gemm_bf16_k(
    const ushort* __restrict__ A, const ushort* __restrict__ Bt,
    const float* __restrict__ bias, void* __restrict__ C,
    ushort* __restrict__ Cvt, int matV, int N, int K)
{
    constexpr int NI = TM / 32;
    constexpr int NJ = TN / 32;
    constexpr int KS = BK / 32;
    constexpr int CHR = BK / 8;                 // 16B chunks per row
    __shared__ __align__(16) ushort At[TM * BK];
    __shared__ __align__(16) ushort Bts[TN * BK];
    const int tid = threadIdx.x, lane = tid & 63, w = tid >> 6;
    const int wm = w >> 1, wn = w & 1;
    const int q = lane & 15, g = lane >> 4;
    const int m0 = blockIdx.y * TM, n0 = blockIdx.x * TN;

    float4v acc[NI][NJ];
    #pragma unroll
    for (int i = 0; i < NI; ++i)
        #pragma unroll
        for (int j = 0; j < NJ; ++j) acc[i][j] = (float4v){0.f, 0.f, 0.f, 0.f};

    for (int k0 = 0; k0 < K; k0 += BK) {
        #pragma unroll
        for (int t = 0; t < TM * CHR / 256; ++t) {
            const int cb = (w * (TM * CHR / 256) + t) * 64;
            const int c = cb + lane;
            const int row = c / CHR, kc = (c % CHR) ^ (row & (CHR - 1));
            glds16(&A[(size_t)(m0 + row) * K + k0 + kc * 8], &At[cb * 8]);
        }
        #pragma unroll
        for (int t = 0; t < TN * CHR / 256; ++t) {
            const int cb = (w * (TN * CHR / 256) + t) * 64;
            const int c = cb + lane;
            const int row = c / CHR, kc = (c % CHR) ^ (row & (CHR - 1));
            glds16(&Bt[(size_t)(n0 + row) * K + k0 + kc * 8], &Bts[cb * 8]);
        }
        __syncthreads();
        #pragma unroll
        for (int ks = 0; ks < KS; ++ks) {
            short8v af[NI], bf[NJ];
            #pragma unroll
            for (int i = 0; i < NI; ++i) {
                const int row = wm * (TM / 2) + i * 16 + q;
                af[i] = *(const short8v*)((const char*)At +
                        row * (BK * 2) + (((ks * 4 + g) ^ (q & (CHR - 1))) << 4));
            }
            #pragma unroll
            for (int j = 0; j < NJ; ++j) {
                const int row = wn * (TN / 2) + j * 16 + q;
                bf[j] = *(const short8v*)((const char*)Bts +
                        row * (BK * 2) + (((ks * 4 + g) ^ (q & (CHR - 1))) << 4));
            }
            #pragma unroll
            for (int i = 0; i < NI; ++i)
                #pragma unroll
                for (int j = 0; j < NJ; ++j)
                    acc[i][j] = mfma16(af[i], bf[j], acc[i][j]);
        }
        __syncthreads();
    }

    float bcol[NJ];
    #pragma unroll
    for (int j = 0; j < NJ; ++j) bcol[j] = bias[n0 + wn * (TN / 2) + j * 16 + q];

    #pragma unroll
    for (int i = 0; i < NI; ++i) {
        const int rowg0 = m0 + wm * (TM / 2) + i * 16 + g * 4;
        #pragma unroll
        for (int j = 0; j < NJ; ++j) {
            const int colg = n0 + wn * (TN / 2) + j * 16 + q;
            float v[4];
            #pragma unroll
            for (int r = 0; r < 4; ++r) {
                v[r] = acc[i][j][r] + bcol[j];
                if (ACT) v[r] = fmaxf(v[r], 0.f);
            }
            if (OUTMODE == 0) {
                #pragma unroll
                for (int r = 0; r < 4; ++r)
                    ((float*)C)[(size_t)(rowg0 + r) * N + colg] = v[r];
            } else if (OUTMODE == 1) {
                #pragma unroll
                for (int r = 0; r < 4; ++r)
                    ((ushort*)C)[(size_t)(rowg0 + r) * N + colg] = f2bf(v[r]);
            } else {
                const int mat = colg >> 10, h = (colg >> 6) & 15, d = colg & 63;
                const int bb = rowg0 >> 11, s0 = rowg0 & 2047;
                if (mat == matV) {   // V -> transposed layout [bh][d][s]
                    uint2 pv;
                    pv.x = cvtpk(v[0], v[1]);
                    pv.y = cvtpk(v[2], v[3]);
                    *(uint2*)&Cvt[((size_t)(bb * H_ + h) * D_ + d) * S_ + s0] = pv;
                } else {
                    #pragma unroll
                    for (int r = 0; r < 4; ++r)
                        ((ushort*)C)[((((size_t)(mat * B_ + bb) * H_ + h) * S_) + s0 + r) * D_ + d] = f2bf(v[r]);
                }
            }
        }
    }
}

// ---------------------------------------------------------------------------
// Flash attention, 32x32x16 bf16 MFMA, swapped form, STATIC-MAX softmax.
// R20-measured-best: kv-tile 128 (two 64-halves per barrier interval).
// ---------------------------------------------------------------------------
template<int CAUSAL>
__global__ __launch_bounds__(256, 2) void fattn_k(
    const ushort* __restrict__ Qg, const ushort* __restrict__ Kg,
    const ushort* __restrict__ VTg, ushort* __restrict__ Og, int Skv)
{
    __shared__ __align__(16) ushort Kt[2][128 * 64];  // [kv][d] swizzled, 16 KB x2
    __shared__ __align__(16) ushort Vt[2][64 * 128];  // [d][kv] swizzled, 16 KB x2
    const int tid = threadIdx.x, lane = tid & 63, w = tid >> 6;   // w 0..3
    const int q = lane & 31, hi = lane >> 5;
    const int id = blockIdx.x;
    const int bh = id & 31;
    const int t_ = id >> 5;
    const int qb = CAUSAL ? ((t_ < 8) ? (15 - t_) : (t_ - 8)) : t_;
    const int q0b = qb * 128;
    const int q0w = q0b + w * 32;
    const float MB = 24.f;                            // static exponent bias

    // staging sources: K 1024 chunks (4/thr), V 1024 chunks (4/thr), pre-swizzled
    const ushort* kS[4]; const ushort* vS[4];
    #pragma unroll
    for (int i = 0; i < 4; ++i) {
        const int c = i * 256 + tid;
        const int rk = c >> 3, chk = c & 7;
        kS[i] = Kg + ((size_t)bh * Skv + rk) * 64 + ((chk ^ (rk & 7)) * 8);
        const int rv = c >> 4, chv = c & 15;
        vS[i] = VTg + ((size_t)bh * 64 + rv) * (size_t)Skv + ((chv ^ (rv & 15)) * 8);
    }

#define STAGE(nb) do { \
        glds16(kS[0], &Kt[nb][(tid) * 8]); \
        glds16(kS[1], &Kt[nb][(tid + 256) * 8]); \
        glds16(kS[2], &Kt[nb][(tid + 512) * 8]); \
        glds16(kS[3], &Kt[nb][(tid + 768) * 8]); \
        glds16(vS[0], &Vt[nb][(tid) * 8]); \
        glds16(vS[1], &Vt[nb][(tid + 256) * 8]); \
        glds16(vS[2], &Vt[nb][(tid + 512) * 8]); \
        glds16(vS[3], &Vt[nb][(tid + 768) * 8]); \
        kS[0] += 128 * 64; kS[1] += 128 * 64; kS[2] += 128 * 64; kS[3] += 128 * 64; \
        vS[0] += 128; vS[1] += 128; vS[2] += 128; vS[3] += 128; } while (0)

    // Q B-fragments (Q pre-scaled by 0.125*log2e): B[k=d][col=q], k=ki*16+hi*8+e
    short8v qf[4];
    #pragma unroll
    for (int ki = 0; ki < 4; ++ki)
        qf[ki] = *(const short8v*)&Qg[((size_t)bh * S_ + q0w + q) * 64 + ki * 16 + hi * 8];

    // K LDS base (within a 64-kv half): row=q, chunk=(2ki+hi)^(q&7) -> ^ (ki<<5)
    const int ktB = q * 128 + ((hi ^ (q & 7)) << 4);

    float16v oacc0, oacc1;
    #pragma unroll
    for (int r = 0; r < 16; ++r) { oacc0[r] = 0.f; oacc1[r] = 0.f; }
    float l_ = 0.f;

    const int ktiles = CAUSAL ? (qb + 1) : (Skv >> 7);
    int cur = 0;

    STAGE(0);
    __syncthreads();

    for (int kt = 0; kt < ktiles; ++kt) {
        if (kt + 1 < ktiles) STAGE(cur ^ 1);          // issue-early
        const char* ktp = (const char*)Kt[cur];
        const char* vtp = (const char*)Vt[cur];

        #pragma unroll
        for (int h = 0; h < 2; ++h) {                 // two 64-kv halves
            const int kv0 = kt * 128 + h * 64;
            const char* ktph = ktp + h * 8192;        // rows h*64..h*64+63

            // S^T = K . Q^T : two kv-32 blocks, K=16 chunks over d
            float16v st0, st1;
            #pragma unroll
            for (int r = 0; r < 16; ++r) { st0[r] = 0.f; st1[r] = 0.f; }
            __builtin_amdgcn_s_setprio(1);
            #pragma unroll
            for (int ki = 0; ki < 4; ++ki) {
                short8v kf0 = *(const short8v*)(ktph + (ktB ^ (ki << 5)));
                short8v kf1 = *(const short8v*)(ktph + (ktB ^ (ki << 5)) + 4096);
                st0 = mfma32(kf0, qf[ki], st0);
                st1 = mfma32(kf1, qf[ki], st1);
            }
            __builtin_amdgcn_s_setprio(0);

            if (CAUSAL && kv0 + 63 > q0b) {           // diagonal-region halves only
                const int qg_ = q0w + q;
                #pragma unroll
                for (int r = 0; r < 16; ++r) {
                    const int row = (r & 3) + 8 * (r >> 2) + 4 * hi;
                    if (kv0 + row > qg_)      st0[r] = -1e9f;
                    if (kv0 + 32 + row > qg_) st1[r] = -1e9f;
                }
            }

            // STATIC-MAX: P = exp2(s - MB), exact (scale cancels in O = PV/l)
            float ts[16];
            #pragma unroll
            for (int r = 0; r < 16; ++r) {
                st0[r] = fexp2(st0[r] - MB);
                st1[r] = fexp2(st1[r] - MB);
                ts[r] = st0[r] + st1[r];
            }
            #pragma unroll
            for (int off = 8; off >= 1; off >>= 1)
                #pragma unroll
                for (int i = 0; i < 8; ++i)
                    if (i < off) ts[i] += ts[i + off];
            l_ += ts[0] + __shfl_xor(ts[0], 32);

            // pack P to bf16 words
            unsigned W0[8], W1[8];
            #pragma unroll
            for (int s = 0; s < 8; ++s) {
                W0[s] = cvtpk(st0[2 * s], st0[2 * s + 1]);
                W1[s] = cvtpk(st1[2 * s], st1[2 * s + 1]);
            }

            // build PV B-frags bq[kb]: P[kv0+kb*16+hi*8+e][q] (R14-verified)
            short8v bq[4];
            #pragma unroll
            for (int kb = 0; kb < 4; ++kb) {
                union { unsigned u[4]; short8v v; } bb;
                #pragma unroll
                for (int j = 0; j < 4; ++j) {
                    const unsigned* Wb = (kb >> 1) ? W1 : W0;
                    const int s0 = (j & 1) + 4 * (kb & 1);
                    const unsigned own  = hi ? Wb[s0 + 2] : Wb[s0];
                    const unsigned send = hi ? Wb[s0]     : Wb[s0 + 2];
                    const unsigned rec  = (unsigned)__shfl_xor((int)send, 32);
                    bb.u[j] = (j >> 1) ? (hi ? own : rec) : (hi ? rec : own);
                }
                bq[kb] = bb.v;
            }

            // O^T += V^T . P^T : kv-chunk x = h*8 + 2kb + hi on 256B rows
            __builtin_amdgcn_s_setprio(1);
            #pragma unroll
            for (int kb = 0; kb < 4; ++kb) {
                const int x = h * 8 + 2 * kb + hi;
                short8v vf0 = *(const short8v*)(vtp +
                              q * 256 + ((x ^ (q & 15)) << 4));
                short8v vf1 = *(const short8v*)(vtp +
                              (32 + q) * 256 + ((x ^ (q & 15)) << 4));
                oacc0 = mfma32(vf0, bq[kb], oacc0);
                oacc1 = mfma32(vf1, bq[kb], oacc1);
            }
            __builtin_amdgcn_s_setprio(0);
        }

        __syncthreads();       // ONE drain+barrier per 128 kv
        cur ^= 1;
    }
#undef STAGE

    // normalize + stage O into Kt region (dead), swizzled; then coalesced out
    const float inv = frcp(l_);
    char* Ob = (char*)Kt;
    const int qr = w * 32 + q;
    #pragma unroll
    for (int s = 0; s < 8; ++s) {
        const int d0a = 2 * (s & 1) + 8 * (s >> 1) + 4 * hi;        // db=0
        unsigned wa = cvtpk(oacc0[2 * s] * inv, oacc0[2 * s + 1] * inv);
        *(unsigned*)(Ob + qr * 128 + ((((d0a >> 3) ^ (qr & 7)) << 4) | ((2 * d0a) & 15))) = wa;
        const int d0b = d0a + 32;                                    // db=1
        unsigned wb = cvtpk(oacc1[2 * s] * inv, oacc1[2 * s + 1] * inv);
        *(unsigned*)(Ob + qr * 128 + ((((d0b >> 3) ^ (qr & 7)) << 4) | ((2 * d0b) & 15))) = wb;
    }
    __syncthreads();
    const int b = bh >> 4, h2 = bh & 15;
    #pragma unroll
    for (int t = 0; t < 4; ++t) {
        const int c = t * 256 + tid;
        const int qrow = c >> 3, ch = c & 7;
        short8v v = *(const short8v*)(Ob + qrow * 128 + ((ch ^ (qrow & 7)) << 4));
        *(short8v*)&Og[((size_t)(b * S_ + q0b + qrow)) * M_ + h2 * 64 + ch * 8] = v;
    }
}

// ---------------------------------------------------------------------------
// Fused residual-add + LayerNorm, bf16 residual chain.
// X bf16, Rz bf16; OUTF=0: emit bf16; OUTF=1: emit fp32 (final output).
// ---------------------------------------------------------------------------
template<int OUTF>
__global__ __launch_bounds__(256) void ln_k(
    const ushort* __restrict__ X, const ushort* __restrict__ Rz,
    const float* __restrict__ g, const float* __restrict__ be,
    ushort* __restrict__ outb, float* __restrict__ outf)
{
    __shared__ float red[8];
    const int row = blockIdx.x, tid = threadIdx.x;
    const int lane = tid & 63, w = tid >> 6;

    ushort4 xu = *(const ushort4*)&X[(size_t)row * M_ + tid * 4];
    ushort4 ru = *(const ushort4*)&Rz[(size_t)row * M_ + tid * 4];
    float4 x = make_float4(bf2f(xu.x) + bf2f(ru.x), bf2f(xu.y) + bf2f(ru.y),
                           bf2f(xu.z) + bf2f(ru.z), bf2f(xu.w) + bf2f(ru.w));

    float sm = x.x + x.y + x.z + x.w;
    #pragma unroll
    for (int off = 1; off < 64; off <<= 1) sm += __shfl_xor(sm, off);
    if (lane == 0) red[w] = sm;
    __syncthreads();
    const float mean = (red[0] + red[1] + red[2] + red[3]) * (1.f / M_);

    x.x -= mean; x.y -= mean; x.z -= mean; x.w -= mean;
    float vs = x.x * x.x + x.y * x.y + x.z * x.z + x.w * x.w;
    #pragma unroll
    for (int off = 1; off < 64; off <<= 1) vs += __shfl_xor(vs, off);
    if (lane == 0) red[4 + w] = vs;
    __syncthreads();
    const float var = (red[4] + red[5] + red[6] + red[7]) * (1.f / M_);
    const float rs = rsqrtf(var + 1e-5f);

    float4 gg = ld4(g + tid * 4), bb = ld4(be + tid * 4);
    float4 y = make_float4(x.x * rs * gg.x + bb.x, x.y * rs * gg.y + bb.y,
                           x.z * rs * gg.z + bb.z, x.w * rs * gg.w + bb.w);
    if (OUTF) {
        *(float4*)(outf + (size_t)row * M_ + tid * 4) = y;
    } else {
        ushort4 ob = { f2bf(y.x), f2bf(y.y), f2bf(y.z), f2bf(y.w) };
        *(ushort4*)&outb[(size_t)row * M_ + tid * 4] = ob;
    }
}

// ---------------------------------------------------------------------------
extern "C" void kernel_launch(void* const* d_in, const int* in_sizes, int n_in,
                              void* d_out, int out_size, void* d_ws, size_t ws_size,
                              hipStream_t stream)
{
    const float* input = (const float*)d_in[0];
    const float* enc   = (const float*)d_in[1];
    const float* Wq1 = (const float*)d_in[2];  const float* bq1 = (const float*)d_in[3];
    const float* Wk1 = (const float*)d_in[4];  const float* bk1 = (const float*)d_in[5];
    const float* Wv1 = (const float*)d_in[6];  const float* bv1 = (const float*)d_in[7];
    const float* Wo1 = (const float*)d_in[8];  const float* bo1 = (const float*)d_in[9];
    const float* ln1g = (const float*)d_in[10]; const float* ln1b = (const float*)d_in[11];
    const float* Wq2 = (const float*)d_in[12]; const float* bq2 = (const float*)d_in[13];
    const float* Wk2 = (const float*)d_in[14]; const float* bk2 = (const float*)d_in[15];
    const float* Wv2 = (const float*)d_in[16]; const float* bv2 = (const float*)d_in[17];
    const float* Wo2 = (const float*)d_in[18]; const float* bo2 = (const float*)d_in[19];
    const float* ln2g = (const float*)d_in[20]; const float* ln2b = (const float*)d_in[21];
    const float* Wf1 = (const float*)d_in[22]; const float* bf1 = (const float*)d_in[23];
    const float* Wf2 = (const float*)d_in[24]; const float* bf2 = (const float*)d_in[25];
    const float* ln3g = (const float*)d_in[26]; const float* ln3b = (const float*)d_in[27];

    const float SC = 0.18033688011112042f;     // 0.125 * log2(e)

    char* W = (char*)d_ws;
    #define OFS(mb) ((void*)(W + (size_t)(mb) * 1024 * 1024))
    ushort* x0b    = (ushort*)OFS(0);    // alive through ln1 (residual)
    ushort* encb   = (ushort*)OFS(8);
    ushort* WqkvT1 = (ushort*)OFS(16);
    ushort* Wo1T   = (ushort*)OFS(22);
    ushort* Wq2T   = (ushort*)OFS(24);
    ushort* WkvT2  = (ushort*)OFS(26);
    ushort* Wo2T   = (ushort*)OFS(30);
    ushort* Wf1T   = (ushort*)OFS(32);
    ushort* Wf2T   = (ushort*)OFS(36);
    float*  biasQKV1 = (float*)OFS(40);
    float*  biasQ2   = (float*)((char*)OFS(40) + 32768);
    ushort* QKV1   = (ushort*)OFS(41);   // [3][B][H][S][D] (V region unused)
    ushort* VT1    = (ushort*)OFS(65);
    ushort* att1b  = (ushort*)OFS(73);
    ushort* o1b    = (ushort*)OFS(81);
    ushort* out1b  = (ushort*)OFS(57);   // bf16 residual 1 (alive thru ln2)
    ushort* Q2     = (ushort*)OFS(65);
    ushort* KV2    = (ushort*)OFS(73);   // [2][B][H][S][D] (V region unused)
    ushort* VT2    = (ushort*)OFS(90);   // x0b alive until ln1
    ushort* att2b  = (ushort*)OFS(8);
    ushort* o2b    = (ushort*)OFS(65);
    ushort* out2b  = (ushort*)OFS(0);    // bf16 residual 2 (x0b dead after ln1)
    ushort* ff1b   = (ushort*)OFS(41);
    ushort* ff2b   = (ushort*)OFS(81);   // o1b dead after ln1
    float*  out    = (float*)d_out;
    const size_t MAT = (size_t)B_ * H_ * S_ * D_;   // 4 Mi elements

    dim3 blk(256);

    // ---- prep (ONE launch, 20504 blocks) ----
    prep_k<<<dim3(20504), blk, 0, stream>>>(
        input, enc, x0b, encb,
        bq1, bk1, bv1, bk2, bv2, bq2, biasQKV1,
        Wq1, Wk1, Wv1, Wq2, Wk2, Wv2, WqkvT1, Wq2T, WkvT2,
        Wo1, Wo2, Wo1T, Wo2T, Wf1, Wf1T, Wf2, Wf2T, SC);

    // ---- masked self-attention ----
    gemm_bf16_k<128, 128, 64, 2, 0><<<dim3(24, 32), blk, 0, stream>>>(
        x0b, WqkvT1, biasQKV1, QKV1, VT1, 2, 3072, 1024);
    fattn_k<1><<<dim3(512), blk, 0, stream>>>(QKV1, QKV1 + MAT, VT1, att1b, S_);
    gemm_bf16_k<64, 64, 64, 1, 0><<<dim3(16, 64), blk, 0, stream>>>(
        att1b, Wo1T, bo1, o1b, nullptr, 9, 1024, 1024);
    ln_k<0><<<dim3(R_), blk, 0, stream>>>(o1b, x0b, ln1g, ln1b, out1b, nullptr);

    // ---- cross-attention ----
    gemm_bf16_k<64, 64, 64, 2, 0><<<dim3(16, 64), blk, 0, stream>>>(
        out1b, Wq2T, biasQ2, Q2, nullptr, 9, 1024, 1024);
    gemm_bf16_k<128, 128, 64, 2, 0><<<dim3(16, 32), blk, 0, stream>>>(
        encb, WkvT2, biasQKV1 + 4096, KV2, VT2, 1, 2048, 1024);
    fattn_k<0><<<dim3(512), blk, 0, stream>>>(Q2, KV2, VT2, att2b, S_);
    gemm_bf16_k<64, 64, 64, 1, 0><<<dim3(16, 64), blk, 0, stream>>>(
        att2b, Wo2T, bo2, o2b, nullptr, 9, 1024, 1024);
    ln_k<0><<<dim3(R_), blk, 0, stream>>>(o2b, out1b, ln2g, ln2b, out2b, nullptr);

    // ---- FFN ----
    gemm_bf16_k<128, 64, 64, 1, 1><<<dim3(32, 32), blk, 0, stream>>>(
        out2b, Wf1T, bf1, ff1b, nullptr, 9, 2048, 1024);
    gemm_bf16_k<64, 64, 64, 1, 0><<<dim3(16, 64), blk, 0, stream>>>(
        ff1b, Wf2T, bf2, ff2b, nullptr, 9, 1024, 2048);
    ln_k<1><<<dim3(R_), blk, 0, stream>>>(ff2b, out2b, ln3g, ln3b, nullptr, out);
    #undef OFS
}

// Round 23
// 275.463 us; speedup vs baseline: 1.1919x; 1.0266x over previous
//
#include <hip/hip_runtime.h>
#include <math.h>

#define B_ 2
#define S_ 2048
#define M_ 1024
#define H_ 16
#define D_ 64
#define R_ (B_*S_)          // 4096 rows

typedef __attribute__((ext_vector_type(8))) short short8v;    // 8 bf16 = 4 VGPR
typedef __attribute__((ext_vector_type(4))) float float4v;
typedef __attribute__((ext_vector_type(16))) float float16v; // 32x32 C/D

__device__ __forceinline__ float4 ld4(const float* p) {
    return *(const float4* __restrict__)p;
}

__device__ __forceinline__ ushort f2bf(float f) {            // RNE
    union { float f; unsigned u; } x; x.f = f;
    unsigned u = x.u + 0x7fffu + ((x.u >> 16) & 1u);
    return (ushort)(u >> 16);
}
__device__ __forceinline__ float bf2f(ushort s) {
    union { unsigned u; float f; } x; x.u = ((unsigned)s) << 16; return x.f;
}
__device__ __forceinline__ unsigned cvtpk(float lo, float hi) {
    unsigned r;
    asm("v_cvt_pk_bf16_f32 %0, %1, %2" : "=v"(r) : "v"(lo), "v"(hi));
    return r;
}
#if __has_builtin(__builtin_amdgcn_exp2f)
__device__ __forceinline__ float fexp2(float x) { return __builtin_amdgcn_exp2f(x); }
#else
__device__ __forceinline__ float fexp2(float x) { return exp2f(x); }
#endif
#if __has_builtin(__builtin_amdgcn_rcpf)
__device__ __forceinline__ float frcp(float x) { return __builtin_amdgcn_rcpf(x); }
#else
__device__ __forceinline__ float frcp(float x) { return 1.f / x; }
#endif
__device__ __forceinline__ float4v mfma16(short8v a, short8v b, float4v c) {
    return __builtin_amdgcn_mfma_f32_16x16x32_bf16(a, b, c, 0, 0, 0);
}
__device__ __forceinline__ float16v mfma32(short8v a, short8v b, float16v c) {
    return __builtin_amdgcn_mfma_f32_32x32x16_bf16(a, b, c, 0, 0, 0);
}
__device__ __forceinline__ void glds16(const void* g, void* l) {
    __builtin_amdgcn_global_load_lds(
        (const __attribute__((address_space(1))) void*)g,
        (__attribute__((address_space(3))) void*)l, 16, 0, 0);
}

// ---------------------------------------------------------------------------
// Fully fused prep: one launch, block-range dispatch (branches block-uniform).
// ---------------------------------------------------------------------------
__device__ __forceinline__ void trans32(const float* __restrict__ ib,
                                        ushort* __restrict__ ob,
                                        int K, int N, int k0, int n0,
                                        float scale, float t[32][33], int tid) {
    const int tx = tid & 31, ty = tid >> 5;
    #pragma unroll
    for (int i = 0; i < 4; ++i)
        t[ty + i * 8][tx] = ib[(size_t)(k0 + ty + i * 8) * N + n0 + tx];
    __syncthreads();
    #pragma unroll
    for (int i = 0; i < 4; ++i)
        ob[(size_t)(n0 + ty + i * 8) * K + k0 + tx] = f2bf(t[tx][ty + i * 8] * scale);
}

__global__ __launch_bounds__(256) void prep_k(
    const float* __restrict__ input, const float* __restrict__ enc,
    ushort* __restrict__ x0b, ushort* __restrict__ encb,
    const float* __restrict__ bq1, const float* __restrict__ bk1,
    const float* __restrict__ bv1, const float* __restrict__ bk2,
    const float* __restrict__ bv2, const float* __restrict__ bq2,
    float* __restrict__ biasDst,
    const float* __restrict__ Wq1, const float* __restrict__ Wk1,
    const float* __restrict__ Wv1, const float* __restrict__ Wq2,
    const float* __restrict__ Wk2, const float* __restrict__ Wv2,
    ushort* __restrict__ oQKV1, ushort* __restrict__ oQ2,
    ushort* __restrict__ oKV2,
    const float* __restrict__ Wo1, const float* __restrict__ Wo2,
    ushort* __restrict__ Wo1T, ushort* __restrict__ Wo2T,
    const float* __restrict__ Wf1, ushort* __restrict__ Wf1T,
    const float* __restrict__ Wf2, ushort* __restrict__ Wf2T,
    float SCv)
{
    __shared__ float t[32][33];
    const int blk = blockIdx.x, tid = threadIdx.x;

    if (blk < 8192) {                       // input/enc cast
        size_t u = (size_t)blk * 256 + tid;
        const float* in; ushort* out;
        if (u < (1u << 20)) { in = input; out = x0b; }
        else { u -= (1u << 20); in = enc; out = encb; }
        float4 v = ld4(in + u * 4);
        ushort4 o = { f2bf(v.x), f2bf(v.y), f2bf(v.z), f2bf(v.w) };
        *(ushort4*)&out[u * 4] = o;
    } else if (blk < 8216) {                // bias packs
        const int lb = blk - 8192;
        const int seg = lb >> 2;
        const int li = (lb & 3) * 256 + tid;
        const float* s; int off; float sc;
        switch (seg) {
            case 0: s = bq1; off = 0;    sc = SCv; break;
            case 1: s = bk1; off = 1024; sc = 1.f; break;
            case 2: s = bv1; off = 2048; sc = 1.f; break;
            case 3: s = bk2; off = 4096; sc = 1.f; break;
            case 4: s = bv2; off = 5120; sc = 1.f; break;
            default: s = bq2; off = 8192; sc = SCv; break;
        }
        biasDst[off + li] = s[li] * sc;
    } else if (blk < 14360) {               // head-stacked weight transposes
        const int local = blk - 8216;
        const int x = local & 1, y = (local >> 1) & 31, z = local >> 6;
        const int s6 = z >> 4, h = z & 15;
        const float* srcs[6] = { Wq1, Wk1, Wv1, Wq2, Wk2, Wv2 };
        const float* ib = srcs[s6] + (size_t)h * 1024 * 64;
        ushort* ob;
        if (s6 < 3)       ob = oQKV1 + (size_t)s6 * (1024 * 1024) + (size_t)h * (64 * 1024);
        else if (s6 == 3) ob = oQ2 + (size_t)h * (64 * 1024);
        else              ob = oKV2 + (size_t)(s6 - 4) * (1024 * 1024) + (size_t)h * (64 * 1024);
        const float scale = (s6 == 0 || s6 == 3) ? SCv : 1.f;
        trans32(ib, ob, 1024, 64, y * 32, x * 32, scale, t, tid);
    } else if (blk < 16408) {               // Wo1/Wo2
        const int local = blk - 14360;
        const int x = local & 31, y = (local >> 5) & 31, z = local >> 10;
        trans32(z ? Wo2 : Wo1, z ? Wo2T : Wo1T, 1024, 1024, y * 32, x * 32, 1.f, t, tid);
    } else if (blk < 18456) {               // Wf1 (K=1024, N=2048)
        const int local = blk - 16408;
        const int x = local & 63, y = local >> 6;
        trans32(Wf1, Wf1T, 1024, 2048, y * 32, x * 32, 1.f, t, tid);
    } else {                                // Wf2 (K=2048, N=1024)
        const int local = blk - 18456;
        const int x = local & 31, y = local >> 5;
        trans32(Wf2, Wf2T, 2048, 1024, y * 32, x * 32, 1.f, t, tid);
    }
}

// ---------------------------------------------------------------------------
// bf16 MFMA GEMM, TMxTN tile, BK templated, 256 thr (4 waves 2x2). XOR-swizzled.
// T1 XCD-aware tile remap: linearize (by,bx) -> swz = (id%8)*(nwg/8) + id/8
// (bijective: all grids %8==0) -> each XCD owns a contiguous tile chunk so
// neighbor tiles sharing A/B panels are L2-co-resident.
// ---------------------------------------------------------------------------
template<int TM, int TN, int BK, int OUTMODE, int ACT>
__global__ __launch_bounds__(256) void gemm_bf16_k(
    const ushort* __restrict__ A, const ushort* __restrict__ Bt,
    const float* __restrict__ bias, void* __restrict__ C,
    ushort* __restrict__ Cvt, int matV, int N, int K)
{
    constexpr int NI = TM / 32;
    constexpr int NJ = TN / 32;
    constexpr int KS = BK / 32;
    constexpr int CHR = BK / 8;                 // 16B chunks per row
    __shared__ __align__(16) ushort At[TM * BK];
    __shared__ __align__(16) ushort Bts[TN * BK];
    const int tid = threadIdx.x, lane = tid & 63, w = tid >> 6;
    const int wm = w >> 1, wn = w & 1;
    const int q = lane & 15, g = lane >> 4;

    // T1 XCD swizzle (nwg % 8 == 0 for every grid in this launch set)
    const int nwg = gridDim.x * gridDim.y;
    const int id0 = blockIdx.y * gridDim.x + blockIdx.x;
    const int swz = (id0 & 7) * (nwg >> 3) + (id0 >> 3);
    const int m0 = (swz / gridDim.x) * TM, n0 = (swz % gridDim.x) * TN;

    float4v acc[NI][NJ];
    #pragma unroll
    for (int i = 0; i < NI; ++i)
        #pragma unroll
        for (int j = 0; j < NJ; ++j) acc[i][j] = (float4v){0.f, 0.f, 0.f, 0.f};

    for (int k0 = 0; k0 < K; k0 += BK) {
        #pragma unroll
        for (int t = 0; t < TM * CHR / 256; ++t) {
            const int cb = (w * (TM * CHR / 256) + t) * 64;
            const int c = cb + lane;
            const int row = c / CHR, kc = (c % CHR) ^ (row & (CHR - 1));
            glds16(&A[(size_t)(m0 + row) * K + k0 + kc * 8], &At[cb * 8]);
        }
        #pragma unroll
        for (int t = 0; t < TN * CHR / 256; ++t) {
            const int cb = (w * (TN * CHR / 256) + t) * 64;
            const int c = cb + lane;
            const int row = c / CHR, kc = (c % CHR) ^ (row & (CHR - 1));
            glds16(&Bt[(size_t)(n0 + row) * K + k0 + kc * 8], &Bts[cb * 8]);
        }
        __syncthreads();
        #pragma unroll
        for (int ks = 0; ks < KS; ++ks) {
            short8v af[NI], bf[NJ];
            #pragma unroll
            for (int i = 0; i < NI; ++i) {
                const int row = wm * (TM / 2) + i * 16 + q;
                af[i] = *(const short8v*)((const char*)At +
                        row * (BK * 2) + (((ks * 4 + g) ^ (q & (CHR - 1))) << 4));
            }
            #pragma unroll
            for (int j = 0; j < NJ; ++j) {
                const int row = wn * (TN / 2) + j * 16 + q;
                bf[j] = *(const short8v*)((const char*)Bts +
                        row * (BK * 2) + (((ks * 4 + g) ^ (q & (CHR - 1))) << 4));
            }
            #pragma unroll
            for (int i = 0; i < NI; ++i)
                #pragma unroll
                for (int j = 0; j < NJ; ++j)
                    acc[i][j] = mfma16(af[i], bf[j], acc[i][j]);
        }
        __syncthreads();
    }

    float bcol[NJ];
    #pragma unroll
    for (int j = 0; j < NJ; ++j) bcol[j] = bias[n0 + wn * (TN / 2) + j * 16 + q];

    #pragma unroll
    for (int i = 0; i < NI; ++i) {
        const int rowg0 = m0 + wm * (TM / 2) + i * 16 + g * 4;
        #pragma unroll
        for (int j = 0; j < NJ; ++j) {
            const int colg = n0 + wn * (TN / 2) + j * 16 + q;
            float v[4];
            #pragma unroll
            for (int r = 0; r < 4; ++r) {
                v[r] = acc[i][j][r] + bcol[j];
                if (ACT) v[r] = fmaxf(v[r], 0.f);
            }
            if (OUTMODE == 0) {
                #pragma unroll
                for (int r = 0; r < 4; ++r)
                    ((float*)C)[(size_t)(rowg0 + r) * N + colg] = v[r];
            } else if (OUTMODE == 1) {
                #pragma unroll
                for (int r = 0; r < 4; ++r)
                    ((ushort*)C)[(size_t)(rowg0 + r) * N + colg] = f2bf(v[r]);
            } else {
                const int mat = colg >> 10, h = (colg >> 6) & 15, d = colg & 63;
                const int bb = rowg0 >> 11, s0 = rowg0 & 2047;
                if (mat == matV) {   // V -> transposed layout [bh][d][s]
                    uint2 pv;
                    pv.x = cvtpk(v[0], v[1]);
                    pv.y = cvtpk(v[2], v[3]);
                    *(uint2*)&Cvt[((size_t)(bb * H_ + h) * D_ + d) * S_ + s0] = pv;
                } else {
                    #pragma unroll
                    for (int r = 0; r < 4; ++r)
                        ((ushort*)C)[((((size_t)(mat * B_ + bb) * H_ + h) * S_) + s0 + r) * D_ + d] = f2bf(v[r]);
                }
            }
        }
    }
}

// ---------------------------------------------------------------------------
// Flash attention, 32x32x16 bf16 MFMA, swapped form, STATIC-MAX softmax.
// R20-measured-best: kv-tile 128 (two 64-halves per barrier interval).
// ---------------------------------------------------------------------------
template<int CAUSAL>
__global__ __launch_bounds__(256, 2) void fattn_k(
    const ushort* __restrict__ Qg, const ushort* __restrict__ Kg,
    const ushort* __restrict__ VTg, ushort* __restrict__ Og, int Skv)
{
    __shared__ __align__(16) ushort Kt[2][128 * 64];  // [kv][d] swizzled, 16 KB x2
    __shared__ __align__(16) ushort Vt[2][64 * 128];  // [d][kv] swizzled, 16 KB x2
    const int tid = threadIdx.x, lane = tid & 63, w = tid >> 6;   // w 0..3
    const int q = lane & 31, hi = lane >> 5;
    const int id = blockIdx.x;
    const int bh = id & 31;
    const int t_ = id >> 5;
    const int qb = CAUSAL ? ((t_ < 8) ? (15 - t_) : (t_ - 8)) : t_;
    const int q0b = qb * 128;
    const int q0w = q0b + w * 32;
    const float MB = 24.f;                            // static exponent bias

    // staging sources: K 1024 chunks (4/thr), V 1024 chunks (4/thr), pre-swizzled
    const ushort* kS[4]; const ushort* vS[4];
    #pragma unroll
    for (int i = 0; i < 4; ++i) {
        const int c = i * 256 + tid;
        const int rk = c >> 3, chk = c & 7;
        kS[i] = Kg + ((size_t)bh * Skv + rk) * 64 + ((chk ^ (rk & 7)) * 8);
        const int rv = c >> 4, chv = c & 15;
        vS[i] = VTg + ((size_t)bh * 64 + rv) * (size_t)Skv + ((chv ^ (rv & 15)) * 8);
    }

#define STAGE(nb) do { \
        glds16(kS[0], &Kt[nb][(tid) * 8]); \
        glds16(kS[1], &Kt[nb][(tid + 256) * 8]); \
        glds16(kS[2], &Kt[nb][(tid + 512) * 8]); \
        glds16(kS[3], &Kt[nb][(tid + 768) * 8]); \
        glds16(vS[0], &Vt[nb][(tid) * 8]); \
        glds16(vS[1], &Vt[nb][(tid + 256) * 8]); \
        glds16(vS[2], &Vt[nb][(tid + 512) * 8]); \
        glds16(vS[3], &Vt[nb][(tid + 768) * 8]); \
        kS[0] += 128 * 64; kS[1] += 128 * 64; kS[2] += 128 * 64; kS[3] += 128 * 64; \
        vS[0] += 128; vS[1] += 128; vS[2] += 128; vS[3] += 128; } while (0)

    // Q B-fragments (Q pre-scaled by 0.125*log2e): B[k=d][col=q], k=ki*16+hi*8+e
    short8v qf[4];
    #pragma unroll
    for (int ki = 0; ki < 4; ++ki)
        qf[ki] = *(const short8v*)&Qg[((size_t)bh * S_ + q0w + q) * 64 + ki * 16 + hi * 8];

    // K LDS base (within a 64-kv half): row=q, chunk=(2ki+hi)^(q&7) -> ^ (ki<<5)
    const int ktB = q * 128 + ((hi ^ (q & 7)) << 4);

    float16v oacc0, oacc1;
    #pragma unroll
    for (int r = 0; r < 16; ++r) { oacc0[r] = 0.f; oacc1[r] = 0.f; }
    float l_ = 0.f;

    const int ktiles = CAUSAL ? (qb + 1) : (Skv >> 7);
    int cur = 0;

    STAGE(0);
    __syncthreads();

    for (int kt = 0; kt < ktiles; ++kt) {
        if (kt + 1 < ktiles) STAGE(cur ^ 1);          // issue-early
        const char* ktp = (const char*)Kt[cur];
        const char* vtp = (const char*)Vt[cur];

        #pragma unroll
        for (int h = 0; h < 2; ++h) {                 // two 64-kv halves
            const int kv0 = kt * 128 + h * 64;
            const char* ktph = ktp + h * 8192;        // rows h*64..h*64+63

            // S^T = K . Q^T : two kv-32 blocks, K=16 chunks over d
            float16v st0, st1;
            #pragma unroll
            for (int r = 0; r < 16; ++r) { st0[r] = 0.f; st1[r] = 0.f; }
            __builtin_amdgcn_s_setprio(1);
            #pragma unroll
            for (int ki = 0; ki < 4; ++ki) {
                short8v kf0 = *(const short8v*)(ktph + (ktB ^ (ki << 5)));
                short8v kf1 = *(const short8v*)(ktph + (ktB ^ (ki << 5)) + 4096);
                st0 = mfma32(kf0, qf[ki], st0);
                st1 = mfma32(kf1, qf[ki], st1);
            }
            __builtin_amdgcn_s_setprio(0);

            if (CAUSAL && kv0 + 63 > q0b) {           // diagonal-region halves only
                const int qg_ = q0w + q;
                #pragma unroll
                for (int r = 0; r < 16; ++r) {
                    const int row = (r & 3) + 8 * (r >> 2) + 4 * hi;
                    if (kv0 + row > qg_)      st0[r] = -1e9f;
                    if (kv0 + 32 + row > qg_) st1[r] = -1e9f;
                }
            }

            // STATIC-MAX: P = exp2(s - MB), exact (scale cancels in O = PV/l)
            float ts[16];
            #pragma unroll
            for (int r = 0; r < 16; ++r) {
                st0[r] = fexp2(st0[r] - MB);
                st1[r] = fexp2(st1[r] - MB);
                ts[r] = st0[r] + st1[r];
            }
            #pragma unroll
            for (int off = 8; off >= 1; off >>= 1)
                #pragma unroll
                for (int i = 0; i < 8; ++i)
                    if (i < off) ts[i] += ts[i + off];
            l_ += ts[0] + __shfl_xor(ts[0], 32);

            // pack P to bf16 words
            unsigned W0[8], W1[8];
            #pragma unroll
            for (int s = 0; s < 8; ++s) {
                W0[s] = cvtpk(st0[2 * s], st0[2 * s + 1]);
                W1[s] = cvtpk(st1[2 * s], st1[2 * s + 1]);
            }

            // build PV B-frags bq[kb]: P[kv0+kb*16+hi*8+e][q] (R14-verified)
            short8v bq[4];
            #pragma unroll
            for (int kb = 0; kb < 4; ++kb) {
                union { unsigned u[4]; short8v v; } bb;
                #pragma unroll
                for (int j = 0; j < 4; ++j) {
                    const unsigned* Wb = (kb >> 1) ? W1 : W0;
                    const int s0 = (j & 1) + 4 * (kb & 1);
                    const unsigned own  = hi ? Wb[s0 + 2] : Wb[s0];
                    const unsigned send = hi ? Wb[s0]     : Wb[s0 + 2];
                    const unsigned rec  = (unsigned)__shfl_xor((int)send, 32);
                    bb.u[j] = (j >> 1) ? (hi ? own : rec) : (hi ? rec : own);
                }
                bq[kb] = bb.v;
            }

            // O^T += V^T . P^T : kv-chunk x = h*8 + 2kb + hi on 256B rows
            __builtin_amdgcn_s_setprio(1);
            #pragma unroll
            for (int kb = 0; kb < 4; ++kb) {
                const int x = h * 8 + 2 * kb + hi;
                short8v vf0 = *(const short8v*)(vtp +
                              q * 256 + ((x ^ (q & 15)) << 4));
                short8v vf1 = *(const short8v*)(vtp +
                              (32 + q) * 256 + ((x ^ (q & 15)) << 4));
                oacc0 = mfma32(vf0, bq[kb], oacc0);
                oacc1 = mfma32(vf1, bq[kb], oacc1);
            }
            __builtin_amdgcn_s_setprio(0);
        }

        __syncthreads();       // ONE drain+barrier per 128 kv
        cur ^= 1;
    }
#undef STAGE

    // normalize + stage O into Kt region (dead), swizzled; then coalesced out
    const float inv = frcp(l_);
    char* Ob = (char*)Kt;
    const int qr = w * 32 + q;
    #pragma unroll
    for (int s = 0; s < 8; ++s) {
        const int d0a = 2 * (s & 1) + 8 * (s >> 1) + 4 * hi;        // db=0
        unsigned wa = cvtpk(oacc0[2 * s] * inv, oacc0[2 * s + 1] * inv);
        *(unsigned*)(Ob + qr * 128 + ((((d0a >> 3) ^ (qr & 7)) << 4) | ((2 * d0a) & 15))) = wa;
        const int d0b = d0a + 32;                                    // db=1
        unsigned wb = cvtpk(oacc1[2 * s] * inv, oacc1[2 * s + 1] * inv);
        *(unsigned*)(Ob + qr * 128 + ((((d0b >> 3) ^ (qr & 7)) << 4) | ((2 * d0b) & 15))) = wb;
    }
    __syncthreads();
    const int b = bh >> 4, h2 = bh & 15;
    #pragma unroll
    for (int t = 0; t < 4; ++t) {
        const int c = t * 256 + tid;
        const int qrow = c >> 3, ch = c & 7;
        short8v v = *(const short8v*)(Ob + qrow * 128 + ((ch ^ (qrow & 7)) << 4));
        *(short8v*)&Og[((size_t)(b * S_ + q0b + qrow)) * M_ + h2 * 64 + ch * 8] = v;
    }
}

// ---------------------------------------------------------------------------
// Fused residual-add + LayerNorm, bf16 residual chain.
// X bf16, Rz bf16; OUTF=0: emit bf16; OUTF=1: emit fp32 (final output).
// ---------------------------------------------------------------------------
template<int OUTF>
__global__ __launch_bounds__(256) void ln_k(
    const ushort* __restrict__ X, const ushort* __restrict__ Rz,
    const float* __restrict__ g, const float* __restrict__ be,
    ushort* __restrict__ outb, float* __restrict__ outf)
{
    __shared__ float red[8];
    const int row = blockIdx.x, tid = threadIdx.x;
    const int lane = tid & 63, w = tid >> 6;

    ushort4 xu = *(const ushort4*)&X[(size_t)row * M_ + tid * 4];
    ushort4 ru = *(const ushort4*)&Rz[(size_t)row * M_ + tid * 4];
    float4 x = make_float4(bf2f(xu.x) + bf2f(ru.x), bf2f(xu.y) + bf2f(ru.y),
                           bf2f(xu.z) + bf2f(ru.z), bf2f(xu.w) + bf2f(ru.w));

    float sm = x.x + x.y + x.z + x.w;
    #pragma unroll
    for (int off = 1; off < 64; off <<= 1) sm += __shfl_xor(sm, off);
    if (lane == 0) red[w] = sm;
    __syncthreads();
    const float mean = (red[0] + red[1] + red[2] + red[3]) * (1.f / M_);

    x.x -= mean; x.y -= mean; x.z -= mean; x.w -= mean;
    float vs = x.x * x.x + x.y * x.y + x.z * x.z + x.w * x.w;
    #pragma unroll
    for (int off = 1; off < 64; off <<= 1) vs += __shfl_xor(vs, off);
    if (lane == 0) red[4 + w] = vs;
    __syncthreads();
    const float var = (red[4] + red[5] + red[6] + red[7]) * (1.f / M_);
    const float rs = rsqrtf(var + 1e-5f);

    float4 gg = ld4(g + tid * 4), bb = ld4(be + tid * 4);
    float4 y = make_float4(x.x * rs * gg.x + bb.x, x.y * rs * gg.y + bb.y,
                           x.z * rs * gg.z + bb.z, x.w * rs * gg.w + bb.w);
    if (OUTF) {
        *(float4*)(outf + (size_t)row * M_ + tid * 4) = y;
    } else {
        ushort4 ob = { f2bf(y.x), f2bf(y.y), f2bf(y.z), f2bf(y.w) };
        *(ushort4*)&outb[(size_t)row * M_ + tid * 4] = ob;
    }
}

// ---------------------------------------------------------------------------
extern "C" void kernel_launch(void* const* d_in, const int* in_sizes, int n_in,
                              void* d_out, int out_size, void* d_ws, size_t ws_size,
                              hipStream_t stream)
{
    const float* input = (const float*)d_in[0];
    const float* enc   = (const float*)d_in[1];
    const float* Wq1 = (const float*)d_in[2];  const float* bq1 = (const float*)d_in[3];
    const float* Wk1 = (const float*)d_in[4];  const float* bk1 = (const float*)d_in[5];
    const float* Wv1 = (const float*)d_in[6];  const float* bv1 = (const float*)d_in[7];
    const float* Wo1 = (const float*)d_in[8];  const float* bo1 = (const float*)d_in[9];
    const float* ln1g = (const float*)d_in[10]; const float* ln1b = (const float*)d_in[11];
    const float* Wq2 = (const float*)d_in[12]; const float* bq2 = (const float*)d_in[13];
    const float* Wk2 = (const float*)d_in[14]; const float* bk2 = (const float*)d_in[15];
    const float* Wv2 = (const float*)d_in[16]; const float* bv2 = (const float*)d_in[17];
    const float* Wo2 = (const float*)d_in[18]; const float* bo2 = (const float*)d_in[19];
    const float* ln2g = (const float*)d_in[20]; const float* ln2b = (const float*)d_in[21];
    const float* Wf1 = (const float*)d_in[22]; const float* bf1 = (const float*)d_in[23];
    const float* Wf2 = (const float*)d_in[24]; const float* bf2 = (const float*)d_in[25];
    const float* ln3g = (const float*)d_in[26]; const float* ln3b = (const float*)d_in[27];

    const float SC = 0.18033688011112042f;     // 0.125 * log2(e)

    char* W = (char*)d_ws;
    #define OFS(mb) ((void*)(W + (size_t)(mb) * 1024 * 1024))
    ushort* x0b    = (ushort*)OFS(0);    // alive through ln1 (residual)
    ushort* encb   = (ushort*)OFS(8);
    ushort* WqkvT1 = (ushort*)OFS(16);
    ushort* Wo1T   = (ushort*)OFS(22);
    ushort* Wq2T   = (ushort*)OFS(24);
    ushort* WkvT2  = (ushort*)OFS(26);
    ushort* Wo2T   = (ushort*)OFS(30);
    ushort* Wf1T   = (ushort*)OFS(32);
    ushort* Wf2T   = (ushort*)OFS(36);
    float*  biasQKV1 = (float*)OFS(40);
    float*  biasQ2   = (float*)((char*)OFS(40) + 32768);
    ushort* QKV1   = (ushort*)OFS(41);   // [3][B][H][S][D] (V region unused)
    ushort* VT1    = (ushort*)OFS(65);
    ushort* att1b  = (ushort*)OFS(73);
    ushort* o1b    = (ushort*)OFS(81);
    ushort* out1b  = (ushort*)OFS(57);   // bf16 residual 1 (alive thru ln2)
    ushort* Q2     = (ushort*)OFS(65);
    ushort* KV2    = (ushort*)OFS(73);   // [2][B][H][S][D] (V region unused)
    ushort* VT2    = (ushort*)OFS(90);   // x0b alive until ln1
    ushort* att2b  = (ushort*)OFS(8);
    ushort* o2b    = (ushort*)OFS(65);
    ushort* out2b  = (ushort*)OFS(0);    // bf16 residual 2 (x0b dead after ln1)
    ushort* ff1b   = (ushort*)OFS(41);
    ushort* ff2b   = (ushort*)OFS(81);   // o1b dead after ln1
    float*  out    = (float*)d_out;
    const size_t MAT = (size_t)B_ * H_ * S_ * D_;   // 4 Mi elements

    dim3 blk(256);

    // ---- prep (ONE launch, 20504 blocks) ----
    prep_k<<<dim3(20504), blk, 0, stream>>>(
        input, enc, x0b, encb,
        bq1, bk1, bv1, bk2, bv2, bq2, biasQKV1,
        Wq1, Wk1, Wv1, Wq2, Wk2, Wv2, WqkvT1, Wq2T, WkvT2,
        Wo1, Wo2, Wo1T, Wo2T, Wf1, Wf1T, Wf2, Wf2T, SC);

    // ---- masked self-attention ----
    gemm_bf16_k<128, 128, 64, 2, 0><<<dim3(24, 32), blk, 0, stream>>>(
        x0b, WqkvT1, biasQKV1, QKV1, VT1, 2, 3072, 1024);
    fattn_k<1><<<dim3(512), blk, 0, stream>>>(QKV1, QKV1 + MAT, VT1, att1b, S_);
    gemm_bf16_k<64, 64, 64, 1, 0><<<dim3(16, 64), blk, 0, stream>>>(
        att1b, Wo1T, bo1, o1b, nullptr, 9, 1024, 1024);
    ln_k<0><<<dim3(R_), blk, 0, stream>>>(o1b, x0b, ln1g, ln1b, out1b, nullptr);

    // ---- cross-attention ----
    gemm_bf16_k<64, 64, 64, 2, 0><<<dim3(16, 64), blk, 0, stream>>>(
        out1b, Wq2T, biasQ2, Q2, nullptr, 9, 1024, 1024);
    gemm_bf16_k<128, 128, 64, 2, 0><<<dim3(16, 32), blk, 0, stream>>>(
        encb, WkvT2, biasQKV1 + 4096, KV2, VT2, 1, 2048, 1024);
    fattn_k<0><<<dim3(512), blk, 0, stream>>>(Q2, KV2, VT2, att2b, S_);
    gemm_bf16_k<64, 64, 64, 1, 0><<<dim3(16, 64), blk, 0, stream>>>(
        att2b, Wo2T, bo2, o2b, nullptr, 9, 1024, 1024);
    ln_k<0><<<dim3(R_), blk, 0, stream>>>(o2b, out1b, ln2g, ln2b, out2b, nullptr);

    // ---- FFN ----
    gemm_bf16_k<128, 64, 64, 1, 1><<<dim3(32, 32), blk, 0, stream>>>(
        out2b, Wf1T, bf1, ff1b, nullptr, 9, 2048, 1024);
    gemm_bf16_k<64, 64, 64, 1, 0><<<dim3(16, 64), blk, 0, stream>>>(
        ff1b, Wf2T, bf2, ff2b, nullptr, 9, 1024, 2048);
    ln_k<1><<<dim3(R_), blk, 0, stream>>>(ff2b, out2b, ln3g, ln3b, nullptr, out);
    #undef OFS
}

// Round 24
// 275.243 us; speedup vs baseline: 1.1929x; 1.0008x over previous
//
#include <hip/hip_runtime.h>
#include <math.h>

#define B_ 2
#define S_ 2048
#define M_ 1024
#define H_ 16
#define D_ 64
#define R_ (B_*S_)          // 4096 rows

typedef __attribute__((ext_vector_type(8))) short short8v;    // 8 bf16 = 4 VGPR
typedef __attribute__((ext_vector_type(4))) float float4v;
typedef __attribute__((ext_vector_type(16))) float float16v; // 32x32 C/D

__device__ __forceinline__ float4 ld4(const float* p) {
    return *(const float4* __restrict__)p;
}

__device__ __forceinline__ ushort f2bf(float f) {            // RNE
    union { float f; unsigned u; } x; x.f = f;
    unsigned u = x.u + 0x7fffu + ((x.u >> 16) & 1u);
    return (ushort)(u >> 16);
}
__device__ __forceinline__ float bf2f(ushort s) {
    union { unsigned u; float f; } x; x.u = ((unsigned)s) << 16; return x.f;
}
__device__ __forceinline__ unsigned cvtpk(float lo, float hi) {
    unsigned r;
    asm("v_cvt_pk_bf16_f32 %0, %1, %2" : "=v"(r) : "v"(lo), "v"(hi));
    return r;
}
#if __has_builtin(__builtin_amdgcn_exp2f)
__device__ __forceinline__ float fexp2(float x) { return __builtin_amdgcn_exp2f(x); }
#else
__device__ __forceinline__ float fexp2(float x) { return exp2f(x); }
#endif
#if __has_builtin(__builtin_amdgcn_rcpf)
__device__ __forceinline__ float frcp(float x) { return __builtin_amdgcn_rcpf(x); }
#else
__device__ __forceinline__ float frcp(float x) { return 1.f / x; }
#endif
__device__ __forceinline__ float4v mfma16(short8v a, short8v b, float4v c) {
    return __builtin_amdgcn_mfma_f32_16x16x32_bf16(a, b, c, 0, 0, 0);
}
__device__ __forceinline__ float16v mfma32(short8v a, short8v b, float16v c) {
    return __builtin_amdgcn_mfma_f32_32x32x16_bf16(a, b, c, 0, 0, 0);
}
__device__ __forceinline__ void glds16(const void* g, void* l) {
    __builtin_amdgcn_global_load_lds(
        (const __attribute__((address_space(1))) void*)g,
        (__attribute__((address_space(3))) void*)l, 16, 0, 0);
}

// ---------------------------------------------------------------------------
// Fully fused prep: one launch, block-range dispatch (branches block-uniform).
// ---------------------------------------------------------------------------
__device__ __forceinline__ void trans32(const float* __restrict__ ib,
                                        ushort* __restrict__ ob,
                                        int K, int N, int k0, int n0,
                                        float scale, float t[32][33], int tid) {
    const int tx = tid & 31, ty = tid >> 5;
    #pragma unroll
    for (int i = 0; i < 4; ++i)
        t[ty + i * 8][tx] = ib[(size_t)(k0 + ty + i * 8) * N + n0 + tx];
    __syncthreads();
    #pragma unroll
    for (int i = 0; i < 4; ++i)
        ob[(size_t)(n0 + ty + i * 8) * K + k0 + tx] = f2bf(t[tx][ty + i * 8] * scale);
}

__global__ __launch_bounds__(256) void prep_k(
    const float* __restrict__ input, const float* __restrict__ enc,
    ushort* __restrict__ x0b, ushort* __restrict__ encb,
    const float* __restrict__ bq1, const float* __restrict__ bk1,
    const float* __restrict__ bv1, const float* __restrict__ bk2,
    const float* __restrict__ bv2, const float* __restrict__ bq2,
    float* __restrict__ biasDst,
    const float* __restrict__ Wq1, const float* __restrict__ Wk1,
    const float* __restrict__ Wv1, const float* __restrict__ Wq2,
    const float* __restrict__ Wk2, const float* __restrict__ Wv2,
    ushort* __restrict__ oQKV1, ushort* __restrict__ oQ2,
    ushort* __restrict__ oKV2,
    const float* __restrict__ Wo1, const float* __restrict__ Wo2,
    ushort* __restrict__ Wo1T, ushort* __restrict__ Wo2T,
    const float* __restrict__ Wf1, ushort* __restrict__ Wf1T,
    const float* __restrict__ Wf2, ushort* __restrict__ Wf2T,
    float SCv)
{
    __shared__ float t[32][33];
    const int blk = blockIdx.x, tid = threadIdx.x;

    if (blk < 8192) {                       // input/enc cast
        size_t u = (size_t)blk * 256 + tid;
        const float* in; ushort* out;
        if (u < (1u << 20)) { in = input; out = x0b; }
        else { u -= (1u << 20); in = enc; out = encb; }
        float4 v = ld4(in + u * 4);
        ushort4 o = { f2bf(v.x), f2bf(v.y), f2bf(v.z), f2bf(v.w) };
        *(ushort4*)&out[u * 4] = o;
    } else if (blk < 8216) {                // bias packs
        const int lb = blk - 8192;
        const int seg = lb >> 2;
        const int li = (lb & 3) * 256 + tid;
        const float* s; int off; float sc;
        switch (seg) {
            case 0: s = bq1; off = 0;    sc = SCv; break;
            case 1: s = bk1; off = 1024; sc = 1.f; break;
            case 2: s = bv1; off = 2048; sc = 1.f; break;
            case 3: s = bk2; off = 4096; sc = 1.f; break;
            case 4: s = bv2; off = 5120; sc = 1.f; break;
            default: s = bq2; off = 8192; sc = SCv; break;
        }
        biasDst[off + li] = s[li] * sc;
    } else if (blk < 14360) {               // head-stacked weight transposes
        const int local = blk - 8216;
        const int x = local & 1, y = (local >> 1) & 31, z = local >> 6;
        const int s6 = z >> 4, h = z & 15;
        const float* srcs[6] = { Wq1, Wk1, Wv1, Wq2, Wk2, Wv2 };
        const float* ib = srcs[s6] + (size_t)h * 1024 * 64;
        ushort* ob;
        if (s6 < 3)       ob = oQKV1 + (size_t)s6 * (1024 * 1024) + (size_t)h * (64 * 1024);
        else if (s6 == 3) ob = oQ2 + (size_t)h * (64 * 1024);
        else              ob = oKV2 + (size_t)(s6 - 4) * (1024 * 1024) + (size_t)h * (64 * 1024);
        const float scale = (s6 == 0 || s6 == 3) ? SCv : 1.f;
        trans32(ib, ob, 1024, 64, y * 32, x * 32, scale, t, tid);
    } else if (blk < 16408) {               // Wo1/Wo2
        const int local = blk - 14360;
        const int x = local & 31, y = (local >> 5) & 31, z = local >> 10;
        trans32(z ? Wo2 : Wo1, z ? Wo2T : Wo1T, 1024, 1024, y * 32, x * 32, 1.f, t, tid);
    } else if (blk < 18456) {               // Wf1 (K=1024, N=2048)
        const int local = blk - 16408;
        const int x = local & 63, y = local >> 6;
        trans32(Wf1, Wf1T, 1024, 2048, y * 32, x * 32, 1.f, t, tid);
    } else {                                // Wf2 (K=2048, N=1024)
        const int local = blk - 18456;
        const int x = local & 31, y = local >> 5;
        trans32(Wf2, Wf2T, 2048, 1024, y * 32, x * 32, 1.f, t, tid);
    }
}

// ---------------------------------------------------------------------------
// bf16 MFMA GEMM, TMxTN tile, BK templated, 256 thr (4 waves 2x2). XOR-swizzled.
// T1 XCD-aware tile remap: swz = (id%8)*(nwg/8) + id/8 (all grids %8==0).
// ---------------------------------------------------------------------------
template<int TM, int TN, int BK, int OUTMODE, int ACT>
__global__ __launch_bounds__(256) void gemm_bf16_k(
    const ushort* __restrict__ A, const ushort* __restrict__ Bt,
    const float* __restrict__ bias, void* __restrict__ C,
    ushort* __restrict__ Cvt, int matV, int N, int K)
{
    constexpr int NI = TM / 32;
    constexpr int NJ = TN / 32;
    constexpr int KS = BK / 32;
    constexpr int CHR = BK / 8;                 // 16B chunks per row
    __shared__ __align__(16) ushort At[TM * BK];
    __shared__ __align__(16) ushort Bts[TN * BK];
    const int tid = threadIdx.x, lane = tid & 63, w = tid >> 6;
    const int wm = w >> 1, wn = w & 1;
    const int q = lane & 15, g = lane >> 4;

    // T1 XCD swizzle (nwg % 8 == 0 for every grid in this launch set)
    const int nwg = gridDim.x * gridDim.y;
    const int id0 = blockIdx.y * gridDim.x + blockIdx.x;
    const int swz = (id0 & 7) * (nwg >> 3) + (id0 >> 3);
    const int m0 = (swz / gridDim.x) * TM, n0 = (swz % gridDim.x) * TN;

    float4v acc[NI][NJ];
    #pragma unroll
    for (int i = 0; i < NI; ++i)
        #pragma unroll
        for (int j = 0; j < NJ; ++j) acc[i][j] = (float4v){0.f, 0.f, 0.f, 0.f};

    for (int k0 = 0; k0 < K; k0 += BK) {
        #pragma unroll
        for (int t = 0; t < TM * CHR / 256; ++t) {
            const int cb = (w * (TM * CHR / 256) + t) * 64;
            const int c = cb + lane;
            const int row = c / CHR, kc = (c % CHR) ^ (row & (CHR - 1));
            glds16(&A[(size_t)(m0 + row) * K + k0 + kc * 8], &At[cb * 8]);
        }
        #pragma unroll
        for (int t = 0; t < TN * CHR / 256; ++t) {
            const int cb = (w * (TN * CHR / 256) + t) * 64;
            const int c = cb + lane;
            const int row = c / CHR, kc = (c % CHR) ^ (row & (CHR - 1));
            glds16(&Bt[(size_t)(n0 + row) * K + k0 + kc * 8], &Bts[cb * 8]);
        }
        __syncthreads();
        #pragma unroll
        for (int ks = 0; ks < KS; ++ks) {
            short8v af[NI], bf[NJ];
            #pragma unroll
            for (int i = 0; i < NI; ++i) {
                const int row = wm * (TM / 2) + i * 16 + q;
                af[i] = *(const short8v*)((const char*)At +
                        row * (BK * 2) + (((ks * 4 + g) ^ (q & (CHR - 1))) << 4));
            }
            #pragma unroll
            for (int j = 0; j < NJ; ++j) {
                const int row = wn * (TN / 2) + j * 16 + q;
                bf[j] = *(const short8v*)((const char*)Bts +
                        row * (BK * 2) + (((ks * 4 + g) ^ (q & (CHR - 1))) << 4));
            }
            #pragma unroll
            for (int i = 0; i < NI; ++i)
                #pragma unroll
                for (int j = 0; j < NJ; ++j)
                    acc[i][j] = mfma16(af[i], bf[j], acc[i][j]);
        }
        __syncthreads();
    }

    float bcol[NJ];
    #pragma unroll
    for (int j = 0; j < NJ; ++j) bcol[j] = bias[n0 + wn * (TN / 2) + j * 16 + q];

    #pragma unroll
    for (int i = 0; i < NI; ++i) {
        const int rowg0 = m0 + wm * (TM / 2) + i * 16 + g * 4;
        #pragma unroll
        for (int j = 0; j < NJ; ++j) {
            const int colg = n0 + wn * (TN / 2) + j * 16 + q;
            float v[4];
            #pragma unroll
            for (int r = 0; r < 4; ++r) {
                v[r] = acc[i][j][r] + bcol[j];
                if (ACT) v[r] = fmaxf(v[r], 0.f);
            }
            if (OUTMODE == 0) {
                #pragma unroll
                for (int r = 0; r < 4; ++r)
                    ((float*)C)[(size_t)(rowg0 + r) * N + colg] = v[r];
            } else if (OUTMODE == 1) {
                #pragma unroll
                for (int r = 0; r < 4; ++r)
                    ((ushort*)C)[(size_t)(rowg0 + r) * N + colg] = f2bf(v[r]);
            } else {
                const int mat = colg >> 10, h = (colg >> 6) & 15, d = colg & 63;
                const int bb = rowg0 >> 11, s0 = rowg0 & 2047;
                if (mat == matV) {   // V -> transposed layout [bh][d][s]
                    uint2 pv;
                    pv.x = cvtpk(v[0], v[1]);
                    pv.y = cvtpk(v[2], v[3]);
                    *(uint2*)&Cvt[((size_t)(bb * H_ + h) * D_ + d) * S_ + s0] = pv;
                } else {
                    #pragma unroll
                    for (int r = 0; r < 4; ++r)
                        ((ushort*)C)[((((size_t)(mat * B_ + bb) * H_ + h) * S_) + s0 + r) * D_ + d] = f2bf(v[r]);
                }
            }
        }
    }
}

// ---------------------------------------------------------------------------
// Flash attention, 32x32x16 bf16 MFMA, swapped form, STATIC-MAX softmax.
// kv-tile 128 (two 64-halves per barrier interval).
// ---------------------------------------------------------------------------
template<int CAUSAL>
__global__ __launch_bounds__(256, 2) void fattn_k(
    const ushort* __restrict__ Qg, const ushort* __restrict__ Kg,
    const ushort* __restrict__ VTg, ushort* __restrict__ Og, int Skv)
{
    __shared__ __align__(16) ushort Kt[2][128 * 64];  // [kv][d] swizzled, 16 KB x2
    __shared__ __align__(16) ushort Vt[2][64 * 128];  // [d][kv] swizzled, 16 KB x2
    const int tid = threadIdx.x, lane = tid & 63, w = tid >> 6;   // w 0..3
    const int q = lane & 31, hi = lane >> 5;
    const int id = blockIdx.x;
    const int bh = id & 31;
    const int t_ = id >> 5;
    const int qb = CAUSAL ? ((t_ < 8) ? (15 - t_) : (t_ - 8)) : t_;
    const int q0b = qb * 128;
    const int q0w = q0b + w * 32;
    const float MB = 24.f;                            // static exponent bias

    // staging sources: K 1024 chunks (4/thr), V 1024 chunks (4/thr), pre-swizzled
    const ushort* kS[4]; const ushort* vS[4];
    #pragma unroll
    for (int i = 0; i < 4; ++i) {
        const int c = i * 256 + tid;
        const int rk = c >> 3, chk = c & 7;
        kS[i] = Kg + ((size_t)bh * Skv + rk) * 64 + ((chk ^ (rk & 7)) * 8);
        const int rv = c >> 4, chv = c & 15;
        vS[i] = VTg + ((size_t)bh * 64 + rv) * (size_t)Skv + ((chv ^ (rv & 15)) * 8);
    }

#define STAGE(nb) do { \
        glds16(kS[0], &Kt[nb][(tid) * 8]); \
        glds16(kS[1], &Kt[nb][(tid + 256) * 8]); \
        glds16(kS[2], &Kt[nb][(tid + 512) * 8]); \
        glds16(kS[3], &Kt[nb][(tid + 768) * 8]); \
        glds16(vS[0], &Vt[nb][(tid) * 8]); \
        glds16(vS[1], &Vt[nb][(tid + 256) * 8]); \
        glds16(vS[2], &Vt[nb][(tid + 512) * 8]); \
        glds16(vS[3], &Vt[nb][(tid + 768) * 8]); \
        kS[0] += 128 * 64; kS[1] += 128 * 64; kS[2] += 128 * 64; kS[3] += 128 * 64; \
        vS[0] += 128; vS[1] += 128; vS[2] += 128; vS[3] += 128; } while (0)

    // Q B-fragments (Q pre-scaled by 0.125*log2e): B[k=d][col=q], k=ki*16+hi*8+e
    short8v qf[4];
    #pragma unroll
    for (int ki = 0; ki < 4; ++ki)
        qf[ki] = *(const short8v*)&Qg[((size_t)bh * S_ + q0w + q) * 64 + ki * 16 + hi * 8];

    // K LDS base (within a 64-kv half): row=q, chunk=(2ki+hi)^(q&7) -> ^ (ki<<5)
    const int ktB = q * 128 + ((hi ^ (q & 7)) << 4);

    float16v oacc0, oacc1;
    #pragma unroll
    for (int r = 0; r < 16; ++r) { oacc0[r] = 0.f; oacc1[r] = 0.f; }
    float l_ = 0.f;

    const int ktiles = CAUSAL ? (qb + 1) : (Skv >> 7);
    int cur = 0;

    STAGE(0);
    __syncthreads();

    for (int kt = 0; kt < ktiles; ++kt) {
        if (kt + 1 < ktiles) STAGE(cur ^ 1);          // issue-early
        const char* ktp = (const char*)Kt[cur];
        const char* vtp = (const char*)Vt[cur];

        #pragma unroll
        for (int h = 0; h < 2; ++h) {                 // two 64-kv halves
            const int kv0 = kt * 128 + h * 64;
            const char* ktph = ktp + h * 8192;        // rows h*64..h*64+63

            // S^T = K . Q^T : two kv-32 blocks, K=16 chunks over d
            float16v st0, st1;
            #pragma unroll
            for (int r = 0; r < 16; ++r) { st0[r] = 0.f; st1[r] = 0.f; }
            __builtin_amdgcn_s_setprio(1);
            #pragma unroll
            for (int ki = 0; ki < 4; ++ki) {
                short8v kf0 = *(const short8v*)(ktph + (ktB ^ (ki << 5)));
                short8v kf1 = *(const short8v*)(ktph + (ktB ^ (ki << 5)) + 4096);
                st0 = mfma32(kf0, qf[ki], st0);
                st1 = mfma32(kf1, qf[ki], st1);
            }
            __builtin_amdgcn_s_setprio(0);

            if (CAUSAL && kv0 + 63 > q0b) {           // diagonal-region halves only
                const int qg_ = q0w + q;
                #pragma unroll
                for (int r = 0; r < 16; ++r) {
                    const int row = (r & 3) + 8 * (r >> 2) + 4 * hi;
                    if (kv0 + row > qg_)      st0[r] = -1e9f;
                    if (kv0 + 32 + row > qg_) st1[r] = -1e9f;
                }
            }

            // STATIC-MAX: P = exp2(s - MB), exact (scale cancels in O = PV/l)
            float ts[16];
            #pragma unroll
            for (int r = 0; r < 16; ++r) {
                st0[r] = fexp2(st0[r] - MB);
                st1[r] = fexp2(st1[r] - MB);
                ts[r] = st0[r] + st1[r];
            }
            #pragma unroll
            for (int off = 8; off >= 1; off >>= 1)
                #pragma unroll
                for (int i = 0; i < 8; ++i)
                    if (i < off) ts[i] += ts[i + off];
            l_ += ts[0] + __shfl_xor(ts[0], 32);

            // pack P to bf16 words
            unsigned W0[8], W1[8];
            #pragma unroll
            for (int s = 0; s < 8; ++s) {
                W0[s] = cvtpk(st0[2 * s], st0[2 * s + 1]);
                W1[s] = cvtpk(st1[2 * s], st1[2 * s + 1]);
            }

            // build PV B-frags bq[kb]: P[kv0+kb*16+hi*8+e][q] (R14-verified)
            short8v bq[4];
            #pragma unroll
            for (int kb = 0; kb < 4; ++kb) {
                union { unsigned u[4]; short8v v; } bb;
                #pragma unroll
                for (int j = 0; j < 4; ++j) {
                    const unsigned* Wb = (kb >> 1) ? W1 : W0;
                    const int s0 = (j & 1) + 4 * (kb & 1);
                    const unsigned own  = hi ? Wb[s0 + 2] : Wb[s0];
                    const unsigned send = hi ? Wb[s0]     : Wb[s0 + 2];
                    const unsigned rec  = (unsigned)__shfl_xor((int)send, 32);
                    bb.u[j] = (j >> 1) ? (hi ? own : rec) : (hi ? rec : own);
                }
                bq[kb] = bb.v;
            }

            // O^T += V^T . P^T : kv-chunk x = h*8 + 2kb + hi on 256B rows
            __builtin_amdgcn_s_setprio(1);
            #pragma unroll
            for (int kb = 0; kb < 4; ++kb) {
                const int x = h * 8 + 2 * kb + hi;
                short8v vf0 = *(const short8v*)(vtp +
                              q * 256 + ((x ^ (q & 15)) << 4));
                short8v vf1 = *(const short8v*)(vtp +
                              (32 + q) * 256 + ((x ^ (q & 15)) << 4));
                oacc0 = mfma32(vf0, bq[kb], oacc0);
                oacc1 = mfma32(vf1, bq[kb], oacc1);
            }
            __builtin_amdgcn_s_setprio(0);
        }

        __syncthreads();       // ONE drain+barrier per 128 kv
        cur ^= 1;
    }
#undef STAGE

    // normalize + stage O into Kt region (dead), swizzled; then coalesced out
    const float inv = frcp(l_);
    char* Ob = (char*)Kt;
    const int qr = w * 32 + q;
    #pragma unroll
    for (int s = 0; s < 8; ++s) {
        const int d0a = 2 * (s & 1) + 8 * (s >> 1) + 4 * hi;        // db=0
        unsigned wa = cvtpk(oacc0[2 * s] * inv, oacc0[2 * s + 1] * inv);
        *(unsigned*)(Ob + qr * 128 + ((((d0a >> 3) ^ (qr & 7)) << 4) | ((2 * d0a) & 15))) = wa;
        const int d0b = d0a + 32;                                    // db=1
        unsigned wb = cvtpk(oacc1[2 * s] * inv, oacc1[2 * s + 1] * inv);
        *(unsigned*)(Ob + qr * 128 + ((((d0b >> 3) ^ (qr & 7)) << 4) | ((2 * d0b) & 15))) = wb;
    }
    __syncthreads();
    const int b = bh >> 4, h2 = bh & 15;
    #pragma unroll
    for (int t = 0; t < 4; ++t) {
        const int c = t * 256 + tid;
        const int qrow = c >> 3, ch = c & 7;
        short8v v = *(const short8v*)(Ob + qrow * 128 + ((ch ^ (qrow & 7)) << 4));
        *(short8v*)&Og[((size_t)(b * S_ + q0b + qrow)) * M_ + h2 * 64 + ch * 8] = v;
    }
}

// ---------------------------------------------------------------------------
// Fused residual-add + LayerNorm, bf16 residual chain.
// X bf16, Rz bf16; OUTF=0: emit bf16; OUTF=1: emit fp32 (final output).
// ---------------------------------------------------------------------------
template<int OUTF>
__global__ __launch_bounds__(256) void ln_k(
    const ushort* __restrict__ X, const ushort* __restrict__ Rz,
    const float* __restrict__ g, const float* __restrict__ be,
    ushort* __restrict__ outb, float* __restrict__ outf)
{
    __shared__ float red[8];
    const int row = blockIdx.x, tid = threadIdx.x;
    const int lane = tid & 63, w = tid >> 6;

    ushort4 xu = *(const ushort4*)&X[(size_t)row * M_ + tid * 4];
    ushort4 ru = *(const ushort4*)&Rz[(size_t)row * M_ + tid * 4];
    float4 x = make_float4(bf2f(xu.x) + bf2f(ru.x), bf2f(xu.y) + bf2f(ru.y),
                           bf2f(xu.z) + bf2f(ru.z), bf2f(xu.w) + bf2f(ru.w));

    float sm = x.x + x.y + x.z + x.w;
    #pragma unroll
    for (int off = 1; off < 64; off <<= 1) sm += __shfl_xor(sm, off);
    if (lane == 0) red[w] = sm;
    __syncthreads();
    const float mean = (red[0] + red[1] + red[2] + red[3]) * (1.f / M_);

    x.x -= mean; x.y -= mean; x.z -= mean; x.w -= mean;
    float vs = x.x * x.x + x.y * x.y + x.z * x.z + x.w * x.w;
    #pragma unroll
    for (int off = 1; off < 64; off <<= 1) vs += __shfl_xor(vs, off);
    if (lane == 0) red[4 + w] = vs;
    __syncthreads();
    const float var = (red[4] + red[5] + red[6] + red[7]) * (1.f / M_);
    const float rs = rsqrtf(var + 1e-5f);

    float4 gg = ld4(g + tid * 4), bb = ld4(be + tid * 4);
    float4 y = make_float4(x.x * rs * gg.x + bb.x, x.y * rs * gg.y + bb.y,
                           x.z * rs * gg.z + bb.z, x.w * rs * gg.w + bb.w);
    if (OUTF) {
        *(float4*)(outf + (size_t)row * M_ + tid * 4) = y;
    } else {
        ushort4 ob = { f2bf(y.x), f2bf(y.y), f2bf(y.z), f2bf(y.w) };
        *(ushort4*)&outb[(size_t)row * M_ + tid * 4] = ob;
    }
}

// ---------------------------------------------------------------------------
extern "C" void kernel_launch(void* const* d_in, const int* in_sizes, int n_in,
                              void* d_out, int out_size, void* d_ws, size_t ws_size,
                              hipStream_t stream)
{
    const float* input = (const float*)d_in[0];
    const float* enc   = (const float*)d_in[1];
    const float* Wq1 = (const float*)d_in[2];  const float* bq1 = (const float*)d_in[3];
    const float* Wk1 = (const float*)d_in[4];  const float* bk1 = (const float*)d_in[5];
    const float* Wv1 = (const float*)d_in[6];  const float* bv1 = (const float*)d_in[7];
    const float* Wo1 = (const float*)d_in[8];  const float* bo1 = (const float*)d_in[9];
    const float* ln1g = (const float*)d_in[10]; const float* ln1b = (const float*)d_in[11];
    const float* Wq2 = (const float*)d_in[12]; const float* bq2 = (const float*)d_in[13];
    const float* Wk2 = (const float*)d_in[14]; const float* bk2 = (const float*)d_in[15];
    const float* Wv2 = (const float*)d_in[16]; const float* bv2 = (const float*)d_in[17];
    const float* Wo2 = (const float*)d_in[18]; const float* bo2 = (const float*)d_in[19];
    const float* ln2g = (const float*)d_in[20]; const float* ln2b = (const float*)d_in[21];
    const float* Wf1 = (const float*)d_in[22]; const float* bf1 = (const float*)d_in[23];
    const float* Wf2 = (const float*)d_in[24]; const float* bf2 = (const float*)d_in[25];
    const float* ln3g = (const float*)d_in[26]; const float* ln3b = (const float*)d_in[27];

    const float SC = 0.18033688011112042f;     // 0.125 * log2(e)

    char* W = (char*)d_ws;
    #define OFS(mb) ((void*)(W + (size_t)(mb) * 1024 * 1024))
    ushort* x0b    = (ushort*)OFS(0);    // alive through ln1 (residual)
    ushort* encb   = (ushort*)OFS(8);
    ushort* WqkvT1 = (ushort*)OFS(16);
    ushort* Wo1T   = (ushort*)OFS(22);
    ushort* Wq2T   = (ushort*)OFS(24);
    ushort* WkvT2  = (ushort*)OFS(26);
    ushort* Wo2T   = (ushort*)OFS(30);
    ushort* Wf1T   = (ushort*)OFS(32);
    ushort* Wf2T   = (ushort*)OFS(36);
    float*  biasQKV1 = (float*)OFS(40);
    float*  biasQ2   = (float*)((char*)OFS(40) + 32768);
    ushort* QKV1   = (ushort*)OFS(41);   // [3][B][H][S][D] (V region unused)
    ushort* VT1    = (ushort*)OFS(65);
    ushort* att1b  = (ushort*)OFS(73);
    ushort* o1b    = (ushort*)OFS(81);
    ushort* out1b  = (ushort*)OFS(57);   // bf16 residual 1 (alive thru ln2)
    ushort* Q2     = (ushort*)OFS(65);
    ushort* KV2    = (ushort*)OFS(73);   // [2][B][H][S][D] (V region unused)
    ushort* VT2    = (ushort*)OFS(90);   // x0b alive until ln1
    ushort* att2b  = (ushort*)OFS(8);
    ushort* o2b    = (ushort*)OFS(65);
    ushort* out2b  = (ushort*)OFS(0);    // bf16 residual 2 (x0b dead after ln1)
    ushort* ff1b   = (ushort*)OFS(41);
    ushort* ff2b   = (ushort*)OFS(81);   // o1b dead after ln1
    float*  out    = (float*)d_out;
    const size_t MAT = (size_t)B_ * H_ * S_ * D_;   // 4 Mi elements

    dim3 blk(256);

    // ---- prep (ONE launch, 20504 blocks) ----
    prep_k<<<dim3(20504), blk, 0, stream>>>(
        input, enc, x0b, encb,
        bq1, bk1, bv1, bk2, bv2, bq2, biasQKV1,
        Wq1, Wk1, Wv1, Wq2, Wk2, Wv2, WqkvT1, Wq2T, WkvT2,
        Wo1, Wo2, Wo1T, Wo2T, Wf1, Wf1T, Wf2, Wf2T, SC);

    // ---- masked self-attention ----
    gemm_bf16_k<128, 128, 64, 2, 0><<<dim3(24, 32), blk, 0, stream>>>(
        x0b, WqkvT1, biasQKV1, QKV1, VT1, 2, 3072, 1024);
    fattn_k<1><<<dim3(512), blk, 0, stream>>>(QKV1, QKV1 + MAT, VT1, att1b, S_);
    gemm_bf16_k<64, 64, 64, 1, 0><<<dim3(16, 64), blk, 0, stream>>>(
        att1b, Wo1T, bo1, o1b, nullptr, 9, 1024, 1024);
    ln_k<0><<<dim3(R_), blk, 0, stream>>>(o1b, x0b, ln1g, ln1b, out1b, nullptr);

    // ---- cross-attention ----
    gemm_bf16_k<64, 64, 64, 2, 0><<<dim3(16, 64), blk, 0, stream>>>(
        out1b, Wq2T, biasQ2, Q2, nullptr, 9, 1024, 1024);
    gemm_bf16_k<128, 128, 64, 2, 0><<<dim3(16, 32), blk, 0, stream>>>(
        encb, WkvT2, biasQKV1 + 4096, KV2, VT2, 1, 2048, 1024);
    fattn_k<0><<<dim3(512), blk, 0, stream>>>(Q2, KV2, VT2, att2b, S_);
    gemm_bf16_k<64, 64, 64, 1, 0><<<dim3(16, 64), blk, 0, stream>>>(
        att2b, Wo2T, bo2, o2b, nullptr, 9, 1024, 1024);
    ln_k<0><<<dim3(R_), blk, 0, stream>>>(o2b, out1b, ln2g, ln2b, out2b, nullptr);

    // ---- FFN ----
    gemm_bf16_k<128, 64, 64, 1, 1><<<dim3(32, 32), blk, 0, stream>>>(
        out2b, Wf1T, bf1, ff1b, nullptr, 9, 2048, 1024);
    gemm_bf16_k<64, 64, 64, 1, 0><<<dim3(16, 64), blk, 0, stream>>>(
        ff1b, Wf2T, bf2, ff2b, nullptr, 9, 1024, 2048);
    ln_k<1><<<dim3(R_), blk, 0, stream>>>(ff2b, out2b, ln3g, ln3b, nullptr, out);
    #undef OFS
}

// Round 25
// 275.165 us; speedup vs baseline: 1.1932x; 1.0003x over previous
//
#include <hip/hip_runtime.h>
#include <math.h>

#define B_ 2
#define S_ 2048
#define M_ 1024
#define H_ 16
#define D_ 64
#define R_ (B_*S_)          // 4096 rows

typedef __attribute__((ext_vector_type(8))) short short8v;    // 8 bf16 = 4 VGPR
typedef __attribute__((ext_vector_type(4))) float float4v;
typedef __attribute__((ext_vector_type(16))) float float16v; // 32x32 C/D

__device__ __forceinline__ float4 ld4(const float* p) {
    return *(const float4* __restrict__)p;
}

__device__ __forceinline__ ushort f2bf(float f) {            // RNE
    union { float f; unsigned u; } x; x.f = f;
    unsigned u = x.u + 0x7fffu + ((x.u >> 16) & 1u);
    return (ushort)(u >> 16);
}
__device__ __forceinline__ float bf2f(ushort s) {
    union { unsigned u; float f; } x; x.u = ((unsigned)s) << 16; return x.f;
}
__device__ __forceinline__ unsigned cvtpk(float lo, float hi) {
    unsigned r;
    asm("v_cvt_pk_bf16_f32 %0, %1, %2" : "=v"(r) : "v"(lo), "v"(hi));
    return r;
}
#if __has_builtin(__builtin_amdgcn_exp2f)
__device__ __forceinline__ float fexp2(float x) { return __builtin_amdgcn_exp2f(x); }
#else
__device__ __forceinline__ float fexp2(float x) { return exp2f(x); }
#endif
#if __has_builtin(__builtin_amdgcn_rcpf)
__device__ __forceinline__ float frcp(float x) { return __builtin_amdgcn_rcpf(x); }
#else
__device__ __forceinline__ float frcp(float x) { return 1.f / x; }
#endif
__device__ __forceinline__ float4v mfma16(short8v a, short8v b, float4v c) {
    return __builtin_amdgcn_mfma_f32_16x16x32_bf16(a, b, c, 0, 0, 0);
}
__device__ __forceinline__ float16v mfma32(short8v a, short8v b, float16v c) {
    return __builtin_amdgcn_mfma_f32_32x32x16_bf16(a, b, c, 0, 0, 0);
}
__device__ __forceinline__ void glds16(const void* g, void* l) {
    __builtin_amdgcn_global_load_lds(
        (const __attribute__((address_space(1))) void*)g,
        (__attribute__((address_space(3))) void*)l, 16, 0, 0);
}

// ---------------------------------------------------------------------------
// Fully fused prep: one launch, block-range dispatch (branches block-uniform).
// ---------------------------------------------------------------------------
__device__ __forceinline__ void trans32(const float* __restrict__ ib,
                                        ushort* __restrict__ ob,
                                        int K, int N, int k0, int n0,
                                        float scale, float t[32][33], int tid) {
    const int tx = tid & 31, ty = tid >> 5;
    #pragma unroll
    for (int i = 0; i < 4; ++i)
        t[ty + i * 8][tx] = ib[(size_t)(k0 + ty + i * 8) * N + n0 + tx];
    __syncthreads();
    #pragma unroll
    for (int i = 0; i < 4; ++i)
        ob[(size_t)(n0 + ty + i * 8) * K + k0 + tx] = f2bf(t[tx][ty + i * 8] * scale);
}

__global__ __launch_bounds__(256) void prep_k(
    const float* __restrict__ input, const float* __restrict__ enc,
    ushort* __restrict__ x0b, ushort* __restrict__ encb,
    const float* __restrict__ bq1, const float* __restrict__ bk1,
    const float* __restrict__ bv1, const float* __restrict__ bk2,
    const float* __restrict__ bv2, const float* __restrict__ bq2,
    float* __restrict__ biasDst,
    const float* __restrict__ Wq1, const float* __restrict__ Wk1,
    const float* __restrict__ Wv1, const float* __restrict__ Wq2,
    const float* __restrict__ Wk2, const float* __restrict__ Wv2,
    ushort* __restrict__ oQKV1, ushort* __restrict__ oQ2,
    ushort* __restrict__ oKV2,
    const float* __restrict__ Wo1, const float* __restrict__ Wo2,
    ushort* __restrict__ Wo1T, ushort* __restrict__ Wo2T,
    const float* __restrict__ Wf1, ushort* __restrict__ Wf1T,
    const float* __restrict__ Wf2, ushort* __restrict__ Wf2T,
    float SCv)
{
    __shared__ float t[32][33];
    const int blk = blockIdx.x, tid = threadIdx.x;

    if (blk < 8192) {                       // input/enc cast
        size_t u = (size_t)blk * 256 + tid;
        const float* in; ushort* out;
        if (u < (1u << 20)) { in = input; out = x0b; }
        else { u -= (1u << 20); in = enc; out = encb; }
        float4 v = ld4(in + u * 4);
        ushort4 o = { f2bf(v.x), f2bf(v.y), f2bf(v.z), f2bf(v.w) };
        *(ushort4*)&out[u * 4] = o;
    } else if (blk < 8216) {                // bias packs
        const int lb = blk - 8192;
        const int seg = lb >> 2;
        const int li = (lb & 3) * 256 + tid;
        const float* s; int off; float sc;
        switch (seg) {
            case 0: s = bq1; off = 0;    sc = SCv; break;
            case 1: s = bk1; off = 1024; sc = 1.f; break;
            case 2: s = bv1; off = 2048; sc = 1.f; break;
            case 3: s = bk2; off = 4096; sc = 1.f; break;
            case 4: s = bv2; off = 5120; sc = 1.f; break;
            default: s = bq2; off = 8192; sc = SCv; break;
        }
        biasDst[off + li] = s[li] * sc;
    } else if (blk < 14360) {               // head-stacked weight transposes
        const int local = blk - 8216;
        const int x = local & 1, y = (local >> 1) & 31, z = local >> 6;
        const int s6 = z >> 4, h = z & 15;
        const float* srcs[6] = { Wq1, Wk1, Wv1, Wq2, Wk2, Wv2 };
        const float* ib = srcs[s6] + (size_t)h * 1024 * 64;
        ushort* ob;
        if (s6 < 3)       ob = oQKV1 + (size_t)s6 * (1024 * 1024) + (size_t)h * (64 * 1024);
        else if (s6 == 3) ob = oQ2 + (size_t)h * (64 * 1024);
        else              ob = oKV2 + (size_t)(s6 - 4) * (1024 * 1024) + (size_t)h * (64 * 1024);
        const float scale = (s6 == 0 || s6 == 3) ? SCv : 1.f;
        trans32(ib, ob, 1024, 64, y * 32, x * 32, scale, t, tid);
    } else if (blk < 16408) {               // Wo1/Wo2
        const int local = blk - 14360;
        const int x = local & 31, y = (local >> 5) & 31, z = local >> 10;
        trans32(z ? Wo2 : Wo1, z ? Wo2T : Wo1T, 1024, 1024, y * 32, x * 32, 1.f, t, tid);
    } else if (blk < 18456) {               // Wf1 (K=1024, N=2048)
        const int local = blk - 16408;
        const int x = local & 63, y = local >> 6;
        trans32(Wf1, Wf1T, 1024, 2048, y * 32, x * 32, 1.f, t, tid);
    } else {                                // Wf2 (K=2048, N=1024)
        const int local = blk - 18456;
        const int x = local & 31, y = local >> 5;
        trans32(Wf2, Wf2T, 2048, 1024, y * 32, x * 32, 1.f, t, tid);
    }
}

// ---------------------------------------------------------------------------
// bf16 MFMA GEMM, TMxTN tile, BK templated, 256 thr (4 waves 2x2). XOR-swizzled.
// T1 XCD-aware tile remap: swz = (id%8)*(nwg/8) + id/8 (all grids %8==0).
// ---------------------------------------------------------------------------
template<int TM, int TN, int BK, int OUTMODE, int ACT>
__global__ __launch_bounds__(256) void gemm_bf16_k(
    const ushort* __restrict__ A, const ushort* __restrict__ Bt,
    const float* __restrict__ bias, void* __restrict__ C,
    ushort* __restrict__ Cvt, int matV, int N, int K)
{
    constexpr int NI = TM / 32;
    constexpr int NJ = TN / 32;
    constexpr int KS = BK / 32;
    constexpr int CHR = BK / 8;                 // 16B chunks per row
    __shared__ __align__(16) ushort At[TM * BK];
    __shared__ __align__(16) ushort Bts[TN * BK];
    const int tid = threadIdx.x, lane = tid & 63, w = tid >> 6;
    const int wm = w >> 1, wn = w & 1;
    const int q = lane & 15, g = lane >> 4;

    // T1 XCD swizzle (nwg % 8 == 0 for every grid in this launch set)
    const int nwg = gridDim.x * gridDim.y;
    const int id0 = blockIdx.y * gridDim.x + blockIdx.x;
    const int swz = (id0 & 7) * (nwg >> 3) + (id0 >> 3);
    const int m0 = (swz / gridDim.x) * TM, n0 = (swz % gridDim.x) * TN;

    float4v acc[NI][NJ];
    #pragma unroll
    for (int i = 0; i < NI; ++i)
        #pragma unroll
        for (int j = 0; j < NJ; ++j) acc[i][j] = (float4v){0.f, 0.f, 0.f, 0.f};

    for (int k0 = 0; k0 < K; k0 += BK) {
        #pragma unroll
        for (int t = 0; t < TM * CHR / 256; ++t) {
            const int cb = (w * (TM * CHR / 256) + t) * 64;
            const int c = cb + lane;
            const int row = c / CHR, kc = (c % CHR) ^ (row & (CHR - 1));
            glds16(&A[(size_t)(m0 + row) * K + k0 + kc * 8], &At[cb * 8]);
        }
        #pragma unroll
        for (int t = 0; t < TN * CHR / 256; ++t) {
            const int cb = (w * (TN * CHR / 256) + t) * 64;
            const int c = cb + lane;
            const int row = c / CHR, kc = (c % CHR) ^ (row & (CHR - 1));
            glds16(&Bt[(size_t)(n0 + row) * K + k0 + kc * 8], &Bts[cb * 8]);
        }
        __syncthreads();
        #pragma unroll
        for (int ks = 0; ks < KS; ++ks) {
            short8v af[NI], bf[NJ];
            #pragma unroll
            for (int i = 0; i < NI; ++i) {
                const int row = wm * (TM / 2) + i * 16 + q;
                af[i] = *(const short8v*)((const char*)At +
                        row * (BK * 2) + (((ks * 4 + g) ^ (q & (CHR - 1))) << 4));
            }
            #pragma unroll
            for (int j = 0; j < NJ; ++j) {
                const int row = wn * (TN / 2) + j * 16 + q;
                bf[j] = *(const short8v*)((const char*)Bts +
                        row * (BK * 2) + (((ks * 4 + g) ^ (q & (CHR - 1))) << 4));
            }
            #pragma unroll
            for (int i = 0; i < NI; ++i)
                #pragma unroll
                for (int j = 0; j < NJ; ++j)
                    acc[i][j] = mfma16(af[i], bf[j], acc[i][j]);
        }
        __syncthreads();
    }

    float bcol[NJ];
    #pragma unroll
    for (int j = 0; j < NJ; ++j) bcol[j] = bias[n0 + wn * (TN / 2) + j * 16 + q];

    #pragma unroll
    for (int i = 0; i < NI; ++i) {
        const int rowg0 = m0 + wm * (TM / 2) + i * 16 + g * 4;
        #pragma unroll
        for (int j = 0; j < NJ; ++j) {
            const int colg = n0 + wn * (TN / 2) + j * 16 + q;
            float v[4];
            #pragma unroll
            for (int r = 0; r < 4; ++r) {
                v[r] = acc[i][j][r] + bcol[j];
                if (ACT) v[r] = fmaxf(v[r], 0.f);
            }
            if (OUTMODE == 0) {
                #pragma unroll
                for (int r = 0; r < 4; ++r)
                    ((float*)C)[(size_t)(rowg0 + r) * N + colg] = v[r];
            } else if (OUTMODE == 1) {
                #pragma unroll
                for (int r = 0; r < 4; ++r)
                    ((ushort*)C)[(size_t)(rowg0 + r) * N + colg] = f2bf(v[r]);
            } else {
                const int mat = colg >> 10, h = (colg >> 6) & 15, d = colg & 63;
                const int bb = rowg0 >> 11, s0 = rowg0 & 2047;
                if (mat == matV) {   // V -> transposed layout [bh][d][s]
                    uint2 pv;
                    pv.x = cvtpk(v[0], v[1]);
                    pv.y = cvtpk(v[2], v[3]);
                    *(uint2*)&Cvt[((size_t)(bb * H_ + h) * D_ + d) * S_ + s0] = pv;
                } else {
                    #pragma unroll
                    for (int r = 0; r < 4; ++r)
                        ((ushort*)C)[((((size_t)(mat * B_ + bb) * H_ + h) * S_) + s0 + r) * D_ + d] = f2bf(v[r]);
                }
            }
        }
    }
}

// ---------------------------------------------------------------------------
// Flash attention, 32x32x16 bf16 MFMA, swapped form, STATIC-MAX softmax.
// kv-tile 128 (two 64-halves per barrier interval).
// ---------------------------------------------------------------------------
template<int CAUSAL>
__global__ __launch_bounds__(256, 2) void fattn_k(
    const ushort* __restrict__ Qg, const ushort* __restrict__ Kg,
    const ushort* __restrict__ VTg, ushort* __restrict__ Og, int Skv)
{
    __shared__ __align__(16) ushort Kt[2][128 * 64];  // [kv][d] swizzled, 16 KB x2
    __shared__ __align__(16) ushort Vt[2][64 * 128];  // [d][kv] swizzled, 16 KB x2
    const int tid = threadIdx.x, lane = tid & 63, w = tid >> 6;   // w 0..3
    const int q = lane & 31, hi = lane >> 5;
    const int id = blockIdx.x;
    const int bh = id & 31;
    const int t_ = id >> 5;
    const int qb = CAUSAL ? ((t_ < 8) ? (15 - t_) : (t_ - 8)) : t_;
    const int q0b = qb * 128;
    const int q0w = q0b + w * 32;
    const float MB = 24.f;                            // static exponent bias

    // staging sources: K 1024 chunks (4/thr), V 1024 chunks (4/thr), pre-swizzled
    const ushort* kS[4]; const ushort* vS[4];
    #pragma unroll
    for (int i = 0; i < 4; ++i) {
        const int c = i * 256 + tid;
        const int rk = c >> 3, chk = c & 7;
        kS[i] = Kg + ((size_t)bh * Skv + rk) * 64 + ((chk ^ (rk & 7)) * 8);
        const int rv = c >> 4, chv = c & 15;
        vS[i] = VTg + ((size_t)bh * 64 + rv) * (size_t)Skv + ((chv ^ (rv & 15)) * 8);
    }

#define STAGE(nb) do { \
        glds16(kS[0], &Kt[nb][(tid) * 8]); \
        glds16(kS[1], &Kt[nb][(tid + 256) * 8]); \
        glds16(kS[2], &Kt[nb][(tid + 512) * 8]); \
        glds16(kS[3], &Kt[nb][(tid + 768) * 8]); \
        glds16(vS[0], &Vt[nb][(tid) * 8]); \
        glds16(vS[1], &Vt[nb][(tid + 256) * 8]); \
        glds16(vS[2], &Vt[nb][(tid + 512) * 8]); \
        glds16(vS[3], &Vt[nb][(tid + 768) * 8]); \
        kS[0] += 128 * 64; kS[1] += 128 * 64; kS[2] += 128 * 64; kS[3] += 128 * 64; \
        vS[0] += 128; vS[1] += 128; vS[2] += 128; vS[3] += 128; } while (0)

    // Q B-fragments (Q pre-scaled by 0.125*log2e): B[k=d][col=q], k=ki*16+hi*8+e
    short8v qf[4];
    #pragma unroll
    for (int ki = 0; ki < 4; ++ki)
        qf[ki] = *(const short8v*)&Qg[((size_t)bh * S_ + q0w + q) * 64 + ki * 16 + hi * 8];

    // K LDS base (within a 64-kv half): row=q, chunk=(2ki+hi)^(q&7) -> ^ (ki<<5)
    const int ktB = q * 128 + ((hi ^ (q & 7)) << 4);

    float16v oacc0, oacc1;
    #pragma unroll
    for (int r = 0; r < 16; ++r) { oacc0[r] = 0.f; oacc1[r] = 0.f; }
    float l_ = 0.f;

    const int ktiles = CAUSAL ? (qb + 1) : (Skv >> 7);
    int cur = 0;

    STAGE(0);
    __syncthreads();

    for (int kt = 0; kt < ktiles; ++kt) {
        if (kt + 1 < ktiles) STAGE(cur ^ 1);          // issue-early
        const char* ktp = (const char*)Kt[cur];
        const char* vtp = (const char*)Vt[cur];

        #pragma unroll
        for (int h = 0; h < 2; ++h) {                 // two 64-kv halves
            const int kv0 = kt * 128 + h * 64;
            const char* ktph = ktp + h * 8192;        // rows h*64..h*64+63

            // S^T = K . Q^T : two kv-32 blocks, K=16 chunks over d
            float16v st0, st1;
            #pragma unroll
            for (int r = 0; r < 16; ++r) { st0[r] = 0.f; st1[r] = 0.f; }
            __builtin_amdgcn_s_setprio(1);
            #pragma unroll
            for (int ki = 0; ki < 4; ++ki) {
                short8v kf0 = *(const short8v*)(ktph + (ktB ^ (ki << 5)));
                short8v kf1 = *(const short8v*)(ktph + (ktB ^ (ki << 5)) + 4096);
                st0 = mfma32(kf0, qf[ki], st0);
                st1 = mfma32(kf1, qf[ki], st1);
            }
            __builtin_amdgcn_s_setprio(0);

            if (CAUSAL && kv0 + 63 > q0b) {           // diagonal-region halves only
                const int qg_ = q0w + q;
                #pragma unroll
                for (int r = 0; r < 16; ++r) {
                    const int row = (r & 3) + 8 * (r >> 2) + 4 * hi;
                    if (kv0 + row > qg_)      st0[r] = -1e9f;
                    if (kv0 + 32 + row > qg_) st1[r] = -1e9f;
                }
            }

            // STATIC-MAX: P = exp2(s - MB), exact (scale cancels in O = PV/l)
            float ts[16];
            #pragma unroll
            for (int r = 0; r < 16; ++r) {
                st0[r] = fexp2(st0[r] - MB);
                st1[r] = fexp2(st1[r] - MB);
                ts[r] = st0[r] + st1[r];
            }
            #pragma unroll
            for (int off = 8; off >= 1; off >>= 1)
                #pragma unroll
                for (int i = 0; i < 8; ++i)
                    if (i < off) ts[i] += ts[i + off];
            l_ += ts[0] + __shfl_xor(ts[0], 32);

            // pack P to bf16 words
            unsigned W0[8], W1[8];
            #pragma unroll
            for (int s = 0; s < 8; ++s) {
                W0[s] = cvtpk(st0[2 * s], st0[2 * s + 1]);
                W1[s] = cvtpk(st1[2 * s], st1[2 * s + 1]);
            }

            // build PV B-frags bq[kb]: P[kv0+kb*16+hi*8+e][q] (R14-verified)
            short8v bq[4];
            #pragma unroll
            for (int kb = 0; kb < 4; ++kb) {
                union { unsigned u[4]; short8v v; } bb;
                #pragma unroll
                for (int j = 0; j < 4; ++j) {
                    const unsigned* Wb = (kb >> 1) ? W1 : W0;
                    const int s0 = (j & 1) + 4 * (kb & 1);
                    const unsigned own  = hi ? Wb[s0 + 2] : Wb[s0];
                    const unsigned send = hi ? Wb[s0]     : Wb[s0 + 2];
                    const unsigned rec  = (unsigned)__shfl_xor((int)send, 32);
                    bb.u[j] = (j >> 1) ? (hi ? own : rec) : (hi ? rec : own);
                }
                bq[kb] = bb.v;
            }

            // O^T += V^T . P^T : kv-chunk x = h*8 + 2kb + hi on 256B rows
            __builtin_amdgcn_s_setprio(1);
            #pragma unroll
            for (int kb = 0; kb < 4; ++kb) {
                const int x = h * 8 + 2 * kb + hi;
                short8v vf0 = *(const short8v*)(vtp +
                              q * 256 + ((x ^ (q & 15)) << 4));
                short8v vf1 = *(const short8v*)(vtp +
                              (32 + q) * 256 + ((x ^ (q & 15)) << 4));
                oacc0 = mfma32(vf0, bq[kb], oacc0);
                oacc1 = mfma32(vf1, bq[kb], oacc1);
            }
            __builtin_amdgcn_s_setprio(0);
        }

        __syncthreads();       // ONE drain+barrier per 128 kv
        cur ^= 1;
    }
#undef STAGE

    // normalize + stage O into Kt region (dead), swizzled; then coalesced out
    const float inv = frcp(l_);
    char* Ob = (char*)Kt;
    const int qr = w * 32 + q;
    #pragma unroll
    for (int s = 0; s < 8; ++s) {
        const int d0a = 2 * (s & 1) + 8 * (s >> 1) + 4 * hi;        // db=0
        unsigned wa = cvtpk(oacc0[2 * s] * inv, oacc0[2 * s + 1] * inv);
        *(unsigned*)(Ob + qr * 128 + ((((d0a >> 3) ^ (qr & 7)) << 4) | ((2 * d0a) & 15))) = wa;
        const int d0b = d0a + 32;                                    // db=1
        unsigned wb = cvtpk(oacc1[2 * s] * inv, oacc1[2 * s + 1] * inv);
        *(unsigned*)(Ob + qr * 128 + ((((d0b >> 3) ^ (qr & 7)) << 4) | ((2 * d0b) & 15))) = wb;
    }
    __syncthreads();
    const int b = bh >> 4, h2 = bh & 15;
    #pragma unroll
    for (int t = 0; t < 4; ++t) {
        const int c = t * 256 + tid;
        const int qrow = c >> 3, ch = c & 7;
        short8v v = *(const short8v*)(Ob + qrow * 128 + ((ch ^ (qrow & 7)) << 4));
        *(short8v*)&Og[((size_t)(b * S_ + q0b + qrow)) * M_ + h2 * 64 + ch * 8] = v;
    }
}

// ---------------------------------------------------------------------------
// Fused residual-add + LayerNorm, bf16 residual chain.
// X bf16, Rz bf16; OUTF=0: emit bf16; OUTF=1: emit fp32 (final output).
// ---------------------------------------------------------------------------
template<int OUTF>
__global__ __launch_bounds__(256) void ln_k(
    const ushort* __restrict__ X, const ushort* __restrict__ Rz,
    const float* __restrict__ g, const float* __restrict__ be,
    ushort* __restrict__ outb, float* __restrict__ outf)
{
    __shared__ float red[8];
    const int row = blockIdx.x, tid = threadIdx.x;
    const int lane = tid & 63, w = tid >> 6;

    ushort4 xu = *(const ushort4*)&X[(size_t)row * M_ + tid * 4];
    ushort4 ru = *(const ushort4*)&Rz[(size_t)row * M_ + tid * 4];
    float4 x = make_float4(bf2f(xu.x) + bf2f(ru.x), bf2f(xu.y) + bf2f(ru.y),
                           bf2f(xu.z) + bf2f(ru.z), bf2f(xu.w) + bf2f(ru.w));

    float sm = x.x + x.y + x.z + x.w;
    #pragma unroll
    for (int off = 1; off < 64; off <<= 1) sm += __shfl_xor(sm, off);
    if (lane == 0) red[w] = sm;
    __syncthreads();
    const float mean = (red[0] + red[1] + red[2] + red[3]) * (1.f / M_);

    x.x -= mean; x.y -= mean; x.z -= mean; x.w -= mean;
    float vs = x.x * x.x + x.y * x.y + x.z * x.z + x.w * x.w;
    #pragma unroll
    for (int off = 1; off < 64; off <<= 1) vs += __shfl_xor(vs, off);
    if (lane == 0) red[4 + w] = vs;
    __syncthreads();
    const float var = (red[4] + red[5] + red[6] + red[7]) * (1.f / M_);
    const float rs = rsqrtf(var + 1e-5f);

    float4 gg = ld4(g + tid * 4), bb = ld4(be + tid * 4);
    float4 y = make_float4(x.x * rs * gg.x + bb.x, x.y * rs * gg.y + bb.y,
                           x.z * rs * gg.z + bb.z, x.w * rs * gg.w + bb.w);
    if (OUTF) {
        *(float4*)(outf + (size_t)row * M_ + tid * 4) = y;
    } else {
        ushort4 ob = { f2bf(y.x), f2bf(y.y), f2bf(y.z), f2bf(y.w) };
        *(ushort4*)&outb[(size_t)row * M_ + tid * 4] = ob;
    }
}

// ---------------------------------------------------------------------------
extern "C" void kernel_launch(void* const* d_in, const int* in_sizes, int n_in,
                              void* d_out, int out_size, void* d_ws, size_t ws_size,
                              hipStream_t stream)
{
    const float* input = (const float*)d_in[0];
    const float* enc   = (const float*)d_in[1];
    const float* Wq1 = (const float*)d_in[2];  const float* bq1 = (const float*)d_in[3];
    const float* Wk1 = (const float*)d_in[4];  const float* bk1 = (const float*)d_in[5];
    const float* Wv1 = (const float*)d_in[6];  const float* bv1 = (const float*)d_in[7];
    const float* Wo1 = (const float*)d_in[8];  const float* bo1 = (const float*)d_in[9];
    const float* ln1g = (const float*)d_in[10]; const float* ln1b = (const float*)d_in[11];
    const float* Wq2 = (const float*)d_in[12]; const float* bq2 = (const float*)d_in[13];
    const float* Wk2 = (const float*)d_in[14]; const float* bk2 = (const float*)d_in[15];
    const float* Wv2 = (const float*)d_in[16]; const float* bv2 = (const float*)d_in[17];
    const float* Wo2 = (const float*)d_in[18]; const float* bo2 = (const float*)d_in[19];
    const float* ln2g = (const float*)d_in[20]; const float* ln2b = (const float*)d_in[21];
    const float* Wf1 = (const float*)d_in[22]; const float* bf1 = (const float*)d_in[23];
    const float* Wf2 = (const float*)d_in[24]; const float* bf2 = (const float*)d_in[25];
    const float* ln3g = (const float*)d_in[26]; const float* ln3b = (const float*)d_in[27];

    const float SC = 0.18033688011112042f;     // 0.125 * log2(e)

    char* W = (char*)d_ws;
    #define OFS(mb) ((void*)(W + (size_t)(mb) * 1024 * 1024))
    ushort* x0b    = (ushort*)OFS(0);    // alive through ln1 (residual)
    ushort* encb   = (ushort*)OFS(8);
    ushort* WqkvT1 = (ushort*)OFS(16);
    ushort* Wo1T   = (ushort*)OFS(22);
    ushort* Wq2T   = (ushort*)OFS(24);
    ushort* WkvT2  = (ushort*)OFS(26);
    ushort* Wo2T   = (ushort*)OFS(30);
    ushort* Wf1T   = (ushort*)OFS(32);
    ushort* Wf2T   = (ushort*)OFS(36);
    float*  biasQKV1 = (float*)OFS(40);
    float*  biasQ2   = (float*)((char*)OFS(40) + 32768);
    ushort* QKV1   = (ushort*)OFS(41);   // [3][B][H][S][D] (V region unused)
    ushort* VT1    = (ushort*)OFS(65);
    ushort* att1b  = (ushort*)OFS(73);
    ushort* o1b    = (ushort*)OFS(81);
    ushort* out1b  = (ushort*)OFS(57);   // bf16 residual 1 (alive thru ln2)
    ushort* Q2     = (ushort*)OFS(65);
    ushort* KV2    = (ushort*)OFS(73);   // [2][B][H][S][D] (V region unused)
    ushort* VT2    = (ushort*)OFS(90);   // x0b alive until ln1
    ushort* att2b  = (ushort*)OFS(8);
    ushort* o2b    = (ushort*)OFS(65);
    ushort* out2b  = (ushort*)OFS(0);    // bf16 residual 2 (x0b dead after ln1)
    ushort* ff1b   = (ushort*)OFS(41);
    ushort* ff2b   = (ushort*)OFS(81);   // o1b dead after ln1
    float*  out    = (float*)d_out;
    const size_t MAT = (size_t)B_ * H_ * S_ * D_;   // 4 Mi elements

    dim3 blk(256);

    // ---- prep (ONE launch, 20504 blocks) ----
    prep_k<<<dim3(20504), blk, 0, stream>>>(
        input, enc, x0b, encb,
        bq1, bk1, bv1, bk2, bv2, bq2, biasQKV1,
        Wq1, Wk1, Wv1, Wq2, Wk2, Wv2, WqkvT1, Wq2T, WkvT2,
        Wo1, Wo2, Wo1T, Wo2T, Wf1, Wf1T, Wf2, Wf2T, SC);

    // ---- masked self-attention ----
    gemm_bf16_k<128, 128, 64, 2, 0><<<dim3(24, 32), blk, 0, stream>>>(
        x0b, WqkvT1, biasQKV1, QKV1, VT1, 2, 3072, 1024);
    fattn_k<1><<<dim3(512), blk, 0, stream>>>(QKV1, QKV1 + MAT, VT1, att1b, S_);
    gemm_bf16_k<64, 64, 64, 1, 0><<<dim3(16, 64), blk, 0, stream>>>(
        att1b, Wo1T, bo1, o1b, nullptr, 9, 1024, 1024);
    ln_k<0><<<dim3(R_), blk, 0, stream>>>(o1b, x0b, ln1g, ln1b, out1b, nullptr);

    // ---- cross-attention ----
    gemm_bf16_k<64, 64, 64, 2, 0><<<dim3(16, 64), blk, 0, stream>>>(
        out1b, Wq2T, biasQ2, Q2, nullptr, 9, 1024, 1024);
    gemm_bf16_k<128, 128, 64, 2, 0><<<dim3(16, 32), blk, 0, stream>>>(
        encb, WkvT2, biasQKV1 + 4096, KV2, VT2, 1, 2048, 1024);
    fattn_k<0><<<dim3(512), blk, 0, stream>>>(Q2, KV2, VT2, att2b, S_);
    gemm_bf16_k<64, 64, 64, 1, 0><<<dim3(16, 64), blk, 0, stream>>>(
        att2b, Wo2T, bo2, o2b, nullptr, 9, 1024, 1024);
    ln_k<0><<<dim3(R_), blk, 0, stream>>>(o2b, out1b, ln2g, ln2b, out2b, nullptr);

    // ---- FFN ----
    gemm_bf16_k<128, 64, 64, 1, 1><<<dim3(32, 32), blk, 0, stream>>>(
        out2b, Wf1T, bf1, ff1b, nullptr, 9, 2048, 1024);
    gemm_bf16_k<64, 64, 64, 1, 0><<<dim3(16, 64), blk, 0, stream>>>(
        ff1b, Wf2T, bf2, ff2b, nullptr, 9, 1024, 2048);
    ln_k<1><<<dim3(R_), blk, 0, stream>>>(ff2b, out2b, ln3g, ln3b, nullptr, out);
    #undef OFS
}